// Round 10
// baseline (4403.341 us; speedup 1.0000x reference)
//
#include <hip/hip_runtime.h>
#include <cstdint>
#include <cstddef>

__device__ __forceinline__ float sigf(float x) { return 1.f / (1.f + expf(-x)); }

__device__ __forceinline__ unsigned packh(float a, float b) {
  union { unsigned u; _Float16 h[2]; } cv;
  cv.h[0] = (_Float16)a; cv.h[1] = (_Float16)b; return cv.u;
}
__device__ __forceinline__ float2 uph(unsigned u) {
  union { unsigned uu; _Float16 h[2]; } cv; cv.uu = u;
  return make_float2((float)cv.h[0], (float)cv.h[1]);
}

typedef _Float16 f16x8 __attribute__((ext_vector_type(8)));
typedef float f32x16 __attribute__((ext_vector_type(16)));

static constexpr int TT = 8192;
static constexpr int MM = 64;
static constexpr int CC = 32;
static constexpr int DD = 512;
static constexpr unsigned GUARD_MAX = 1u << 30;

// ---------------------------------------------------------------- ws zeroing
__global__ void zero_k(float* __restrict__ p, long n) {
  long i = (long)blockIdx.x * 256 + threadIdx.x;
  long stride = (long)gridDim.x * 256;
  for (; i < n; i += stride) p[i] = 0.f;
}

// ---------------------------------------------------------------- elementwise
__global__ void copy_k(const float* __restrict__ a, float* __restrict__ o, int n) {
  int i = blockIdx.x * 256 + threadIdx.x;
  if (i < n) o[i] = a[i];
}
__global__ void addff_k(const float* __restrict__ a, const float* __restrict__ b, float* __restrict__ o, int n) {
  int i = blockIdx.x * 256 + threadIdx.x;
  if (i < n) o[i] = a[i] + b[i];
}
__global__ void acomb_k(const float* __restrict__ hf, const float* __restrict__ hb, float* __restrict__ o, int n) {
  int i = blockIdx.x * 256 + threadIdx.x;
  if (i >= n) return;
  int s = i >> 9, j = i & 511;
  float v = (j < 256) ? hf[(size_t)s * 256 + j] : hb[(size_t)s * 256 + (j - 256)];
  o[i] = fmaxf(v, 0.f);
}
__global__ void gatherpos_k(const float* __restrict__ fpos, const int* __restrict__ centers,
                            float* __restrict__ segpos, int n) {
  int i = blockIdx.x * 256 + threadIdx.x;
  if (i >= n) return;
  int s = i >> 9, dd = i & 511;
  int ct = centers[s];
  ct = ct < 0 ? 0 : (ct > TT - 1 ? TT - 1 : ct);
  segpos[i] = fpos[(size_t)ct * 512 + dd];
}

// ---------------------------------------------------------------- text norms
__global__ void tnorm_k(const float* __restrict__ text, float* __restrict__ tnorm) {
  int c = blockIdx.x * 256 + threadIdx.x;
  if (c >= 32) return;
  float s = 0.f;
  for (int dd = 0; dd < 512; dd++) { float v = text[(size_t)c * 512 + dd]; s += v * v; }
  tnorm[c] = sqrtf(s);
}

// ---------------- fold argmax projection: M[k][c] = Wf2c[k,:]·(text_c/|t_c|)
// argmax_c((ff@W + b)·t_c/|t_c|) == argmax_c(ff·M_c + bdot_c)  (norm_v > 0
// cancels in argmax). 16x less frame work than the 8192x512 fp32 GEMM.
__global__ void prepM_k(const float* __restrict__ W, const float* __restrict__ b,
                        const float* __restrict__ text, const float* __restrict__ tnorm,
                        float* __restrict__ M, float* __restrict__ bdot) {
  int idx = blockIdx.x * 256 + threadIdx.x;
  if (idx < 512 * 32) {
    int k = idx >> 5, c = idx & 31;
    const float* wr = W + (size_t)k * 512;
    const float* tr = text + (size_t)c * 512;
    float s = 0.f;
    for (int dd = 0; dd < 512; dd++) s += wr[dd] * tr[dd];
    M[idx] = s / tnorm[c];
  }
  if (idx < 32) {
    const float* tr = text + (size_t)idx * 512;
    float s = 0.f;
    for (int dd = 0; dd < 512; dd++) s += b[dd] * tr[dd];
    bdot[idx] = s / tnorm[idx];
  }
}

// 8 rows/block; lane c of each 32-group owns class c; shfl-argmax (min idx tie)
__launch_bounds__(256)
__global__ void fargmax_k(const float* __restrict__ ff, const float* __restrict__ M,
                          const float* __restrict__ bdot, int* __restrict__ pred) {
  const int r = blockIdx.x * 8 + (threadIdx.x >> 5);
  const int c = threadIdx.x & 31;
  const float* fr = ff + (size_t)r * 512;
  float acc = bdot[c];
  for (int k = 0; k < 512; k++) acc += fr[k] * M[k * 32 + c];
  float best = acc; int bidx = c;
  for (int off = 16; off >= 1; off >>= 1) {
    const float ov = __shfl_xor(best, off);
    const int oi = __shfl_xor(bidx, off);
    if (ov > best || (ov == best && oi < bidx)) { best = ov; bidx = oi; }
  }
  if (c == 0) pred[r] = bidx;
}

// ---------------------------------------------------- naive attention pieces
__global__ void nlogit_k(const float* __restrict__ Q, const float* __restrict__ Kk,
                         float* __restrict__ L, int NY, int NX) {
  int idx = blockIdx.x * 256 + threadIdx.x;
  if (idx >= NY * NX) return;
  int y = idx / NX, x = idx - y * NX;
  const float* qr = Q + (size_t)y * 512;
  const float* kr = Kk + (size_t)x * 512;
  float d = 0.f;
  for (int k = 0; k < 512; k++) d += qr[k] * kr[k];
  L[idx] = d * 0.044194173824159216f;
}
__global__ void nsoft_k(float* __restrict__ L, int NY, int NX) {
  int y = blockIdx.x * 256 + threadIdx.x;
  if (y >= NY) return;
  float* row = L + (size_t)y * NX;
  float m = row[0];
  for (int x = 1; x < NX; x++) m = fmaxf(m, row[x]);
  float s = 0.f;
  for (int x = 0; x < NX; x++) { float p = expf(row[x] - m); row[x] = p; s += p; }
  const float inv = 1.f / s;
  for (int x = 0; x < NX; x++) row[x] *= inv;
}
__global__ void nav_k(const float* __restrict__ P, const float* __restrict__ V,
                      float* __restrict__ O, int NY, int NX) {
  int idx = blockIdx.x * 256 + threadIdx.x;
  if (idx >= NY * 512) return;
  int y = idx >> 9, dd = idx & 511;
  const float* pr = P + (size_t)y * NX;
  float o = 0.f;
  for (int x = 0; x < NX; x++) o += pr[x] * V[(size_t)x * 512 + dd];
  O[idx] = o;
}

// ------------------------------- parallel run-length segmentation (one block)
__global__ void segscan_k(const int* __restrict__ pred, int* __restrict__ segid,
                          int* __restrict__ starts, int* __restrict__ centers,
                          int* __restrict__ cnts) {
  __shared__ int base[256];
  __shared__ int SS;
  const int tid = threadIdx.x;
  int lc = 0;
  unsigned flags = 0;
  int prev = (tid > 0) ? pred[tid * 32 - 1] : 0;
  for (int i = 0; i < 32; i++) {
    const int t = tid * 32 + i;
    const int cur = pred[t];
    const int c = (t > 0) && (cur != prev);
    prev = cur;
    flags |= ((unsigned)c) << i;
    lc += c;
  }
  base[tid] = lc;
  __syncthreads();
  if (tid == 0) {
    int run = 0;
    for (int i = 0; i < 256; i++) { const int v = base[i]; base[i] = run; run += v; }
    SS = run + 1;
  }
  __syncthreads();
  int b = base[tid];
  for (int i = 0; i < 32; i++) {
    const int t = tid * 32 + i;
    if ((flags >> i) & 1u) { b++; starts[b] = t; }
    segid[t] = b;
  }
  if (tid == 0) starts[0] = 0;
  __threadfence_block();
  __syncthreads();
  const int S = SS;
  for (int s = tid; s < TT; s += 256) {
    if (s < S) {
      const int e = (s == S - 1) ? (TT - 1) : (starts[s + 1] - 1);
      centers[s] = (starts[s] + e) >> 1;
      cnts[s] = e - starts[s] + 1;
    } else {
      starts[s] = 0; cnts[s] = 1; centers[s] = 0;
    }
  }
}

// ---------------------------------------------------------- segment mean pool
__global__ void segmean_k(const float* __restrict__ ff, const int* __restrict__ starts,
                          const int* __restrict__ cnts, float* __restrict__ segmean, int S) {
  int idx = blockIdx.x * 256 + threadIdx.x;
  if (idx >= S * 512) return;
  int s = idx >> 9, dd = idx & 511;
  int st = starts[s], n = cnts[s];
  st = st < 0 ? 0 : (st > TT - 1 ? TT - 1 : st);
  n = n < 1 ? 1 : n;
  if (st + n > TT) n = TT - st;
  float a = 0.f;
  for (int t = st; t < st + n; t++) a += ff[(size_t)t * 512 + dd];
  segmean[idx] = a / (float)n;
}

// ------------------- multi-block bidirectional seg GRU (H=256), LDS weights
// gi prefetched into registers; next-step gi load overlaps the flag spin.
// [r0-verified 1571us mailbox protocol, FROZEN.]
// XCD co-location (r10): grid padded to 32; only blockIdx%8==0 (dir0) and
// ==1 (dir1) work -> under round-robin workgroup->XCD dispatch each dir's 4
// partitions share ONE XCD, so the per-step h/flag mailbox stays in that
// XCD's L2 (~200cy) instead of crossing XCDs (~900cy). Placement-independent
// correctness: surplus blocks exit; protocol unchanged.
__launch_bounds__(192)
__global__ void gru_seg_mb_k(const float* __restrict__ gi_f, const float* __restrict__ gi_b,
                             const float* __restrict__ Whh_f, const float* __restrict__ bhh_f,
                             const float* __restrict__ Whh_b, const float* __restrict__ bhh_b,
                             float* __restrict__ hf, float* __restrict__ hb, int S,
                             int* __restrict__ flag_f, int* __restrict__ flag_b) {
  const int xcd = blockIdx.x & 7;
  const int ord = blockIdx.x >> 3;
  if (xcd > 1 || ord > 3) return;
  const int dir = xcd;
  const int part = ord;
  const float* gi = dir ? gi_b : gi_f;
  const float* Whh = dir ? Whh_b : Whh_f;
  const float* bhh = dir ? bhh_b : bhh_f;
  float* ho = dir ? hb : hf;
  int* flg = dir ? flag_b : flag_f;
  const int tid = threadIdx.x;
  const int h0 = part * 64;
  const int grp = tid >> 6;
  const int jj = tid & 63;
  const int j = grp * 256 + h0 + jj;
  __shared__ __align__(16) unsigned wlds[128 * 192];
  __shared__ __align__(16) unsigned hpk[128];
  __shared__ float hcur[256];
  __shared__ float rbuf[64], zbuf[64], gnbuf[64];
  for (int e = tid; e < 128 * 192; e += 192) {
    const int q = e / 768, rem = e % 768;
    const int g = rem >> 2, r = rem & 3;
    const int i2 = q * 4 + r;
    const int gg = (g >> 6) * 256 + h0 + (g & 63);
    wlds[e] = packh(Whh[(size_t)(2 * i2) * 768 + gg], Whh[(size_t)(2 * i2 + 1) * 768 + gg]);
  }
  for (int e = tid; e < 128; e += 192) hpk[e] = 0u;
  for (int e = tid; e < 256; e += 192) hcur[e] = 0.f;
  const float bj = bhh[j];
  __syncthreads();
  const uint4* hp4 = reinterpret_cast<const uint4*>(hpk);
  const uint4* wp4 = reinterpret_cast<const uint4*>(wlds);
  // prefetch step 0 gi
  int s = dir ? (S - 1) : 0;
  float g_j = gi[(size_t)s * 768 + j];
  float g_n = (tid < 64) ? gi[(size_t)s * 768 + 512 + h0 + tid] : 0.f;
  for (int step = 0; step < S; step++) {
    float a0 = 0.f, a1 = 0.f, a2 = 0.f, a3 = 0.f;
#pragma unroll 8
    for (int q = 0; q < 32; q++) {
      const uint4 h4 = hp4[q];
      const uint4 w4 = wp4[q * 192 + tid];
      const float2 hh0 = uph(h4.x), hh1 = uph(h4.y), hh2 = uph(h4.z), hh3 = uph(h4.w);
      const float2 ww0 = uph(w4.x), ww1 = uph(w4.y), ww2 = uph(w4.z), ww3 = uph(w4.w);
      a0 += hh0.x * ww0.x + hh0.y * ww0.y;
      a1 += hh1.x * ww1.x + hh1.y * ww1.y;
      a2 += hh2.x * ww2.x + hh2.y * ww2.y;
      a3 += hh3.x * ww3.x + hh3.y * ww3.y;
    }
    const float gh = bj + (a0 + a1) + (a2 + a3);
    if (grp == 0)      rbuf[jj] = sigf(g_j + gh);
    else if (grp == 1) zbuf[jj] = sigf(g_j + gh);
    else               gnbuf[jj] = gh;
    __syncthreads();
    if (tid < 64) {
      const float nval = tanhf(g_n + rbuf[tid] * gnbuf[tid]);
      const float hn = (1.f - zbuf[tid]) * nval + zbuf[tid] * hcur[h0 + tid];
      __hip_atomic_store(&ho[(size_t)s * 256 + h0 + tid], hn,
                         __ATOMIC_RELAXED, __HIP_MEMORY_SCOPE_AGENT);
    }
    __syncthreads();
    if (tid == 0)
      __hip_atomic_store(&flg[step * 64 + part * 16], 1,
                         __ATOMIC_RELEASE, __HIP_MEMORY_SCOPE_AGENT);
    // prefetch next-step gi while peers arrive (overlaps the spin below)
    const int sn = dir ? (s - 1) : (s + 1);
    if (step + 1 < S) {
      g_j = gi[(size_t)sn * 768 + j];
      if (tid < 64) g_n = gi[(size_t)sn * 768 + 512 + h0 + tid];
    }
    if (tid < 4) {
      int* fp = &flg[step * 64 + tid * 16];
      unsigned guard = 0;
      while (__hip_atomic_load(fp, __ATOMIC_RELAXED, __HIP_MEMORY_SCOPE_AGENT) == 0 &&
             ++guard < GUARD_MAX) {
        __builtin_amdgcn_s_sleep(2);
      }
      (void)__hip_atomic_load(fp, __ATOMIC_ACQUIRE, __HIP_MEMORY_SCOPE_AGENT);
    }
    __syncthreads();
    for (int e = tid; e < 256; e += 192)
      hcur[e] = __hip_atomic_load(&ho[(size_t)s * 256 + e],
                                  __ATOMIC_RELAXED, __HIP_MEMORY_SCOPE_AGENT);
    __syncthreads();
    for (int e = tid; e < 128; e += 192) hpk[e] = packh(hcur[2 * e], hcur[2 * e + 1]);
    __syncthreads();
    s = sn;
  }
}

// ------------------------- multi-block action GRU (H=512), LDS weights
// XCD co-location (r10): grid padded to 128; only blockIdx%8==0 work (16
// parts), all on one XCD under round-robin dispatch.
__launch_bounds__(128)
__global__ void gru_act_mb_k(const float* __restrict__ gi, const float* __restrict__ Whh,
                             const float* __restrict__ bhh, float* __restrict__ hout,
                             int steps, int* __restrict__ flg) {
  if ((blockIdx.x & 7) != 0) return;
  const int part = blockIdx.x >> 3;
  const int tid = threadIdx.x;
  const int h0 = part * 32;
  const int grp = tid >> 5;
  const int jj = tid & 31;
  const bool act = (tid < 96);
  const int j = act ? (grp * 512 + h0 + jj) : 0;
  __shared__ __align__(16) unsigned wlds[256 * 96];
  __shared__ __align__(16) unsigned hpk[256];
  __shared__ float hcur[512];
  __shared__ float rbuf[32], zbuf[32], gnbuf[32];
  for (int e = tid; e < 256 * 96; e += 128) {
    const int q = e / 384, rem = e % 384;
    const int g = rem >> 2, r = rem & 3;
    const int i2 = q * 4 + r;
    const int gg = (g >> 5) * 512 + h0 + (g & 31);
    wlds[e] = packh(Whh[(size_t)(2 * i2) * 1536 + gg], Whh[(size_t)(2 * i2 + 1) * 1536 + gg]);
  }
  for (int e = tid; e < 256; e += 128) hpk[e] = 0u;
  for (int e = tid; e < 512; e += 128) hcur[e] = 0.f;
  const float bj = act ? bhh[j] : 0.f;
  __syncthreads();
  const uint4* hp4 = reinterpret_cast<const uint4*>(hpk);
  const uint4* wp4 = reinterpret_cast<const uint4*>(wlds);
  float g_j = act ? gi[j] : 0.f;
  float g_n = (tid < 32) ? gi[1024 + h0 + tid] : 0.f;
  for (int step = 0; step < steps; step++) {
    if (act) {
      float a0 = 0.f, a1 = 0.f, a2 = 0.f, a3 = 0.f;
#pragma unroll 8
      for (int q = 0; q < 64; q++) {
        const uint4 h4 = hp4[q];
        const uint4 w4 = wp4[q * 96 + tid];
        const float2 hh0 = uph(h4.x), hh1 = uph(h4.y), hh2 = uph(h4.z), hh3 = uph(h4.w);
        const float2 ww0 = uph(w4.x), ww1 = uph(w4.y), ww2 = uph(w4.z), ww3 = uph(w4.w);
        a0 += hh0.x * ww0.x + hh0.y * ww0.y;
        a1 += hh1.x * ww1.x + hh1.y * ww1.y;
        a2 += hh2.x * ww2.x + hh2.y * ww2.y;
        a3 += hh3.x * ww3.x + hh3.y * ww3.y;
      }
      const float gh = bj + (a0 + a1) + (a2 + a3);
      if (grp == 0)      rbuf[jj] = sigf(g_j + gh);
      else if (grp == 1) zbuf[jj] = sigf(g_j + gh);
      else               gnbuf[jj] = gh;
    }
    __syncthreads();
    if (tid < 32) {
      const float nval = tanhf(g_n + rbuf[tid] * gnbuf[tid]);
      const float hn = (1.f - zbuf[tid]) * nval + zbuf[tid] * hcur[h0 + tid];
      __hip_atomic_store(&hout[(size_t)step * 512 + h0 + tid], hn,
                         __ATOMIC_RELAXED, __HIP_MEMORY_SCOPE_AGENT);
    }
    __syncthreads();
    if (tid == 0)
      __hip_atomic_store(&flg[step * 256 + part * 16], 1,
                         __ATOMIC_RELEASE, __HIP_MEMORY_SCOPE_AGENT);
    if (step + 1 < steps) {
      if (act) g_j = gi[(size_t)(step + 1) * 1536 + j];
      if (tid < 32) g_n = gi[(size_t)(step + 1) * 1536 + 1024 + h0 + tid];
    }
    if (tid < 16) {
      int* fp = &flg[step * 256 + tid * 16];
      unsigned guard = 0;
      while (__hip_atomic_load(fp, __ATOMIC_RELAXED, __HIP_MEMORY_SCOPE_AGENT) == 0 &&
             ++guard < GUARD_MAX) {
        __builtin_amdgcn_s_sleep(2);
      }
      (void)__hip_atomic_load(fp, __ATOMIC_ACQUIRE, __HIP_MEMORY_SCOPE_AGENT);
    }
    __syncthreads();
    for (int e = tid; e < 512; e += 128)
      hcur[e] = __hip_atomic_load(&hout[(size_t)step * 512 + e],
                                  __ATOMIC_RELAXED, __HIP_MEMORY_SCOPE_AGENT);
    __syncthreads();
    for (int e = tid; e < 256; e += 128) hpk[e] = packh(hcur[2 * e], hcur[2 * e + 1]);
    __syncthreads();
  }
}

// ------------------------------------------------ MFMA GEMM (fp16 staged)
// C[M,N] = A[M,K] @ B[K,N] + bias.  Tile M64 x N128, K-chunk 64.
// M mult of 64, N mult of 128, K mult of 64.
__launch_bounds__(256)
__global__ void gemmm_k(const float* __restrict__ A, const float* __restrict__ B,
                        const float* __restrict__ bias, float* __restrict__ C,
                        int M, int N, int K) {
  __shared__ __align__(16) _Float16 As16[64][72];
  __shared__ __align__(16) _Float16 Bs16[128][72];
  const int n0 = blockIdx.x * 128, m0 = blockIdx.y * 64;
  const int tid = threadIdx.x;
  const int l = tid & 63, w = tid >> 6;
  const int wm = w & 1, wn = w >> 1;
  const int l31 = l & 31, q = l >> 5;
  f32x16 acc0, acc1;
#pragma unroll
  for (int i = 0; i < 16; i++) { acc0[i] = 0.f; acc1[i] = 0.f; }
  const int am = tid >> 2, ak0 = (tid & 3) * 16;
  const int bk = tid >> 2, bn0 = (tid & 3) * 32;
  for (int kc = 0; kc < K; kc += 64) {
    __syncthreads();
#pragma unroll
    for (int kk = 0; kk < 16; kk += 4) {
      const float4 av = *reinterpret_cast<const float4*>(A + (size_t)(m0 + am) * K + kc + ak0 + kk);
      As16[am][ak0 + kk + 0] = (_Float16)av.x; As16[am][ak0 + kk + 1] = (_Float16)av.y;
      As16[am][ak0 + kk + 2] = (_Float16)av.z; As16[am][ak0 + kk + 3] = (_Float16)av.w;
    }
#pragma unroll
    for (int nn = 0; nn < 32; nn += 4) {
      const float4 bv = *reinterpret_cast<const float4*>(B + (size_t)(kc + bk) * N + n0 + bn0 + nn);
      Bs16[bn0 + nn + 0][bk] = (_Float16)bv.x; Bs16[bn0 + nn + 1][bk] = (_Float16)bv.y;
      Bs16[bn0 + nn + 2][bk] = (_Float16)bv.z; Bs16[bn0 + nn + 3][bk] = (_Float16)bv.w;
    }
    __syncthreads();
#pragma unroll
    for (int ks = 0; ks < 4; ks++) {
      const int k0 = ks * 16 + q * 8;
      const f16x8 a = *reinterpret_cast<const f16x8*>(&As16[wm * 32 + l31][k0]);
      const f16x8 b0 = *reinterpret_cast<const f16x8*>(&Bs16[wn * 64 + l31][k0]);
      acc0 = __builtin_amdgcn_mfma_f32_32x32x16_f16(a, b0, acc0, 0, 0, 0);
      const f16x8 b1 = *reinterpret_cast<const f16x8*>(&Bs16[wn * 64 + 32 + l31][k0]);
      acc1 = __builtin_amdgcn_mfma_f32_32x32x16_f16(a, b1, acc1, 0, 0, 0);
    }
  }
#pragma unroll
  for (int r = 0; r < 16; r++) {
    const int m = m0 + wm * 32 + (r & 3) + 8 * (r >> 2) + 4 * q;
    {
      const int n = n0 + wn * 64 + l31;
      float v = acc0[r];
      if (bias) v += bias[n];
      C[(size_t)m * N + n] = v;
    }
    {
      const int n = n0 + wn * 64 + 32 + l31;
      float v = acc1[r];
      if (bias) v += bias[n];
      C[(size_t)m * N + n] = v;
    }
  }
}

// ------------------- MFMA ff2: Y(D,T) = relu([seg2[sid[t]], ff[t]] @ Wsf + b)^T
// Tile: 64 dims (m) x 128 frames (n), K=1024 in chunks of 64.
__launch_bounds__(256)
__global__ void ff2m_k(const float* __restrict__ seg2, const float* __restrict__ ff,
                       const int* __restrict__ segid, const float* __restrict__ Wsf,
                       const float* __restrict__ bsf, float* __restrict__ Y, int S) {
  __shared__ __align__(16) _Float16 As16[64][72];    // [dim][k]
  __shared__ __align__(16) _Float16 Bs16[128][72];   // [frame][k]
  const int t0 = blockIdx.x * 128, nd0 = blockIdx.y * 64;
  const int tid = threadIdx.x;
  const int l = tid & 63, w = tid >> 6;
  const int wm = w & 1, wn = w >> 1;
  const int l31 = l & 31, q = l >> 5;
  f32x16 acc0, acc1;
#pragma unroll
  for (int i = 0; i < 16; i++) { acc0[i] = 0.f; acc1[i] = 0.f; }
  const int ak = tid >> 2, an0 = (tid & 3) * 16;     // Wsf: k-row, 16 dims each
  const int bt = tid >> 1, bk0 = (tid & 1) * 32;     // frames: 32 k each
  const int tglob = t0 + bt;
  int sid = segid[tglob];
  sid = sid < 0 ? 0 : (sid >= S ? S - 1 : sid);
  for (int kc = 0; kc < 1024; kc += 64) {
    __syncthreads();
    // stage Wsf[kc+ak][nd0 + an0 .. +15] -> As16[nd][k] (scatter)
#pragma unroll
    for (int nn = 0; nn < 16; nn += 4) {
      const float4 wv = *reinterpret_cast<const float4*>(Wsf + (size_t)(kc + ak) * 512 + nd0 + an0 + nn);
      As16[an0 + nn + 0][ak] = (_Float16)wv.x; As16[an0 + nn + 1][ak] = (_Float16)wv.y;
      As16[an0 + nn + 2][ak] = (_Float16)wv.z; As16[an0 + nn + 3][ak] = (_Float16)wv.w;
    }
    // stage input rows (concat): frame bt, k = kc+bk0 .. +31
    {
      const float* src = (kc < 512) ? (seg2 + (size_t)sid * 512 + kc + bk0)
                                    : (ff + (size_t)tglob * 512 + (kc - 512) + bk0);
#pragma unroll
      for (int kk = 0; kk < 32; kk += 4) {
        const float4 xv = *reinterpret_cast<const float4*>(src + kk);
        Bs16[bt][bk0 + kk + 0] = (_Float16)xv.x; Bs16[bt][bk0 + kk + 1] = (_Float16)xv.y;
        Bs16[bt][bk0 + kk + 2] = (_Float16)xv.z; Bs16[bt][bk0 + kk + 3] = (_Float16)xv.w;
      }
    }
    __syncthreads();
#pragma unroll
    for (int ks = 0; ks < 4; ks++) {
      const int k0 = ks * 16 + q * 8;
      const f16x8 a = *reinterpret_cast<const f16x8*>(&As16[wm * 32 + l31][k0]);
      const f16x8 b0 = *reinterpret_cast<const f16x8*>(&Bs16[wn * 64 + l31][k0]);
      acc0 = __builtin_amdgcn_mfma_f32_32x32x16_f16(a, b0, acc0, 0, 0, 0);
      const f16x8 b1 = *reinterpret_cast<const f16x8*>(&Bs16[wn * 64 + 32 + l31][k0]);
      acc1 = __builtin_amdgcn_mfma_f32_32x32x16_f16(a, b1, acc1, 0, 0, 0);
    }
  }
#pragma unroll
  for (int r = 0; r < 16; r++) {
    const int nd = nd0 + wm * 32 + (r & 3) + 8 * (r >> 2) + 4 * q;
    const float bb = bsf[nd];
    {
      const int t = t0 + wn * 64 + l31;
      Y[(size_t)nd * TT + t] = fmaxf(acc0[r] + bb, 0.f);
    }
    {
      const int t = t0 + wn * 64 + 32 + l31;
      Y[(size_t)nd * TT + t] = fmaxf(acc1[r] + bb, 0.f);
    }
  }
}

// --------------------------------------------------- MFMA TCN conv (fp16 in)
template<int NTAPS, int RELU, int RES>
__launch_bounds__(256)
__global__ void convm_k(const float* __restrict__ X, const float* __restrict__ W,
                        const float* __restrict__ bias, const float* __restrict__ Res,
                        float* __restrict__ Y, int dil) {
  const int d = (NTAPS == 3) ? dil : 0;
  const int width = 128 + 2 * d;
  __shared__ __align__(16) _Float16 Ws16[NTAPS][64][72];
  __shared__ __align__(16) _Float16 Xs16[192][72];
  const int t0 = blockIdx.x * 128, c0 = blockIdx.y * 64;
  const int tid = threadIdx.x;
  const int l = tid & 63, w = tid >> 6;
  const int wm = w & 1, wn = w >> 1;
  const int l31 = l & 31, q = l >> 5;
  f32x16 acc0, acc1;
#pragma unroll
  for (int i = 0; i < 16; i++) { acc0[i] = 0.f; acc1[i] = 0.f; }
  const int xk = tid >> 2;
  const int xu0 = tid & 3;
  for (int kc = 0; kc < 512; kc += 64) {
    __syncthreads();
    {
      const float* xr = X + (size_t)(kc + xk) * TT;
      for (int u = xu0; u < width; u += 4) {
        const int gt = t0 - d + u;
        const float v = (gt >= 0 && gt < TT) ? xr[gt] : 0.f;
        Xs16[u][xk] = (_Float16)v;
      }
    }
    if (NTAPS == 3) {
      // W chunk for channel row c is 192 CONTIGUOUS floats at
      // (c0+c)*1536 + kc*3  (f = i*3+tap). Vector-load + scatter.
      for (int e = tid; e < 64 * 48; e += 256) {
        const int c = e / 48;
        const int f0 = (e - c * 48) * 4;
        const float4 wv = *reinterpret_cast<const float4*>(
            W + (size_t)(c0 + c) * 1536 + (size_t)kc * 3 + f0);
        const float vv[4] = {wv.x, wv.y, wv.z, wv.w};
#pragma unroll
        for (int t = 0; t < 4; t++) {
          const int f = f0 + t;
          Ws16[f % 3][c][f / 3] = (_Float16)vv[t];
        }
      }
    } else {
      for (int e = tid; e < 1024; e += 256) {
        const int c = e >> 4, i0 = (e & 15) << 2;
        const float4 wv = *reinterpret_cast<const float4*>(W + (size_t)(c0 + c) * 512 + kc + i0);
        Ws16[0][c][i0 + 0] = (_Float16)wv.x; Ws16[0][c][i0 + 1] = (_Float16)wv.y;
        Ws16[0][c][i0 + 2] = (_Float16)wv.z; Ws16[0][c][i0 + 3] = (_Float16)wv.w;
      }
    }
    __syncthreads();
#pragma unroll
    for (int tap = 0; tap < NTAPS; tap++) {
#pragma unroll
      for (int ks = 0; ks < 4; ks++) {
        const int k0 = ks * 16 + q * 8;
        const f16x8 a = *reinterpret_cast<const f16x8*>(&Ws16[tap][wm * 32 + l31][k0]);
        const int row0 = wn * 64 + l31 + tap * d;
        const f16x8 b0 = *reinterpret_cast<const f16x8*>(&Xs16[row0][k0]);
        acc0 = __builtin_amdgcn_mfma_f32_32x32x16_f16(a, b0, acc0, 0, 0, 0);
        const f16x8 b1 = *reinterpret_cast<const f16x8*>(&Xs16[row0 + 32][k0]);
        acc1 = __builtin_amdgcn_mfma_f32_32x32x16_f16(a, b1, acc1, 0, 0, 0);
      }
    }
  }
#pragma unroll
  for (int r = 0; r < 16; r++) {
    const int m = wm * 32 + (r & 3) + 8 * (r >> 2) + 4 * q;
    const int c = c0 + m;
    const float bb = bias[c];
    {
      const int t = t0 + wn * 64 + l31;
      float v = acc0[r] + bb;
      if (RES) v += Res[(size_t)c * TT + t];
      if (RELU) v = fmaxf(v, 0.f);
      Y[(size_t)c * TT + t] = v;
    }
    {
      const int t = t0 + wn * 64 + 32 + l31;
      float v = acc1[r] + bb;
      if (RES) v += Res[(size_t)c * TT + t];
      if (RELU) v = fmaxf(v, 0.f);
      Y[(size_t)c * TT + t] = v;
    }
  }
}

// -------------------- tiled transpose (512,T) -> out (T,512) + f32 copy (T,512)
__launch_bounds__(256)
__global__ void temit_k(const float* __restrict__ Xin, float* __restrict__ outp,
                        float* __restrict__ Aout) {
  __shared__ float tile[32][33];
  const int t0 = blockIdx.x * 32, d0 = blockIdx.y * 32;
  const int lx = threadIdx.x & 31, ly = threadIdx.x >> 5;
#pragma unroll
  for (int r = 0; r < 4; r++)
    tile[ly + 8 * r][lx] = Xin[(size_t)(d0 + ly + 8 * r) * TT + t0 + lx];
  __syncthreads();
#pragma unroll
  for (int r = 0; r < 4; r++) {
    const int t = t0 + ly + 8 * r, dd = d0 + lx;
    const float v = tile[lx][ly + 8 * r];
    outp[(size_t)t * 512 + dd] = v;
    Aout[(size_t)t * 512 + dd] = v;
  }
}

// --------------------------- cosine sim, block per row (||v|| computed once)
__launch_bounds__(256)
__global__ void csim_k(const float* __restrict__ V, const float* __restrict__ text,
                       const float* __restrict__ tnorm, float* __restrict__ out) {
  __shared__ float vs[512];
  __shared__ float red[4];
  const int r = blockIdx.x, tid = threadIdx.x;
  const float a = V[(size_t)r * 512 + tid];
  const float b = V[(size_t)r * 512 + 256 + tid];
  vs[tid] = a; vs[tid + 256] = b;
  float ssp = a * a + b * b;
  for (int off = 32; off >= 1; off >>= 1) ssp += __shfl_xor(ssp, off);
  if ((tid & 63) == 0) red[tid >> 6] = ssp;
  __syncthreads();
  const float ss = red[0] + red[1] + red[2] + red[3];
  const int c = tid >> 3, p = tid & 7;
  const float* tr = text + (size_t)c * 512 + p * 64;
  const float* vr = vs + p * 64;
  float d = 0.f;
#pragma unroll
  for (int k = 0; k < 64; k++) d += vr[k] * tr[k];
  for (int off = 4; off >= 1; off >>= 1) d += __shfl_xor(d, off);
  if (p == 0) out[(size_t)r * 32 + c] = d / (sqrtf(ss) * tnorm[c]);
}

// ======================================================================= host
extern "C" void kernel_launch(void* const* d_in, const int* in_sizes, int n_in,
                              void* d_out, int out_size, void* d_ws, size_t ws_size,
                              hipStream_t stream) {
  const float* in_ff   = (const float*)d_in[0];
  const float* in_act  = (const float*)d_in[1];
  const float* in_fpos = (const float*)d_in[2];
  const float* in_apos = (const float*)d_in[3];
  const float* in_text = (const float*)d_in[4];
  const float* Wf2c = (const float*)d_in[5];  const float* bf2c = (const float*)d_in[6];
  const float* Wa2c = (const float*)d_in[7];  const float* ba2c = (const float*)d_in[8];
  const float* Ws2c = (const float*)d_in[9];  const float* bs2c = (const float*)d_in[10];
  const float* Wih_f = (const float*)d_in[11]; const float* Whh_f = (const float*)d_in[12];
  const float* bih_f = (const float*)d_in[13]; const float* bhh_f = (const float*)d_in[14];
  const float* Wih_b = (const float*)d_in[15]; const float* Whh_b = (const float*)d_in[16];
  const float* bih_b = (const float*)d_in[17]; const float* bhh_b = (const float*)d_in[18];
  const float* Wcomb = (const float*)d_in[19]; const float* bcomb = (const float*)d_in[20];
  const float* f2a_Wq = (const float*)d_in[21]; const float* f2a_Wk = (const float*)d_in[22];
  const float* f2a_Wv = (const float*)d_in[23]; const float* f2a_Wo = (const float*)d_in[24];
  const float* f2a_bo = (const float*)d_in[25];
  const float* ag_Wih = (const float*)d_in[26]; const float* ag_Whh = (const float*)d_in[27];
  const float* ag_bih = (const float*)d_in[28]; const float* ag_bhh = (const float*)d_in[29];
  const float* a2f_Wq = (const float*)d_in[30]; const float* a2f_Wk = (const float*)d_in[31];
  const float* a2f_Wv = (const float*)d_in[32]; const float* a2f_Wo = (const float*)d_in[33];
  const float* a2f_bo = (const float*)d_in[34];
  const float* Wsf = (const float*)d_in[35]; const float* bsf = (const float*)d_in[36];
  const float* tcn_inW = (const float*)d_in[37]; const float* tcn_inb = (const float*)d_in[38];
  const float* tcn_dW = (const float*)d_in[39]; const float* tcn_db = (const float*)d_in[40];
  const float* tcn_pW = (const float*)d_in[41]; const float* tcn_pb = (const float*)d_in[42];
  const float* tcn_outW = (const float*)d_in[43]; const float* tcn_outb = (const float*)d_in[44];

  int S = (out_size - (TT * DD + MM * DD + TT * CC + MM * CC)) / CC;
  if (S < 1) S = 1;
  if (S > TT) S = TT;
  const int Spad = (S + 63) & ~63;

  char* ws = (char*)d_ws;
  size_t off = 0;
  auto alloc = [&](size_t b) -> char* { char* p = ws + off; off += (b + 255) & ~(size_t)255; return p; };
  int* flgF = (int*)alloc((size_t)S * 64 * 4);
  int* flgB = (int*)alloc((size_t)S * 64 * 4);
  int* flgA = (int*)alloc((size_t)MM * 256 * 4);
  const size_t zero_words = off / 4;
  float* Mmat = (float*)alloc((size_t)512 * 32 * 4);
  float* bdot = (float*)alloc(32 * 4);
  const size_t BTD = (size_t)TT * DD * 4;
  float* bufA = (float*)alloc(BTD);
  float* bufB = (float*)alloc(BTD);
  int* pred    = (int*)alloc((size_t)TT * 4);
  int* segid   = (int*)alloc((size_t)TT * 4);
  int* starts  = (int*)alloc((size_t)TT * 4);
  int* centers = (int*)alloc((size_t)TT * 4);
  int* cnts    = (int*)alloc((size_t)TT * 4);
  float* tnorm = (float*)alloc(32 * 4);
  float* segmean = (float*)alloc((size_t)Spad * 512 * 4);
  float* gif  = (float*)alloc((size_t)Spad * 768 * 4);
  float* gib  = (float*)alloc((size_t)Spad * 768 * 4);
  float* hfb  = (float*)alloc((size_t)Spad * 256 * 4);
  float* hbb  = (float*)alloc((size_t)Spad * 256 * 4);
  float* acmb = (float*)alloc((size_t)Spad * 512 * 4);
  float* segc = (float*)alloc((size_t)Spad * 512 * 4);
  float* segpos = (float*)alloc((size_t)Spad * 512 * 4);
  float* kin  = (float*)alloc((size_t)Spad * 512 * 4);
  float* kf2a = (float*)alloc((size_t)Spad * 512 * 4);
  float* vf2a = (float*)alloc((size_t)Spad * 512 * 4);
  float* q2   = (float*)alloc((size_t)Spad * 512 * 4);
  float* att2 = (float*)alloc((size_t)Spad * 512 * 4);
  float* seg2 = (float*)alloc((size_t)Spad * 512 * 4);
  float* vseg = (float*)alloc((size_t)Spad * 512 * 4);
  float* pbuf = (float*)alloc((size_t)64 * Spad * 4);
  float* qin  = (float*)alloc((size_t)64 * 512 * 4);
  float* qf2a = (float*)alloc((size_t)64 * 512 * 4);
  float* att1 = (float*)alloc((size_t)64 * 512 * 4);
  float* af0  = (float*)alloc((size_t)64 * 512 * 4);
  float* aggi = (float*)alloc((size_t)64 * 1536 * 4);
  float* afg  = (float*)alloc((size_t)64 * 512 * 4);
  float* k2in = (float*)alloc((size_t)64 * 512 * 4);
  float* k2   = (float*)alloc((size_t)64 * 512 * 4);
  float* v2   = (float*)alloc((size_t)64 * 512 * 4);
  float* vaf  = (float*)alloc((size_t)64 * 512 * 4);
  (void)ws_size; (void)in_sizes; (void)n_in;

  float* outp = (float*)d_out;
  float* out_ff   = outp;
  float* out_af   = outp + (size_t)TT * DD;
  float* out_fsim = out_af + (size_t)MM * DD;
  float* out_asim = out_fsim + (size_t)TT * CC;
  float* out_ssim = out_asim + (size_t)MM * CC;

  auto GR = [](long n) { return (unsigned)((n + 255) / 256); };
  const unsigned Sg = (unsigned)(Spad / 64);

  zero_k<<<256, 256, 0, stream>>>((float*)d_ws, (long)zero_words);

  tnorm_k<<<1, 256, 0, stream>>>(in_text, tnorm);

  // segmentation: folded projection (ff @ (Wf2c @ t_hat)) -> argmax
  prepM_k<<<64, 256, 0, stream>>>(Wf2c, bf2c, in_text, tnorm, Mmat, bdot);
  fargmax_k<<<TT / 8, 256, 0, stream>>>(in_ff, Mmat, bdot, pred);
  segscan_k<<<1, 256, 0, stream>>>(pred, segid, starts, centers, cnts);
  segmean_k<<<GR((long)S * 512), 256, 0, stream>>>(in_ff, starts, cnts, segmean, S);

  // seg BiGRU (XCD-colocated mailbox: 32-block grid, 8 working)
  gemmm_k<<<dim3(6, Sg), 256, 0, stream>>>(segmean, Wih_f, bih_f, gif, Spad, 768, 512);
  gemmm_k<<<dim3(6, Sg), 256, 0, stream>>>(segmean, Wih_b, bih_b, gib, Spad, 768, 512);
  gru_seg_mb_k<<<32, 192, 0, stream>>>(gif, gib, Whh_f, bhh_f, Whh_b, bhh_b,
                                       hfb, hbb, S, flgF, flgB);
  acomb_k<<<GR((long)S * 512), 256, 0, stream>>>(hfb, hbb, acmb, S * 512);
  gemmm_k<<<dim3(4, Sg), 256, 0, stream>>>(acmb, Wcomb, bcomb, segc, Spad, 512, 512);
  gatherpos_k<<<GR((long)S * 512), 256, 0, stream>>>(in_fpos, centers, segpos, S * 512);

  // f2a attention (actions query segments)
  addff_k<<<GR(64 * 512), 256, 0, stream>>>(in_act, in_apos, qin, 64 * 512);
  addff_k<<<GR((long)S * 512), 256, 0, stream>>>(segc, segpos, kin, S * 512);
  gemmm_k<<<dim3(4, 1), 256, 0, stream>>>(qin, f2a_Wq, nullptr, qf2a, 64, 512, 512);
  gemmm_k<<<dim3(4, Sg), 256, 0, stream>>>(kin, f2a_Wk, nullptr, kf2a, Spad, 512, 512);
  gemmm_k<<<dim3(4, Sg), 256, 0, stream>>>(segc, f2a_Wv, nullptr, vf2a, Spad, 512, 512);
  nlogit_k<<<GR((long)64 * S), 256, 0, stream>>>(qf2a, kf2a, pbuf, 64, S);
  nsoft_k<<<1, 256, 0, stream>>>(pbuf, 64, S);
  nav_k<<<GR(64 * 512), 256, 0, stream>>>(pbuf, vf2a, att1, 64, S);
  gemmm_k<<<dim3(4, 1), 256, 0, stream>>>(att1, f2a_Wo, f2a_bo, af0, 64, 512, 512);

  // action GRU (XCD-colocated mailbox: 128-block grid, 16 working)
  gemmm_k<<<dim3(12, 1), 256, 0, stream>>>(af0, ag_Wih, ag_bih, aggi, 64, 1536, 512);
  gru_act_mb_k<<<128, 128, 0, stream>>>(aggi, ag_Whh, ag_bhh, afg, MM, flgA);
  copy_k<<<GR(64 * 512), 256, 0, stream>>>(afg, out_af, 64 * 512);

  // a2f attention (segments query actions)
  addff_k<<<GR(64 * 512), 256, 0, stream>>>(afg, in_apos, k2in, 64 * 512);
  gemmm_k<<<dim3(4, Sg), 256, 0, stream>>>(kin, a2f_Wq, nullptr, q2, Spad, 512, 512);
  gemmm_k<<<dim3(4, 1), 256, 0, stream>>>(k2in, a2f_Wk, nullptr, k2, 64, 512, 512);
  gemmm_k<<<dim3(4, 1), 256, 0, stream>>>(afg, a2f_Wv, nullptr, v2, 64, 512, 512);
  nlogit_k<<<GR((long)S * 64), 256, 0, stream>>>(q2, k2, pbuf, S, 64);
  nsoft_k<<<GR(S), 256, 0, stream>>>(pbuf, S, 64);
  nav_k<<<GR((long)S * 512), 256, 0, stream>>>(pbuf, v2, att2, S, 64);
  gemmm_k<<<dim3(4, Sg), 256, 0, stream>>>(att2, a2f_Wo, a2f_bo, seg2, Spad, 512, 512);

  // frame fusion + TCN (MFMA), ping-pong bufA <-> bufB as (D,T)
  ff2m_k<<<dim3(64, 8), 256, 0, stream>>>(seg2, in_ff, segid, Wsf, bsf, bufA, S);
  convm_k<1, 0, 0><<<dim3(64, 8), 256, 0, stream>>>(bufA, tcn_inW, tcn_inb, nullptr, bufB, 1);
  for (int l = 0; l < 6; l++) {
    convm_k<3, 1, 0><<<dim3(64, 8), 256, 0, stream>>>(
        bufB, tcn_dW + (size_t)l * 512 * 512 * 3, tcn_db + (size_t)l * 512, nullptr, bufA, 1 << l);
    convm_k<1, 0, 1><<<dim3(64, 8), 256, 0, stream>>>(
        bufA, tcn_pW + (size_t)l * 512 * 512, tcn_pb + (size_t)l * 512, bufB, bufB, 1);
  }
  convm_k<1, 0, 0><<<dim3(64, 8), 256, 0, stream>>>(bufB, tcn_outW, tcn_outb, nullptr, bufA, 1);
  temit_k<<<dim3(256, 16), 256, 0, stream>>>(bufA, out_ff, bufB);

  // similarity heads
  gemmm_k<<<dim3(4, 128), 256, 0, stream>>>(bufB, Wf2c, bf2c, bufA, TT, 512, 512);
  csim_k<<<TT, 256, 0, stream>>>(bufA, in_text, tnorm, out_fsim);
  gemmm_k<<<dim3(4, 1), 256, 0, stream>>>(afg, Wa2c, ba2c, vaf, 64, 512, 512);
  csim_k<<<64, 256, 0, stream>>>(vaf, in_text, tnorm, out_asim);
  gemmm_k<<<dim3(4, Sg), 256, 0, stream>>>(seg2, Ws2c, bs2c, vseg, Spad, 512, 512);
  csim_k<<<(unsigned)S, 256, 0, stream>>>(vseg, in_text, tnorm, out_ssim);
}

// Round 11
// 3965.383 us; speedup vs baseline: 1.1104x; 1.1104x over previous
//
#include <hip/hip_runtime.h>
#include <cstdint>
#include <cstddef>

__device__ __forceinline__ float sigf(float x) { return 1.f / (1.f + expf(-x)); }

__device__ __forceinline__ unsigned packh(float a, float b) {
  union { unsigned u; _Float16 h[2]; } cv;
  cv.h[0] = (_Float16)a; cv.h[1] = (_Float16)b; return cv.u;
}
__device__ __forceinline__ float2 uph(unsigned u) {
  union { unsigned uu; _Float16 h[2]; } cv; cv.uu = u;
  return make_float2((float)cv.h[0], (float)cv.h[1]);
}

typedef _Float16 f16x8 __attribute__((ext_vector_type(8)));
typedef float f32x16 __attribute__((ext_vector_type(16)));

static constexpr int TT = 8192;
static constexpr int MM = 64;
static constexpr int CC = 32;
static constexpr int DD = 512;
static constexpr unsigned GUARD_MAX = 1u << 30;

// --------------------------------------------------------------- NaN filling
// h mailboxes are written exactly once per (step,slot); readers poll the data
// itself (v!=v) instead of a separate flag -> one less serialized round trip.
__global__ void nanfill_k(float* __restrict__ p, long n) {
  long i = (long)blockIdx.x * 256 + threadIdx.x;
  long stride = (long)gridDim.x * 256;
  const float qnan = __int_as_float(0x7fc00000);
  for (; i < n; i += stride) p[i] = qnan;
}

// ---------------------------------------------------------------- elementwise
__global__ void copy_k(const float* __restrict__ a, float* __restrict__ o, int n) {
  int i = blockIdx.x * 256 + threadIdx.x;
  if (i < n) o[i] = a[i];
}
__global__ void addff_k(const float* __restrict__ a, const float* __restrict__ b, float* __restrict__ o, int n) {
  int i = blockIdx.x * 256 + threadIdx.x;
  if (i < n) o[i] = a[i] + b[i];
}
__global__ void acomb_k(const float* __restrict__ hf, const float* __restrict__ hb, float* __restrict__ o, int n) {
  int i = blockIdx.x * 256 + threadIdx.x;
  if (i >= n) return;
  int s = i >> 9, j = i & 511;
  float v = (j < 256) ? hf[(size_t)s * 256 + j] : hb[(size_t)s * 256 + (j - 256)];
  o[i] = fmaxf(v, 0.f);
}
__global__ void gatherpos_k(const float* __restrict__ fpos, const int* __restrict__ centers,
                            float* __restrict__ segpos, int n) {
  int i = blockIdx.x * 256 + threadIdx.x;
  if (i >= n) return;
  int s = i >> 9, dd = i & 511;
  int ct = centers[s];
  ct = ct < 0 ? 0 : (ct > TT - 1 ? TT - 1 : ct);
  segpos[i] = fpos[(size_t)ct * 512 + dd];
}

// ---------------------------------------------------------------- text norms
__global__ void tnorm_k(const float* __restrict__ text, float* __restrict__ tnorm) {
  int c = blockIdx.x * 256 + threadIdx.x;
  if (c >= 32) return;
  float s = 0.f;
  for (int dd = 0; dd < 512; dd++) { float v = text[(size_t)c * 512 + dd]; s += v * v; }
  tnorm[c] = sqrtf(s);
}

// ---------------- fold argmax projection: M[k][c] = Wf2c[k,:]·(text_c/|t_c|)
__global__ void prepM_k(const float* __restrict__ W, const float* __restrict__ b,
                        const float* __restrict__ text, const float* __restrict__ tnorm,
                        float* __restrict__ M, float* __restrict__ bdot) {
  int idx = blockIdx.x * 256 + threadIdx.x;
  if (idx < 512 * 32) {
    int k = idx >> 5, c = idx & 31;
    const float* wr = W + (size_t)k * 512;
    const float* tr = text + (size_t)c * 512;
    float s = 0.f;
    for (int dd = 0; dd < 512; dd++) s += wr[dd] * tr[dd];
    M[idx] = s / tnorm[c];
  }
  if (idx < 32) {
    const float* tr = text + (size_t)idx * 512;
    float s = 0.f;
    for (int dd = 0; dd < 512; dd++) s += b[dd] * tr[dd];
    bdot[idx] = s / tnorm[idx];
  }
}

// 8 rows/block; lane c of each 32-group owns class c; shfl-argmax (min idx tie)
__launch_bounds__(256)
__global__ void fargmax_k(const float* __restrict__ ff, const float* __restrict__ M,
                          const float* __restrict__ bdot, int* __restrict__ pred) {
  const int r = blockIdx.x * 8 + (threadIdx.x >> 5);
  const int c = threadIdx.x & 31;
  const float* fr = ff + (size_t)r * 512;
  float acc = bdot[c];
  for (int k = 0; k < 512; k++) acc += fr[k] * M[k * 32 + c];
  float best = acc; int bidx = c;
  for (int off = 16; off >= 1; off >>= 1) {
    const float ov = __shfl_xor(best, off);
    const int oi = __shfl_xor(bidx, off);
    if (ov > best || (ov == best && oi < bidx)) { best = ov; bidx = oi; }
  }
  if (c == 0) pred[r] = bidx;
}

// ---------------------------------------------------- naive attention pieces
__global__ void nlogit_k(const float* __restrict__ Q, const float* __restrict__ Kk,
                         float* __restrict__ L, int NY, int NX) {
  int idx = blockIdx.x * 256 + threadIdx.x;
  if (idx >= NY * NX) return;
  int y = idx / NX, x = idx - y * NX;
  const float* qr = Q + (size_t)y * 512;
  const float* kr = Kk + (size_t)x * 512;
  float d = 0.f;
  for (int k = 0; k < 512; k++) d += qr[k] * kr[k];
  L[idx] = d * 0.044194173824159216f;
}
__global__ void nsoft_k(float* __restrict__ L, int NY, int NX) {
  int y = blockIdx.x * 256 + threadIdx.x;
  if (y >= NY) return;
  float* row = L + (size_t)y * NX;
  float m = row[0];
  for (int x = 1; x < NX; x++) m = fmaxf(m, row[x]);
  float s = 0.f;
  for (int x = 0; x < NX; x++) { float p = expf(row[x] - m); row[x] = p; s += p; }
  const float inv = 1.f / s;
  for (int x = 0; x < NX; x++) row[x] *= inv;
}
__global__ void nav_k(const float* __restrict__ P, const float* __restrict__ V,
                      float* __restrict__ O, int NY, int NX) {
  int idx = blockIdx.x * 256 + threadIdx.x;
  if (idx >= NY * 512) return;
  int y = idx >> 9, dd = idx & 511;
  const float* pr = P + (size_t)y * NX;
  float o = 0.f;
  for (int x = 0; x < NX; x++) o += pr[x] * V[(size_t)x * 512 + dd];
  O[idx] = o;
}

// ------------------------------- parallel run-length segmentation (one block)
__global__ void segscan_k(const int* __restrict__ pred, int* __restrict__ segid,
                          int* __restrict__ starts, int* __restrict__ centers,
                          int* __restrict__ cnts) {
  __shared__ int base[256];
  __shared__ int SS;
  const int tid = threadIdx.x;
  int lc = 0;
  unsigned flags = 0;
  int prev = (tid > 0) ? pred[tid * 32 - 1] : 0;
  for (int i = 0; i < 32; i++) {
    const int t = tid * 32 + i;
    const int cur = pred[t];
    const int c = (t > 0) && (cur != prev);
    prev = cur;
    flags |= ((unsigned)c) << i;
    lc += c;
  }
  base[tid] = lc;
  __syncthreads();
  if (tid == 0) {
    int run = 0;
    for (int i = 0; i < 256; i++) { const int v = base[i]; base[i] = run; run += v; }
    SS = run + 1;
  }
  __syncthreads();
  int b = base[tid];
  for (int i = 0; i < 32; i++) {
    const int t = tid * 32 + i;
    if ((flags >> i) & 1u) { b++; starts[b] = t; }
    segid[t] = b;
  }
  if (tid == 0) starts[0] = 0;
  __threadfence_block();
  __syncthreads();
  const int S = SS;
  for (int s = tid; s < TT; s += 256) {
    if (s < S) {
      const int e = (s == S - 1) ? (TT - 1) : (starts[s + 1] - 1);
      centers[s] = (starts[s] + e) >> 1;
      cnts[s] = e - starts[s] + 1;
    } else {
      starts[s] = 0; cnts[s] = 1; centers[s] = 0;
    }
  }
}

// ---------------------------------------------------------- segment mean pool
__global__ void segmean_k(const float* __restrict__ ff, const int* __restrict__ starts,
                          const int* __restrict__ cnts, float* __restrict__ segmean, int S) {
  int idx = blockIdx.x * 256 + threadIdx.x;
  if (idx >= S * 512) return;
  int s = idx >> 9, dd = idx & 511;
  int st = starts[s], n = cnts[s];
  st = st < 0 ? 0 : (st > TT - 1 ? TT - 1 : st);
  n = n < 1 ? 1 : n;
  if (st + n > TT) n = TT - st;
  float a = 0.f;
  for (int t = st; t < st + n; t++) a += ff[(size_t)t * 512 + dd];
  segmean[idx] = a / (float)n;
}

// ------------------- multi-block bidirectional seg GRU (H=256), LDS weights
// gi prefetched into registers. r0-verified mailbox compute core, FROZEN.
// r11 protocol: NO flags -- h buffer is NaN-prefilled, writers store data
// relaxed, readers poll the datum itself (v!=v). A non-NaN load IS the value
// (per-location monotonic write-once), removing the flag release/observe hop.
// [r10 evidence: XCD colocation moved mailbox traffic into L2 (FETCH -38%)
// with NO time gain -> cost is serialized protocol hops, not memory tier.]
__launch_bounds__(192)
__global__ void gru_seg_mb_k(const float* __restrict__ gi_f, const float* __restrict__ gi_b,
                             const float* __restrict__ Whh_f, const float* __restrict__ bhh_f,
                             const float* __restrict__ Whh_b, const float* __restrict__ bhh_b,
                             float* __restrict__ hf, float* __restrict__ hb, int S) {
  const int dir = blockIdx.x >> 2;
  const int part = blockIdx.x & 3;
  const float* gi = dir ? gi_b : gi_f;
  const float* Whh = dir ? Whh_b : Whh_f;
  const float* bhh = dir ? bhh_b : bhh_f;
  float* ho = dir ? hb : hf;
  const int tid = threadIdx.x;
  const int h0 = part * 64;
  const int grp = tid >> 6;
  const int jj = tid & 63;
  const int j = grp * 256 + h0 + jj;
  __shared__ __align__(16) unsigned wlds[128 * 192];
  __shared__ __align__(16) unsigned hpk[128];
  __shared__ float hcur[256];
  __shared__ float rbuf[64], zbuf[64], gnbuf[64];
  for (int e = tid; e < 128 * 192; e += 192) {
    const int q = e / 768, rem = e % 768;
    const int g = rem >> 2, r = rem & 3;
    const int i2 = q * 4 + r;
    const int gg = (g >> 6) * 256 + h0 + (g & 63);
    wlds[e] = packh(Whh[(size_t)(2 * i2) * 768 + gg], Whh[(size_t)(2 * i2 + 1) * 768 + gg]);
  }
  for (int e = tid; e < 128; e += 192) hpk[e] = 0u;
  for (int e = tid; e < 256; e += 192) hcur[e] = 0.f;
  const float bj = bhh[j];
  __syncthreads();
  const uint4* hp4 = reinterpret_cast<const uint4*>(hpk);
  const uint4* wp4 = reinterpret_cast<const uint4*>(wlds);
  // prefetch step 0 gi
  int s = dir ? (S - 1) : 0;
  float g_j = gi[(size_t)s * 768 + j];
  float g_n = (tid < 64) ? gi[(size_t)s * 768 + 512 + h0 + tid] : 0.f;
  for (int step = 0; step < S; step++) {
    float a0 = 0.f, a1 = 0.f, a2 = 0.f, a3 = 0.f;
#pragma unroll 8
    for (int q = 0; q < 32; q++) {
      const uint4 h4 = hp4[q];
      const uint4 w4 = wp4[q * 192 + tid];
      const float2 hh0 = uph(h4.x), hh1 = uph(h4.y), hh2 = uph(h4.z), hh3 = uph(h4.w);
      const float2 ww0 = uph(w4.x), ww1 = uph(w4.y), ww2 = uph(w4.z), ww3 = uph(w4.w);
      a0 += hh0.x * ww0.x + hh0.y * ww0.y;
      a1 += hh1.x * ww1.x + hh1.y * ww1.y;
      a2 += hh2.x * ww2.x + hh2.y * ww2.y;
      a3 += hh3.x * ww3.x + hh3.y * ww3.y;
    }
    const float gh = bj + (a0 + a1) + (a2 + a3);
    if (grp == 0)      rbuf[jj] = sigf(g_j + gh);
    else if (grp == 1) zbuf[jj] = sigf(g_j + gh);
    else               gnbuf[jj] = gh;
    __syncthreads();
    if (tid < 64) {
      const float nval = tanhf(g_n + rbuf[tid] * gnbuf[tid]);
      const float hn = (1.f - zbuf[tid]) * nval + zbuf[tid] * hcur[h0 + tid];
      __hip_atomic_store(&ho[(size_t)s * 256 + h0 + tid], hn,
                         __ATOMIC_RELAXED, __HIP_MEMORY_SCOPE_AGENT);
    }
    // prefetch next-step gi (overlaps peers' stores landing)
    const int sn = dir ? (s - 1) : (s + 1);
    if (step + 1 < S) {
      g_j = gi[(size_t)sn * 768 + j];
      if (tid < 64) g_n = gi[(size_t)sn * 768 + 512 + h0 + tid];
    }
    __syncthreads();
    // poll the data itself: non-NaN load IS the peer's value
    for (int e = tid; e < 256; e += 192) {
      float v = __hip_atomic_load(&ho[(size_t)s * 256 + e],
                                  __ATOMIC_RELAXED, __HIP_MEMORY_SCOPE_AGENT);
      unsigned guard = 0;
      while (v != v && ++guard < GUARD_MAX) {
        __builtin_amdgcn_s_sleep(1);
        v = __hip_atomic_load(&ho[(size_t)s * 256 + e],
                              __ATOMIC_RELAXED, __HIP_MEMORY_SCOPE_AGENT);
      }
      hcur[e] = v;
    }
    __syncthreads();
    for (int e = tid; e < 128; e += 192) hpk[e] = packh(hcur[2 * e], hcur[2 * e + 1]);
    __syncthreads();
    s = sn;
  }
}

// ------------------------- multi-block action GRU (H=512), LDS weights
// Same NaN-poll mailbox protocol (r11).
__launch_bounds__(128)
__global__ void gru_act_mb_k(const float* __restrict__ gi, const float* __restrict__ Whh,
                             const float* __restrict__ bhh, float* __restrict__ hout,
                             int steps) {
  const int part = blockIdx.x;
  const int tid = threadIdx.x;
  const int h0 = part * 32;
  const int grp = tid >> 5;
  const int jj = tid & 31;
  const bool act = (tid < 96);
  const int j = act ? (grp * 512 + h0 + jj) : 0;
  __shared__ __align__(16) unsigned wlds[256 * 96];
  __shared__ __align__(16) unsigned hpk[256];
  __shared__ float hcur[512];
  __shared__ float rbuf[32], zbuf[32], gnbuf[32];
  for (int e = tid; e < 256 * 96; e += 128) {
    const int q = e / 384, rem = e % 384;
    const int g = rem >> 2, r = rem & 3;
    const int i2 = q * 4 + r;
    const int gg = (g >> 5) * 512 + h0 + (g & 31);
    wlds[e] = packh(Whh[(size_t)(2 * i2) * 1536 + gg], Whh[(size_t)(2 * i2 + 1) * 1536 + gg]);
  }
  for (int e = tid; e < 256; e += 128) hpk[e] = 0u;
  for (int e = tid; e < 512; e += 128) hcur[e] = 0.f;
  const float bj = act ? bhh[j] : 0.f;
  __syncthreads();
  const uint4* hp4 = reinterpret_cast<const uint4*>(hpk);
  const uint4* wp4 = reinterpret_cast<const uint4*>(wlds);
  float g_j = act ? gi[j] : 0.f;
  float g_n = (tid < 32) ? gi[1024 + h0 + tid] : 0.f;
  for (int step = 0; step < steps; step++) {
    if (act) {
      float a0 = 0.f, a1 = 0.f, a2 = 0.f, a3 = 0.f;
#pragma unroll 8
      for (int q = 0; q < 64; q++) {
        const uint4 h4 = hp4[q];
        const uint4 w4 = wp4[q * 96 + tid];
        const float2 hh0 = uph(h4.x), hh1 = uph(h4.y), hh2 = uph(h4.z), hh3 = uph(h4.w);
        const float2 ww0 = uph(w4.x), ww1 = uph(w4.y), ww2 = uph(w4.z), ww3 = uph(w4.w);
        a0 += hh0.x * ww0.x + hh0.y * ww0.y;
        a1 += hh1.x * ww1.x + hh1.y * ww1.y;
        a2 += hh2.x * ww2.x + hh2.y * ww2.y;
        a3 += hh3.x * ww3.x + hh3.y * ww3.y;
      }
      const float gh = bj + (a0 + a1) + (a2 + a3);
      if (grp == 0)      rbuf[jj] = sigf(g_j + gh);
      else if (grp == 1) zbuf[jj] = sigf(g_j + gh);
      else               gnbuf[jj] = gh;
    }
    __syncthreads();
    if (tid < 32) {
      const float nval = tanhf(g_n + rbuf[tid] * gnbuf[tid]);
      const float hn = (1.f - zbuf[tid]) * nval + zbuf[tid] * hcur[h0 + tid];
      __hip_atomic_store(&hout[(size_t)step * 512 + h0 + tid], hn,
                         __ATOMIC_RELAXED, __HIP_MEMORY_SCOPE_AGENT);
    }
    if (step + 1 < steps) {
      if (act) g_j = gi[(size_t)(step + 1) * 1536 + j];
      if (tid < 32) g_n = gi[(size_t)(step + 1) * 1536 + 1024 + h0 + tid];
    }
    __syncthreads();
    for (int e = tid; e < 512; e += 128) {
      float v = __hip_atomic_load(&hout[(size_t)step * 512 + e],
                                  __ATOMIC_RELAXED, __HIP_MEMORY_SCOPE_AGENT);
      unsigned guard = 0;
      while (v != v && ++guard < GUARD_MAX) {
        __builtin_amdgcn_s_sleep(1);
        v = __hip_atomic_load(&hout[(size_t)step * 512 + e],
                              __ATOMIC_RELAXED, __HIP_MEMORY_SCOPE_AGENT);
      }
      hcur[e] = v;
    }
    __syncthreads();
    for (int e = tid; e < 256; e += 128) hpk[e] = packh(hcur[2 * e], hcur[2 * e + 1]);
    __syncthreads();
  }
}

// ------------------------------------------------ MFMA GEMM (fp16 staged)
// C[M,N] = A[M,K] @ B[K,N] + bias.  Tile M64 x N128, K-chunk 64.
__launch_bounds__(256)
__global__ void gemmm_k(const float* __restrict__ A, const float* __restrict__ B,
                        const float* __restrict__ bias, float* __restrict__ C,
                        int M, int N, int K) {
  __shared__ __align__(16) _Float16 As16[64][72];
  __shared__ __align__(16) _Float16 Bs16[128][72];
  const int n0 = blockIdx.x * 128, m0 = blockIdx.y * 64;
  const int tid = threadIdx.x;
  const int l = tid & 63, w = tid >> 6;
  const int wm = w & 1, wn = w >> 1;
  const int l31 = l & 31, q = l >> 5;
  f32x16 acc0, acc1;
#pragma unroll
  for (int i = 0; i < 16; i++) { acc0[i] = 0.f; acc1[i] = 0.f; }
  const int am = tid >> 2, ak0 = (tid & 3) * 16;
  const int bk = tid >> 2, bn0 = (tid & 3) * 32;
  for (int kc = 0; kc < K; kc += 64) {
    __syncthreads();
#pragma unroll
    for (int kk = 0; kk < 16; kk += 4) {
      const float4 av = *reinterpret_cast<const float4*>(A + (size_t)(m0 + am) * K + kc + ak0 + kk);
      As16[am][ak0 + kk + 0] = (_Float16)av.x; As16[am][ak0 + kk + 1] = (_Float16)av.y;
      As16[am][ak0 + kk + 2] = (_Float16)av.z; As16[am][ak0 + kk + 3] = (_Float16)av.w;
    }
#pragma unroll
    for (int nn = 0; nn < 32; nn += 4) {
      const float4 bv = *reinterpret_cast<const float4*>(B + (size_t)(kc + bk) * N + n0 + bn0 + nn);
      Bs16[bn0 + nn + 0][bk] = (_Float16)bv.x; Bs16[bn0 + nn + 1][bk] = (_Float16)bv.y;
      Bs16[bn0 + nn + 2][bk] = (_Float16)bv.z; Bs16[bn0 + nn + 3][bk] = (_Float16)bv.w;
    }
    __syncthreads();
#pragma unroll
    for (int ks = 0; ks < 4; ks++) {
      const int k0 = ks * 16 + q * 8;
      const f16x8 a = *reinterpret_cast<const f16x8*>(&As16[wm * 32 + l31][k0]);
      const f16x8 b0 = *reinterpret_cast<const f16x8*>(&Bs16[wn * 64 + l31][k0]);
      acc0 = __builtin_amdgcn_mfma_f32_32x32x16_f16(a, b0, acc0, 0, 0, 0);
      const f16x8 b1 = *reinterpret_cast<const f16x8*>(&Bs16[wn * 64 + 32 + l31][k0]);
      acc1 = __builtin_amdgcn_mfma_f32_32x32x16_f16(a, b1, acc1, 0, 0, 0);
    }
  }
#pragma unroll
  for (int r = 0; r < 16; r++) {
    const int m = m0 + wm * 32 + (r & 3) + 8 * (r >> 2) + 4 * q;
    {
      const int n = n0 + wn * 64 + l31;
      float v = acc0[r];
      if (bias) v += bias[n];
      C[(size_t)m * N + n] = v;
    }
    {
      const int n = n0 + wn * 64 + 32 + l31;
      float v = acc1[r];
      if (bias) v += bias[n];
      C[(size_t)m * N + n] = v;
    }
  }
}

// ------------------- MFMA ff2: Y(D,T) = relu([seg2[sid[t]], ff[t]] @ Wsf + b)^T
__launch_bounds__(256)
__global__ void ff2m_k(const float* __restrict__ seg2, const float* __restrict__ ff,
                       const int* __restrict__ segid, const float* __restrict__ Wsf,
                       const float* __restrict__ bsf, float* __restrict__ Y, int S) {
  __shared__ __align__(16) _Float16 As16[64][72];    // [dim][k]
  __shared__ __align__(16) _Float16 Bs16[128][72];   // [frame][k]
  const int t0 = blockIdx.x * 128, nd0 = blockIdx.y * 64;
  const int tid = threadIdx.x;
  const int l = tid & 63, w = tid >> 6;
  const int wm = w & 1, wn = w >> 1;
  const int l31 = l & 31, q = l >> 5;
  f32x16 acc0, acc1;
#pragma unroll
  for (int i = 0; i < 16; i++) { acc0[i] = 0.f; acc1[i] = 0.f; }
  const int ak = tid >> 2, an0 = (tid & 3) * 16;
  const int bt = tid >> 1, bk0 = (tid & 1) * 32;
  const int tglob = t0 + bt;
  int sid = segid[tglob];
  sid = sid < 0 ? 0 : (sid >= S ? S - 1 : sid);
  for (int kc = 0; kc < 1024; kc += 64) {
    __syncthreads();
#pragma unroll
    for (int nn = 0; nn < 16; nn += 4) {
      const float4 wv = *reinterpret_cast<const float4*>(Wsf + (size_t)(kc + ak) * 512 + nd0 + an0 + nn);
      As16[an0 + nn + 0][ak] = (_Float16)wv.x; As16[an0 + nn + 1][ak] = (_Float16)wv.y;
      As16[an0 + nn + 2][ak] = (_Float16)wv.z; As16[an0 + nn + 3][ak] = (_Float16)wv.w;
    }
    {
      const float* src = (kc < 512) ? (seg2 + (size_t)sid * 512 + kc + bk0)
                                    : (ff + (size_t)tglob * 512 + (kc - 512) + bk0);
#pragma unroll
      for (int kk = 0; kk < 32; kk += 4) {
        const float4 xv = *reinterpret_cast<const float4*>(src + kk);
        Bs16[bt][bk0 + kk + 0] = (_Float16)xv.x; Bs16[bt][bk0 + kk + 1] = (_Float16)xv.y;
        Bs16[bt][bk0 + kk + 2] = (_Float16)xv.z; Bs16[bt][bk0 + kk + 3] = (_Float16)xv.w;
      }
    }
    __syncthreads();
#pragma unroll
    for (int ks = 0; ks < 4; ks++) {
      const int k0 = ks * 16 + q * 8;
      const f16x8 a = *reinterpret_cast<const f16x8*>(&As16[wm * 32 + l31][k0]);
      const f16x8 b0 = *reinterpret_cast<const f16x8*>(&Bs16[wn * 64 + l31][k0]);
      acc0 = __builtin_amdgcn_mfma_f32_32x32x16_f16(a, b0, acc0, 0, 0, 0);
      const f16x8 b1 = *reinterpret_cast<const f16x8*>(&Bs16[wn * 64 + 32 + l31][k0]);
      acc1 = __builtin_amdgcn_mfma_f32_32x32x16_f16(a, b1, acc1, 0, 0, 0);
    }
  }
#pragma unroll
  for (int r = 0; r < 16; r++) {
    const int nd = nd0 + wm * 32 + (r & 3) + 8 * (r >> 2) + 4 * q;
    const float bb = bsf[nd];
    {
      const int t = t0 + wn * 64 + l31;
      Y[(size_t)nd * TT + t] = fmaxf(acc0[r] + bb, 0.f);
    }
    {
      const int t = t0 + wn * 64 + 32 + l31;
      Y[(size_t)nd * TT + t] = fmaxf(acc1[r] + bb, 0.f);
    }
  }
}

// --------------------------------------------------- MFMA TCN conv (fp16 in)
template<int NTAPS, int RELU, int RES>
__launch_bounds__(256)
__global__ void convm_k(const float* __restrict__ X, const float* __restrict__ W,
                        const float* __restrict__ bias, const float* __restrict__ Res,
                        float* __restrict__ Y, int dil) {
  const int d = (NTAPS == 3) ? dil : 0;
  const int width = 128 + 2 * d;
  __shared__ __align__(16) _Float16 Ws16[NTAPS][64][72];
  __shared__ __align__(16) _Float16 Xs16[192][72];
  const int t0 = blockIdx.x * 128, c0 = blockIdx.y * 64;
  const int tid = threadIdx.x;
  const int l = tid & 63, w = tid >> 6;
  const int wm = w & 1, wn = w >> 1;
  const int l31 = l & 31, q = l >> 5;
  f32x16 acc0, acc1;
#pragma unroll
  for (int i = 0; i < 16; i++) { acc0[i] = 0.f; acc1[i] = 0.f; }
  const int xk = tid >> 2;
  const int xu0 = tid & 3;
  for (int kc = 0; kc < 512; kc += 64) {
    __syncthreads();
    {
      const float* xr = X + (size_t)(kc + xk) * TT;
      for (int u = xu0; u < width; u += 4) {
        const int gt = t0 - d + u;
        const float v = (gt >= 0 && gt < TT) ? xr[gt] : 0.f;
        Xs16[u][xk] = (_Float16)v;
      }
    }
    if (NTAPS == 3) {
      // W chunk for channel row c is 192 CONTIGUOUS floats at
      // (c0+c)*1536 + kc*3  (f = i*3+tap). Vector-load + scatter.
      for (int e = tid; e < 64 * 48; e += 256) {
        const int c = e / 48;
        const int f0 = (e - c * 48) * 4;
        const float4 wv = *reinterpret_cast<const float4*>(
            W + (size_t)(c0 + c) * 1536 + (size_t)kc * 3 + f0);
        const float vv[4] = {wv.x, wv.y, wv.z, wv.w};
#pragma unroll
        for (int t = 0; t < 4; t++) {
          const int f = f0 + t;
          Ws16[f % 3][c][f / 3] = (_Float16)vv[t];
        }
      }
    } else {
      for (int e = tid; e < 1024; e += 256) {
        const int c = e >> 4, i0 = (e & 15) << 2;
        const float4 wv = *reinterpret_cast<const float4*>(W + (size_t)(c0 + c) * 512 + kc + i0);
        Ws16[0][c][i0 + 0] = (_Float16)wv.x; Ws16[0][c][i0 + 1] = (_Float16)wv.y;
        Ws16[0][c][i0 + 2] = (_Float16)wv.z; Ws16[0][c][i0 + 3] = (_Float16)wv.w;
      }
    }
    __syncthreads();
#pragma unroll
    for (int tap = 0; tap < NTAPS; tap++) {
#pragma unroll
      for (int ks = 0; ks < 4; ks++) {
        const int k0 = ks * 16 + q * 8;
        const f16x8 a = *reinterpret_cast<const f16x8*>(&Ws16[tap][wm * 32 + l31][k0]);
        const int row0 = wn * 64 + l31 + tap * d;
        const f16x8 b0 = *reinterpret_cast<const f16x8*>(&Xs16[row0][k0]);
        acc0 = __builtin_amdgcn_mfma_f32_32x32x16_f16(a, b0, acc0, 0, 0, 0);
        const f16x8 b1 = *reinterpret_cast<const f16x8*>(&Xs16[row0 + 32][k0]);
        acc1 = __builtin_amdgcn_mfma_f32_32x32x16_f16(a, b1, acc1, 0, 0, 0);
      }
    }
  }
#pragma unroll
  for (int r = 0; r < 16; r++) {
    const int m = wm * 32 + (r & 3) + 8 * (r >> 2) + 4 * q;
    const int c = c0 + m;
    const float bb = bias[c];
    {
      const int t = t0 + wn * 64 + l31;
      float v = acc0[r] + bb;
      if (RES) v += Res[(size_t)c * TT + t];
      if (RELU) v = fmaxf(v, 0.f);
      Y[(size_t)c * TT + t] = v;
    }
    {
      const int t = t0 + wn * 64 + 32 + l31;
      float v = acc1[r] + bb;
      if (RES) v += Res[(size_t)c * TT + t];
      if (RELU) v = fmaxf(v, 0.f);
      Y[(size_t)c * TT + t] = v;
    }
  }
}

// -------------------- tiled transpose (512,T) -> out (T,512) + f32 copy (T,512)
__launch_bounds__(256)
__global__ void temit_k(const float* __restrict__ Xin, float* __restrict__ outp,
                        float* __restrict__ Aout) {
  __shared__ float tile[32][33];
  const int t0 = blockIdx.x * 32, d0 = blockIdx.y * 32;
  const int lx = threadIdx.x & 31, ly = threadIdx.x >> 5;
#pragma unroll
  for (int r = 0; r < 4; r++)
    tile[ly + 8 * r][lx] = Xin[(size_t)(d0 + ly + 8 * r) * TT + t0 + lx];
  __syncthreads();
#pragma unroll
  for (int r = 0; r < 4; r++) {
    const int t = t0 + ly + 8 * r, dd = d0 + lx;
    const float v = tile[lx][ly + 8 * r];
    outp[(size_t)t * 512 + dd] = v;
    Aout[(size_t)t * 512 + dd] = v;
  }
}

// --------------------------- cosine sim, block per row (||v|| computed once)
__launch_bounds__(256)
__global__ void csim_k(const float* __restrict__ V, const float* __restrict__ text,
                       const float* __restrict__ tnorm, float* __restrict__ out) {
  __shared__ float vs[512];
  __shared__ float red[4];
  const int r = blockIdx.x, tid = threadIdx.x;
  const float a = V[(size_t)r * 512 + tid];
  const float b = V[(size_t)r * 512 + 256 + tid];
  vs[tid] = a; vs[tid + 256] = b;
  float ssp = a * a + b * b;
  for (int off = 32; off >= 1; off >>= 1) ssp += __shfl_xor(ssp, off);
  if ((tid & 63) == 0) red[tid >> 6] = ssp;
  __syncthreads();
  const float ss = red[0] + red[1] + red[2] + red[3];
  const int c = tid >> 3, p = tid & 7;
  const float* tr = text + (size_t)c * 512 + p * 64;
  const float* vr = vs + p * 64;
  float d = 0.f;
#pragma unroll
  for (int k = 0; k < 64; k++) d += vr[k] * tr[k];
  for (int off = 4; off >= 1; off >>= 1) d += __shfl_xor(d, off);
  if (p == 0) out[(size_t)r * 32 + c] = d / (sqrtf(ss) * tnorm[c]);
}

// ======================================================================= host
extern "C" void kernel_launch(void* const* d_in, const int* in_sizes, int n_in,
                              void* d_out, int out_size, void* d_ws, size_t ws_size,
                              hipStream_t stream) {
  const float* in_ff   = (const float*)d_in[0];
  const float* in_act  = (const float*)d_in[1];
  const float* in_fpos = (const float*)d_in[2];
  const float* in_apos = (const float*)d_in[3];
  const float* in_text = (const float*)d_in[4];
  const float* Wf2c = (const float*)d_in[5];  const float* bf2c = (const float*)d_in[6];
  const float* Wa2c = (const float*)d_in[7];  const float* ba2c = (const float*)d_in[8];
  const float* Ws2c = (const float*)d_in[9];  const float* bs2c = (const float*)d_in[10];
  const float* Wih_f = (const float*)d_in[11]; const float* Whh_f = (const float*)d_in[12];
  const float* bih_f = (const float*)d_in[13]; const float* bhh_f = (const float*)d_in[14];
  const float* Wih_b = (const float*)d_in[15]; const float* Whh_b = (const float*)d_in[16];
  const float* bih_b = (const float*)d_in[17]; const float* bhh_b = (const float*)d_in[18];
  const float* Wcomb = (const float*)d_in[19]; const float* bcomb = (const float*)d_in[20];
  const float* f2a_Wq = (const float*)d_in[21]; const float* f2a_Wk = (const float*)d_in[22];
  const float* f2a_Wv = (const float*)d_in[23]; const float* f2a_Wo = (const float*)d_in[24];
  const float* f2a_bo = (const float*)d_in[25];
  const float* ag_Wih = (const float*)d_in[26]; const float* ag_Whh = (const float*)d_in[27];
  const float* ag_bih = (const float*)d_in[28]; const float* ag_bhh = (const float*)d_in[29];
  const float* a2f_Wq = (const float*)d_in[30]; const float* a2f_Wk = (const float*)d_in[31];
  const float* a2f_Wv = (const float*)d_in[32]; const float* a2f_Wo = (const float*)d_in[33];
  const float* a2f_bo = (const float*)d_in[34];
  const float* Wsf = (const float*)d_in[35]; const float* bsf = (const float*)d_in[36];
  const float* tcn_inW = (const float*)d_in[37]; const float* tcn_inb = (const float*)d_in[38];
  const float* tcn_dW = (const float*)d_in[39]; const float* tcn_db = (const float*)d_in[40];
  const float* tcn_pW = (const float*)d_in[41]; const float* tcn_pb = (const float*)d_in[42];
  const float* tcn_outW = (const float*)d_in[43]; const float* tcn_outb = (const float*)d_in[44];

  int S = (out_size - (TT * DD + MM * DD + TT * CC + MM * CC)) / CC;
  if (S < 1) S = 1;
  if (S > TT) S = TT;
  const int Spad = (S + 63) & ~63;

  char* ws = (char*)d_ws;
  size_t off = 0;
  auto alloc = [&](size_t b) -> char* { char* p = ws + off; off += (b + 255) & ~(size_t)255; return p; };
  float* Mmat = (float*)alloc((size_t)512 * 32 * 4);
  float* bdot = (float*)alloc(32 * 4);
  const size_t BTD = (size_t)TT * DD * 4;
  float* bufA = (float*)alloc(BTD);
  float* bufB = (float*)alloc(BTD);
  int* pred    = (int*)alloc((size_t)TT * 4);
  int* segid   = (int*)alloc((size_t)TT * 4);
  int* starts  = (int*)alloc((size_t)TT * 4);
  int* centers = (int*)alloc((size_t)TT * 4);
  int* cnts    = (int*)alloc((size_t)TT * 4);
  float* tnorm = (float*)alloc(32 * 4);
  float* segmean = (float*)alloc((size_t)Spad * 512 * 4);
  float* gif  = (float*)alloc((size_t)Spad * 768 * 4);
  float* gib  = (float*)alloc((size_t)Spad * 768 * 4);
  float* hfb  = (float*)alloc((size_t)Spad * 256 * 4);
  float* hbb  = (float*)alloc((size_t)Spad * 256 * 4);
  float* acmb = (float*)alloc((size_t)Spad * 512 * 4);
  float* segc = (float*)alloc((size_t)Spad * 512 * 4);
  float* segpos = (float*)alloc((size_t)Spad * 512 * 4);
  float* kin  = (float*)alloc((size_t)Spad * 512 * 4);
  float* kf2a = (float*)alloc((size_t)Spad * 512 * 4);
  float* vf2a = (float*)alloc((size_t)Spad * 512 * 4);
  float* q2   = (float*)alloc((size_t)Spad * 512 * 4);
  float* att2 = (float*)alloc((size_t)Spad * 512 * 4);
  float* seg2 = (float*)alloc((size_t)Spad * 512 * 4);
  float* vseg = (float*)alloc((size_t)Spad * 512 * 4);
  float* pbuf = (float*)alloc((size_t)64 * Spad * 4);
  float* qin  = (float*)alloc((size_t)64 * 512 * 4);
  float* qf2a = (float*)alloc((size_t)64 * 512 * 4);
  float* att1 = (float*)alloc((size_t)64 * 512 * 4);
  float* af0  = (float*)alloc((size_t)64 * 512 * 4);
  float* aggi = (float*)alloc((size_t)64 * 1536 * 4);
  float* afg  = (float*)alloc((size_t)64 * 512 * 4);
  float* k2in = (float*)alloc((size_t)64 * 512 * 4);
  float* k2   = (float*)alloc((size_t)64 * 512 * 4);
  float* v2   = (float*)alloc((size_t)64 * 512 * 4);
  float* vaf  = (float*)alloc((size_t)64 * 512 * 4);
  (void)ws_size; (void)in_sizes; (void)n_in;

  float* outp = (float*)d_out;
  float* out_ff   = outp;
  float* out_af   = outp + (size_t)TT * DD;
  float* out_fsim = out_af + (size_t)MM * DD;
  float* out_asim = out_fsim + (size_t)TT * CC;
  float* out_ssim = out_asim + (size_t)MM * CC;

  auto GR = [](long n) { return (unsigned)((n + 255) / 256); };
  const unsigned Sg = (unsigned)(Spad / 64);

  tnorm_k<<<1, 256, 0, stream>>>(in_text, tnorm);

  // NaN-prefill mailbox buffers (polled-data protocol)
  nanfill_k<<<128, 256, 0, stream>>>(hfb, (long)Spad * 256);
  nanfill_k<<<128, 256, 0, stream>>>(hbb, (long)Spad * 256);
  nanfill_k<<<32, 256, 0, stream>>>(afg, (long)64 * 512);

  // segmentation: folded projection (ff @ (Wf2c @ t_hat)) -> argmax
  prepM_k<<<64, 256, 0, stream>>>(Wf2c, bf2c, in_text, tnorm, Mmat, bdot);
  fargmax_k<<<TT / 8, 256, 0, stream>>>(in_ff, Mmat, bdot, pred);
  segscan_k<<<1, 256, 0, stream>>>(pred, segid, starts, centers, cnts);
  segmean_k<<<GR((long)S * 512), 256, 0, stream>>>(in_ff, starts, cnts, segmean, S);

  // seg BiGRU (NaN-poll mailbox)
  gemmm_k<<<dim3(6, Sg), 256, 0, stream>>>(segmean, Wih_f, bih_f, gif, Spad, 768, 512);
  gemmm_k<<<dim3(6, Sg), 256, 0, stream>>>(segmean, Wih_b, bih_b, gib, Spad, 768, 512);
  gru_seg_mb_k<<<8, 192, 0, stream>>>(gif, gib, Whh_f, bhh_f, Whh_b, bhh_b, hfb, hbb, S);
  acomb_k<<<GR((long)S * 512), 256, 0, stream>>>(hfb, hbb, acmb, S * 512);
  gemmm_k<<<dim3(4, Sg), 256, 0, stream>>>(acmb, Wcomb, bcomb, segc, Spad, 512, 512);
  gatherpos_k<<<GR((long)S * 512), 256, 0, stream>>>(in_fpos, centers, segpos, S * 512);

  // f2a attention (actions query segments)
  addff_k<<<GR(64 * 512), 256, 0, stream>>>(in_act, in_apos, qin, 64 * 512);
  addff_k<<<GR((long)S * 512), 256, 0, stream>>>(segc, segpos, kin, S * 512);
  gemmm_k<<<dim3(4, 1), 256, 0, stream>>>(qin, f2a_Wq, nullptr, qf2a, 64, 512, 512);
  gemmm_k<<<dim3(4, Sg), 256, 0, stream>>>(kin, f2a_Wk, nullptr, kf2a, Spad, 512, 512);
  gemmm_k<<<dim3(4, Sg), 256, 0, stream>>>(segc, f2a_Wv, nullptr, vf2a, Spad, 512, 512);
  nlogit_k<<<GR((long)64 * S), 256, 0, stream>>>(qf2a, kf2a, pbuf, 64, S);
  nsoft_k<<<1, 256, 0, stream>>>(pbuf, 64, S);
  nav_k<<<GR(64 * 512), 256, 0, stream>>>(pbuf, vf2a, att1, 64, S);
  gemmm_k<<<dim3(4, 1), 256, 0, stream>>>(att1, f2a_Wo, f2a_bo, af0, 64, 512, 512);

  // action GRU (NaN-poll mailbox)
  gemmm_k<<<dim3(12, 1), 256, 0, stream>>>(af0, ag_Wih, ag_bih, aggi, 64, 1536, 512);
  gru_act_mb_k<<<16, 128, 0, stream>>>(aggi, ag_Whh, ag_bhh, afg, MM);
  copy_k<<<GR(64 * 512), 256, 0, stream>>>(afg, out_af, 64 * 512);

  // a2f attention (segments query actions)
  addff_k<<<GR(64 * 512), 256, 0, stream>>>(afg, in_apos, k2in, 64 * 512);
  gemmm_k<<<dim3(4, Sg), 256, 0, stream>>>(kin, a2f_Wq, nullptr, q2, Spad, 512, 512);
  gemmm_k<<<dim3(4, 1), 256, 0, stream>>>(k2in, a2f_Wk, nullptr, k2, 64, 512, 512);
  gemmm_k<<<dim3(4, 1), 256, 0, stream>>>(afg, a2f_Wv, nullptr, v2, 64, 512, 512);
  nlogit_k<<<GR((long)S * 64), 256, 0, stream>>>(q2, k2, pbuf, S, 64);
  nsoft_k<<<GR(S), 256, 0, stream>>>(pbuf, S, 64);
  nav_k<<<GR((long)S * 512), 256, 0, stream>>>(pbuf, v2, att2, S, 64);
  gemmm_k<<<dim3(4, Sg), 256, 0, stream>>>(att2, a2f_Wo, a2f_bo, seg2, Spad, 512, 512);

  // frame fusion + TCN (MFMA), ping-pong bufA <-> bufB as (D,T)
  ff2m_k<<<dim3(64, 8), 256, 0, stream>>>(seg2, in_ff, segid, Wsf, bsf, bufA, S);
  convm_k<1, 0, 0><<<dim3(64, 8), 256, 0, stream>>>(bufA, tcn_inW, tcn_inb, nullptr, bufB, 1);
  for (int l = 0; l < 6; l++) {
    convm_k<3, 1, 0><<<dim3(64, 8), 256, 0, stream>>>(
        bufB, tcn_dW + (size_t)l * 512 * 512 * 3, tcn_db + (size_t)l * 512, nullptr, bufA, 1 << l);
    convm_k<1, 0, 1><<<dim3(64, 8), 256, 0, stream>>>(
        bufA, tcn_pW + (size_t)l * 512 * 512, tcn_pb + (size_t)l * 512, bufB, bufB, 1);
  }
  convm_k<1, 0, 0><<<dim3(64, 8), 256, 0, stream>>>(bufB, tcn_outW, tcn_outb, nullptr, bufA, 1);
  temit_k<<<dim3(256, 16), 256, 0, stream>>>(bufA, out_ff, bufB);

  // similarity heads
  gemmm_k<<<dim3(4, 128), 256, 0, stream>>>(bufB, Wf2c, bf2c, bufA, TT, 512, 512);
  csim_k<<<TT, 256, 0, stream>>>(bufA, in_text, tnorm, out_fsim);
  gemmm_k<<<dim3(4, 1), 256, 0, stream>>>(afg, Wa2c, ba2c, vaf, 64, 512, 512);
  csim_k<<<64, 256, 0, stream>>>(vaf, in_text, tnorm, out_asim);
  gemmm_k<<<dim3(4, Sg), 256, 0, stream>>>(seg2, Ws2c, bs2c, vseg, Spad, 512, 512);
  csim_k<<<(unsigned)S, 256, 0, stream>>>(vseg, in_text, tnorm, out_ssim);
}

// Round 12
// 3781.470 us; speedup vs baseline: 1.1645x; 1.0486x over previous
//
#include <hip/hip_runtime.h>
#include <cstdint>
#include <cstddef>

__device__ __forceinline__ float sigf(float x) { return 1.f / (1.f + expf(-x)); }

__device__ __forceinline__ unsigned packh(float a, float b) {
  union { unsigned u; _Float16 h[2]; } cv;
  cv.h[0] = (_Float16)a; cv.h[1] = (_Float16)b; return cv.u;
}
__device__ __forceinline__ float2 uph(unsigned u) {
  union { unsigned uu; _Float16 h[2]; } cv; cv.uu = u;
  return make_float2((float)cv.h[0], (float)cv.h[1]);
}

typedef _Float16 f16x8 __attribute__((ext_vector_type(8)));
typedef float f32x16 __attribute__((ext_vector_type(16)));

static constexpr int TT = 8192;
static constexpr int MM = 64;
static constexpr int CC = 32;
static constexpr int DD = 512;
static constexpr unsigned GUARD_MAX = 1u << 30;

// --------------------------------------------------------------- NaN filling
// h mailboxes are written exactly once per (step,slot); readers poll the data
// itself (v!=v) instead of a separate flag -> one less serialized round trip.
__global__ void nanfill_k(float* __restrict__ p, long n) {
  long i = (long)blockIdx.x * 256 + threadIdx.x;
  long stride = (long)gridDim.x * 256;
  const float qnan = __int_as_float(0x7fc00000);
  for (; i < n; i += stride) p[i] = qnan;
}

// ---------------------------------------------------------------- elementwise
__global__ void copy_k(const float* __restrict__ a, float* __restrict__ o, int n) {
  int i = blockIdx.x * 256 + threadIdx.x;
  if (i < n) o[i] = a[i];
}
__global__ void addff_k(const float* __restrict__ a, const float* __restrict__ b, float* __restrict__ o, int n) {
  int i = blockIdx.x * 256 + threadIdx.x;
  if (i < n) o[i] = a[i] + b[i];
}
__global__ void acomb_k(const float* __restrict__ hf, const float* __restrict__ hb, float* __restrict__ o, int n) {
  int i = blockIdx.x * 256 + threadIdx.x;
  if (i >= n) return;
  int s = i >> 9, j = i & 511;
  float v = (j < 256) ? hf[(size_t)s * 256 + j] : hb[(size_t)s * 256 + (j - 256)];
  o[i] = fmaxf(v, 0.f);
}
__global__ void gatherpos_k(const float* __restrict__ fpos, const int* __restrict__ centers,
                            float* __restrict__ segpos, int n) {
  int i = blockIdx.x * 256 + threadIdx.x;
  if (i >= n) return;
  int s = i >> 9, dd = i & 511;
  int ct = centers[s];
  ct = ct < 0 ? 0 : (ct > TT - 1 ? TT - 1 : ct);
  segpos[i] = fpos[(size_t)ct * 512 + dd];
}

// ---------------------------------------------------------------- text norms
__global__ void tnorm_k(const float* __restrict__ text, float* __restrict__ tnorm) {
  int c = blockIdx.x * 256 + threadIdx.x;
  if (c >= 32) return;
  float s = 0.f;
  for (int dd = 0; dd < 512; dd++) { float v = text[(size_t)c * 512 + dd]; s += v * v; }
  tnorm[c] = sqrtf(s);
}

// ---------------- fold argmax projection: M[k][c] = Wf2c[k,:]·(text_c/|t_c|)
__global__ void prepM_k(const float* __restrict__ W, const float* __restrict__ b,
                        const float* __restrict__ text, const float* __restrict__ tnorm,
                        float* __restrict__ M, float* __restrict__ bdot) {
  int idx = blockIdx.x * 256 + threadIdx.x;
  if (idx < 512 * 32) {
    int k = idx >> 5, c = idx & 31;
    const float* wr = W + (size_t)k * 512;
    const float* tr = text + (size_t)c * 512;
    float s = 0.f;
    for (int dd = 0; dd < 512; dd++) s += wr[dd] * tr[dd];
    M[idx] = s / tnorm[c];
  }
  if (idx < 32) {
    const float* tr = text + (size_t)idx * 512;
    float s = 0.f;
    for (int dd = 0; dd < 512; dd++) s += b[dd] * tr[dd];
    bdot[idx] = s / tnorm[idx];
  }
}

// 8 rows/block; lane c of each 32-group owns class c; shfl-argmax (min idx tie)
__launch_bounds__(256)
__global__ void fargmax_k(const float* __restrict__ ff, const float* __restrict__ M,
                          const float* __restrict__ bdot, int* __restrict__ pred) {
  const int r = blockIdx.x * 8 + (threadIdx.x >> 5);
  const int c = threadIdx.x & 31;
  const float* fr = ff + (size_t)r * 512;
  float acc = bdot[c];
  for (int k = 0; k < 512; k++) acc += fr[k] * M[k * 32 + c];
  float best = acc; int bidx = c;
  for (int off = 16; off >= 1; off >>= 1) {
    const float ov = __shfl_xor(best, off);
    const int oi = __shfl_xor(bidx, off);
    if (ov > best || (ov == best && oi < bidx)) { best = ov; bidx = oi; }
  }
  if (c == 0) pred[r] = bidx;
}

// ---------------------------------------------------- naive attention pieces
__global__ void nlogit_k(const float* __restrict__ Q, const float* __restrict__ Kk,
                         float* __restrict__ L, int NY, int NX) {
  int idx = blockIdx.x * 256 + threadIdx.x;
  if (idx >= NY * NX) return;
  int y = idx / NX, x = idx - y * NX;
  const float* qr = Q + (size_t)y * 512;
  const float* kr = Kk + (size_t)x * 512;
  float d = 0.f;
  for (int k = 0; k < 512; k++) d += qr[k] * kr[k];
  L[idx] = d * 0.044194173824159216f;
}
__global__ void nsoft_k(float* __restrict__ L, int NY, int NX) {
  int y = blockIdx.x * 256 + threadIdx.x;
  if (y >= NY) return;
  float* row = L + (size_t)y * NX;
  float m = row[0];
  for (int x = 1; x < NX; x++) m = fmaxf(m, row[x]);
  float s = 0.f;
  for (int x = 0; x < NX; x++) { float p = expf(row[x] - m); row[x] = p; s += p; }
  const float inv = 1.f / s;
  for (int x = 0; x < NX; x++) row[x] *= inv;
}
__global__ void nav_k(const float* __restrict__ P, const float* __restrict__ V,
                      float* __restrict__ O, int NY, int NX) {
  int idx = blockIdx.x * 256 + threadIdx.x;
  if (idx >= NY * 512) return;
  int y = idx >> 9, dd = idx & 511;
  const float* pr = P + (size_t)y * NX;
  float o = 0.f;
  for (int x = 0; x < NX; x++) o += pr[x] * V[(size_t)x * 512 + dd];
  O[idx] = o;
}

// ------------------------------- parallel run-length segmentation (one block)
__global__ void segscan_k(const int* __restrict__ pred, int* __restrict__ segid,
                          int* __restrict__ starts, int* __restrict__ centers,
                          int* __restrict__ cnts) {
  __shared__ int base[256];
  __shared__ int SS;
  const int tid = threadIdx.x;
  int lc = 0;
  unsigned flags = 0;
  int prev = (tid > 0) ? pred[tid * 32 - 1] : 0;
  for (int i = 0; i < 32; i++) {
    const int t = tid * 32 + i;
    const int cur = pred[t];
    const int c = (t > 0) && (cur != prev);
    prev = cur;
    flags |= ((unsigned)c) << i;
    lc += c;
  }
  base[tid] = lc;
  __syncthreads();
  if (tid == 0) {
    int run = 0;
    for (int i = 0; i < 256; i++) { const int v = base[i]; base[i] = run; run += v; }
    SS = run + 1;
  }
  __syncthreads();
  int b = base[tid];
  for (int i = 0; i < 32; i++) {
    const int t = tid * 32 + i;
    if ((flags >> i) & 1u) { b++; starts[b] = t; }
    segid[t] = b;
  }
  if (tid == 0) starts[0] = 0;
  __threadfence_block();
  __syncthreads();
  const int S = SS;
  for (int s = tid; s < TT; s += 256) {
    if (s < S) {
      const int e = (s == S - 1) ? (TT - 1) : (starts[s + 1] - 1);
      centers[s] = (starts[s] + e) >> 1;
      cnts[s] = e - starts[s] + 1;
    } else {
      starts[s] = 0; cnts[s] = 1; centers[s] = 0;
    }
  }
}

// ---------------------------------------------------------- segment mean pool
__global__ void segmean_k(const float* __restrict__ ff, const int* __restrict__ starts,
                          const int* __restrict__ cnts, float* __restrict__ segmean, int S) {
  int idx = blockIdx.x * 256 + threadIdx.x;
  if (idx >= S * 512) return;
  int s = idx >> 9, dd = idx & 511;
  int st = starts[s], n = cnts[s];
  st = st < 0 ? 0 : (st > TT - 1 ? TT - 1 : st);
  n = n < 1 ? 1 : n;
  if (st + n > TT) n = TT - st;
  float a = 0.f;
  for (int t = st; t < st + n; t++) a += ff[(size_t)t * 512 + dd];
  segmean[idx] = a / (float)n;
}

// ------------------- multi-block bidirectional seg GRU (H=256), LDS weights
// r0-verified mailbox compute core, FROZEN. r11 NaN-poll protocol (v!=v on
// the datum; no flags). r12: self-partition skip -- own 64 h values written
// straight to LDS hcur (no round trip on own store); poll only the 192
// REMOTE entries, exactly one per thread (was up to 2 sequential RTs).
__launch_bounds__(192)
__global__ void gru_seg_mb_k(const float* __restrict__ gi_f, const float* __restrict__ gi_b,
                             const float* __restrict__ Whh_f, const float* __restrict__ bhh_f,
                             const float* __restrict__ Whh_b, const float* __restrict__ bhh_b,
                             float* __restrict__ hf, float* __restrict__ hb, int S) {
  const int dir = blockIdx.x >> 2;
  const int part = blockIdx.x & 3;
  const float* gi = dir ? gi_b : gi_f;
  const float* Whh = dir ? Whh_b : Whh_f;
  const float* bhh = dir ? bhh_b : bhh_f;
  float* ho = dir ? hb : hf;
  const int tid = threadIdx.x;
  const int h0 = part * 64;
  const int grp = tid >> 6;
  const int jj = tid & 63;
  const int j = grp * 256 + h0 + jj;
  __shared__ __align__(16) unsigned wlds[128 * 192];
  __shared__ __align__(16) unsigned hpk[128];
  __shared__ float hcur[256];
  __shared__ float rbuf[64], zbuf[64], gnbuf[64];
  for (int e = tid; e < 128 * 192; e += 192) {
    const int q = e / 768, rem = e % 768;
    const int g = rem >> 2, r = rem & 3;
    const int i2 = q * 4 + r;
    const int gg = (g >> 6) * 256 + h0 + (g & 63);
    wlds[e] = packh(Whh[(size_t)(2 * i2) * 768 + gg], Whh[(size_t)(2 * i2 + 1) * 768 + gg]);
  }
  for (int e = tid; e < 128; e += 192) hpk[e] = 0u;
  for (int e = tid; e < 256; e += 192) hcur[e] = 0.f;
  const float bj = bhh[j];
  __syncthreads();
  const uint4* hp4 = reinterpret_cast<const uint4*>(hpk);
  const uint4* wp4 = reinterpret_cast<const uint4*>(wlds);
  // prefetch step 0 gi
  int s = dir ? (S - 1) : 0;
  float g_j = gi[(size_t)s * 768 + j];
  float g_n = (tid < 64) ? gi[(size_t)s * 768 + 512 + h0 + tid] : 0.f;
  for (int step = 0; step < S; step++) {
    float a0 = 0.f, a1 = 0.f, a2 = 0.f, a3 = 0.f;
#pragma unroll 8
    for (int q = 0; q < 32; q++) {
      const uint4 h4 = hp4[q];
      const uint4 w4 = wp4[q * 192 + tid];
      const float2 hh0 = uph(h4.x), hh1 = uph(h4.y), hh2 = uph(h4.z), hh3 = uph(h4.w);
      const float2 ww0 = uph(w4.x), ww1 = uph(w4.y), ww2 = uph(w4.z), ww3 = uph(w4.w);
      a0 += hh0.x * ww0.x + hh0.y * ww0.y;
      a1 += hh1.x * ww1.x + hh1.y * ww1.y;
      a2 += hh2.x * ww2.x + hh2.y * ww2.y;
      a3 += hh3.x * ww3.x + hh3.y * ww3.y;
    }
    const float gh = bj + (a0 + a1) + (a2 + a3);
    if (grp == 0)      rbuf[jj] = sigf(g_j + gh);
    else if (grp == 1) zbuf[jj] = sigf(g_j + gh);
    else               gnbuf[jj] = gh;
    __syncthreads();
    if (tid < 64) {
      const float nval = tanhf(g_n + rbuf[tid] * gnbuf[tid]);
      const float hn = (1.f - zbuf[tid]) * nval + zbuf[tid] * hcur[h0 + tid];
      hcur[h0 + tid] = hn;                                  // own slice: LDS direct
      __hip_atomic_store(&ho[(size_t)s * 256 + h0 + tid], hn,
                         __ATOMIC_RELAXED, __HIP_MEMORY_SCOPE_AGENT);
    }
    // prefetch next-step gi (overlaps peers' stores landing)
    const int sn = dir ? (s - 1) : (s + 1);
    if (step + 1 < S) {
      g_j = gi[(size_t)sn * 768 + j];
      if (tid < 64) g_n = gi[(size_t)sn * 768 + 512 + h0 + tid];
    }
    __syncthreads();
    // poll REMOTE entries only; one per thread (192 threads, 192 remote)
    {
      const int re = (tid < h0) ? tid : tid + 64;
      float v = __hip_atomic_load(&ho[(size_t)s * 256 + re],
                                  __ATOMIC_RELAXED, __HIP_MEMORY_SCOPE_AGENT);
      unsigned guard = 0;
      while (v != v && ++guard < GUARD_MAX) {
        __builtin_amdgcn_s_sleep(1);
        v = __hip_atomic_load(&ho[(size_t)s * 256 + re],
                              __ATOMIC_RELAXED, __HIP_MEMORY_SCOPE_AGENT);
      }
      hcur[re] = v;
    }
    __syncthreads();
    for (int e = tid; e < 128; e += 192) hpk[e] = packh(hcur[2 * e], hcur[2 * e + 1]);
    __syncthreads();
    s = sn;
  }
}

// ------------------------- multi-block action GRU (H=512), LDS weights
// r11 NaN-poll protocol; r12: own 32 h values -> LDS direct, remote polled
// as float4-wide groups (4 loads issued back-to-back, single wait) instead
// of 4 sequential dependent round trips per thread.
__launch_bounds__(128)
__global__ void gru_act_mb_k(const float* __restrict__ gi, const float* __restrict__ Whh,
                             const float* __restrict__ bhh, float* __restrict__ hout,
                             int steps) {
  const int part = blockIdx.x;
  const int tid = threadIdx.x;
  const int h0 = part * 32;
  const int grp = tid >> 5;
  const int jj = tid & 31;
  const bool act = (tid < 96);
  const int j = act ? (grp * 512 + h0 + jj) : 0;
  __shared__ __align__(16) unsigned wlds[256 * 96];
  __shared__ __align__(16) unsigned hpk[256];
  __shared__ float hcur[512];
  __shared__ float rbuf[32], zbuf[32], gnbuf[32];
  for (int e = tid; e < 256 * 96; e += 128) {
    const int q = e / 384, rem = e % 384;
    const int g = rem >> 2, r = rem & 3;
    const int i2 = q * 4 + r;
    const int gg = (g >> 5) * 512 + h0 + (g & 31);
    wlds[e] = packh(Whh[(size_t)(2 * i2) * 1536 + gg], Whh[(size_t)(2 * i2 + 1) * 1536 + gg]);
  }
  for (int e = tid; e < 256; e += 128) hpk[e] = 0u;
  for (int e = tid; e < 512; e += 128) hcur[e] = 0.f;
  const float bj = act ? bhh[j] : 0.f;
  __syncthreads();
  const uint4* hp4 = reinterpret_cast<const uint4*>(hpk);
  const uint4* wp4 = reinterpret_cast<const uint4*>(wlds);
  float g_j = act ? gi[j] : 0.f;
  float g_n = (tid < 32) ? gi[1024 + h0 + tid] : 0.f;
  const int gown0 = h0 >> 2;            // own float4 groups [gown0, gown0+8)
  for (int step = 0; step < steps; step++) {
    if (act) {
      float a0 = 0.f, a1 = 0.f, a2 = 0.f, a3 = 0.f;
#pragma unroll 8
      for (int q = 0; q < 64; q++) {
        const uint4 h4 = hp4[q];
        const uint4 w4 = wp4[q * 96 + tid];
        const float2 hh0 = uph(h4.x), hh1 = uph(h4.y), hh2 = uph(h4.z), hh3 = uph(h4.w);
        const float2 ww0 = uph(w4.x), ww1 = uph(w4.y), ww2 = uph(w4.z), ww3 = uph(w4.w);
        a0 += hh0.x * ww0.x + hh0.y * ww0.y;
        a1 += hh1.x * ww1.x + hh1.y * ww1.y;
        a2 += hh2.x * ww2.x + hh2.y * ww2.y;
        a3 += hh3.x * ww3.x + hh3.y * ww3.y;
      }
      const float gh = bj + (a0 + a1) + (a2 + a3);
      if (grp == 0)      rbuf[jj] = sigf(g_j + gh);
      else if (grp == 1) zbuf[jj] = sigf(g_j + gh);
      else               gnbuf[jj] = gh;
    }
    __syncthreads();
    if (tid < 32) {
      const float nval = tanhf(g_n + rbuf[tid] * gnbuf[tid]);
      const float hn = (1.f - zbuf[tid]) * nval + zbuf[tid] * hcur[h0 + tid];
      hcur[h0 + tid] = hn;                                  // own slice: LDS direct
      __hip_atomic_store(&hout[(size_t)step * 512 + h0 + tid], hn,
                         __ATOMIC_RELAXED, __HIP_MEMORY_SCOPE_AGENT);
    }
    if (step + 1 < steps) {
      if (act) g_j = gi[(size_t)(step + 1) * 1536 + j];
      if (tid < 32) g_n = gi[(size_t)(step + 1) * 1536 + 1024 + h0 + tid];
    }
    __syncthreads();
    // poll remote groups (4-wide); own groups already in hcur
    {
      const int g = tid;  // 0..127 covers all 128 groups of 4
      if (g < gown0 || g >= gown0 + 8) {
        const float* gp = hout + (size_t)step * 512 + 4 * g;
        float x0, x1, x2, x3;
        unsigned guard = 0;
        do {
          x0 = __hip_atomic_load(gp + 0, __ATOMIC_RELAXED, __HIP_MEMORY_SCOPE_AGENT);
          x1 = __hip_atomic_load(gp + 1, __ATOMIC_RELAXED, __HIP_MEMORY_SCOPE_AGENT);
          x2 = __hip_atomic_load(gp + 2, __ATOMIC_RELAXED, __HIP_MEMORY_SCOPE_AGENT);
          x3 = __hip_atomic_load(gp + 3, __ATOMIC_RELAXED, __HIP_MEMORY_SCOPE_AGENT);
          if (x0 == x0 && x1 == x1 && x2 == x2 && x3 == x3) break;
          __builtin_amdgcn_s_sleep(1);
        } while (++guard < GUARD_MAX);
        hcur[4 * g + 0] = x0; hcur[4 * g + 1] = x1;
        hcur[4 * g + 2] = x2; hcur[4 * g + 3] = x3;
      }
    }
    __syncthreads();
    for (int e = tid; e < 256; e += 128) hpk[e] = packh(hcur[2 * e], hcur[2 * e + 1]);
    __syncthreads();
  }
}

// ------------------------------------------------ MFMA GEMM (fp16 staged)
// C[M,N] = A[M,K] @ B[K,N] + bias.  Tile M64 x N128, K-chunk 64.
__launch_bounds__(256)
__global__ void gemmm_k(const float* __restrict__ A, const float* __restrict__ B,
                        const float* __restrict__ bias, float* __restrict__ C,
                        int M, int N, int K) {
  __shared__ __align__(16) _Float16 As16[64][72];
  __shared__ __align__(16) _Float16 Bs16[128][72];
  const int n0 = blockIdx.x * 128, m0 = blockIdx.y * 64;
  const int tid = threadIdx.x;
  const int l = tid & 63, w = tid >> 6;
  const int wm = w & 1, wn = w >> 1;
  const int l31 = l & 31, q = l >> 5;
  f32x16 acc0, acc1;
#pragma unroll
  for (int i = 0; i < 16; i++) { acc0[i] = 0.f; acc1[i] = 0.f; }
  const int am = tid >> 2, ak0 = (tid & 3) * 16;
  const int bk = tid >> 2, bn0 = (tid & 3) * 32;
  for (int kc = 0; kc < K; kc += 64) {
    __syncthreads();
#pragma unroll
    for (int kk = 0; kk < 16; kk += 4) {
      const float4 av = *reinterpret_cast<const float4*>(A + (size_t)(m0 + am) * K + kc + ak0 + kk);
      As16[am][ak0 + kk + 0] = (_Float16)av.x; As16[am][ak0 + kk + 1] = (_Float16)av.y;
      As16[am][ak0 + kk + 2] = (_Float16)av.z; As16[am][ak0 + kk + 3] = (_Float16)av.w;
    }
#pragma unroll
    for (int nn = 0; nn < 32; nn += 4) {
      const float4 bv = *reinterpret_cast<const float4*>(B + (size_t)(kc + bk) * N + n0 + bn0 + nn);
      Bs16[bn0 + nn + 0][bk] = (_Float16)bv.x; Bs16[bn0 + nn + 1][bk] = (_Float16)bv.y;
      Bs16[bn0 + nn + 2][bk] = (_Float16)bv.z; Bs16[bn0 + nn + 3][bk] = (_Float16)bv.w;
    }
    __syncthreads();
#pragma unroll
    for (int ks = 0; ks < 4; ks++) {
      const int k0 = ks * 16 + q * 8;
      const f16x8 a = *reinterpret_cast<const f16x8*>(&As16[wm * 32 + l31][k0]);
      const f16x8 b0 = *reinterpret_cast<const f16x8*>(&Bs16[wn * 64 + l31][k0]);
      acc0 = __builtin_amdgcn_mfma_f32_32x32x16_f16(a, b0, acc0, 0, 0, 0);
      const f16x8 b1 = *reinterpret_cast<const f16x8*>(&Bs16[wn * 64 + 32 + l31][k0]);
      acc1 = __builtin_amdgcn_mfma_f32_32x32x16_f16(a, b1, acc1, 0, 0, 0);
    }
  }
#pragma unroll
  for (int r = 0; r < 16; r++) {
    const int m = m0 + wm * 32 + (r & 3) + 8 * (r >> 2) + 4 * q;
    {
      const int n = n0 + wn * 64 + l31;
      float v = acc0[r];
      if (bias) v += bias[n];
      C[(size_t)m * N + n] = v;
    }
    {
      const int n = n0 + wn * 64 + 32 + l31;
      float v = acc1[r];
      if (bias) v += bias[n];
      C[(size_t)m * N + n] = v;
    }
  }
}

// ------------------- MFMA ff2: Y(D,T) = relu([seg2[sid[t]], ff[t]] @ Wsf + b)^T
__launch_bounds__(256)
__global__ void ff2m_k(const float* __restrict__ seg2, const float* __restrict__ ff,
                       const int* __restrict__ segid, const float* __restrict__ Wsf,
                       const float* __restrict__ bsf, float* __restrict__ Y, int S) {
  __shared__ __align__(16) _Float16 As16[64][72];    // [dim][k]
  __shared__ __align__(16) _Float16 Bs16[128][72];   // [frame][k]
  const int t0 = blockIdx.x * 128, nd0 = blockIdx.y * 64;
  const int tid = threadIdx.x;
  const int l = tid & 63, w = tid >> 6;
  const int wm = w & 1, wn = w >> 1;
  const int l31 = l & 31, q = l >> 5;
  f32x16 acc0, acc1;
#pragma unroll
  for (int i = 0; i < 16; i++) { acc0[i] = 0.f; acc1[i] = 0.f; }
  const int ak = tid >> 2, an0 = (tid & 3) * 16;
  const int bt = tid >> 1, bk0 = (tid & 1) * 32;
  const int tglob = t0 + bt;
  int sid = segid[tglob];
  sid = sid < 0 ? 0 : (sid >= S ? S - 1 : sid);
  for (int kc = 0; kc < 1024; kc += 64) {
    __syncthreads();
#pragma unroll
    for (int nn = 0; nn < 16; nn += 4) {
      const float4 wv = *reinterpret_cast<const float4*>(Wsf + (size_t)(kc + ak) * 512 + nd0 + an0 + nn);
      As16[an0 + nn + 0][ak] = (_Float16)wv.x; As16[an0 + nn + 1][ak] = (_Float16)wv.y;
      As16[an0 + nn + 2][ak] = (_Float16)wv.z; As16[an0 + nn + 3][ak] = (_Float16)wv.w;
    }
    {
      const float* src = (kc < 512) ? (seg2 + (size_t)sid * 512 + kc + bk0)
                                    : (ff + (size_t)tglob * 512 + (kc - 512) + bk0);
#pragma unroll
      for (int kk = 0; kk < 32; kk += 4) {
        const float4 xv = *reinterpret_cast<const float4*>(src + kk);
        Bs16[bt][bk0 + kk + 0] = (_Float16)xv.x; Bs16[bt][bk0 + kk + 1] = (_Float16)xv.y;
        Bs16[bt][bk0 + kk + 2] = (_Float16)xv.z; Bs16[bt][bk0 + kk + 3] = (_Float16)xv.w;
      }
    }
    __syncthreads();
#pragma unroll
    for (int ks = 0; ks < 4; ks++) {
      const int k0 = ks * 16 + q * 8;
      const f16x8 a = *reinterpret_cast<const f16x8*>(&As16[wm * 32 + l31][k0]);
      const f16x8 b0 = *reinterpret_cast<const f16x8*>(&Bs16[wn * 64 + l31][k0]);
      acc0 = __builtin_amdgcn_mfma_f32_32x32x16_f16(a, b0, acc0, 0, 0, 0);
      const f16x8 b1 = *reinterpret_cast<const f16x8*>(&Bs16[wn * 64 + 32 + l31][k0]);
      acc1 = __builtin_amdgcn_mfma_f32_32x32x16_f16(a, b1, acc1, 0, 0, 0);
    }
  }
#pragma unroll
  for (int r = 0; r < 16; r++) {
    const int nd = nd0 + wm * 32 + (r & 3) + 8 * (r >> 2) + 4 * q;
    const float bb = bsf[nd];
    {
      const int t = t0 + wn * 64 + l31;
      Y[(size_t)nd * TT + t] = fmaxf(acc0[r] + bb, 0.f);
    }
    {
      const int t = t0 + wn * 64 + 32 + l31;
      Y[(size_t)nd * TT + t] = fmaxf(acc1[r] + bb, 0.f);
    }
  }
}

// --------------------------------------------------- MFMA TCN conv (fp16 in)
template<int NTAPS, int RELU, int RES>
__launch_bounds__(256)
__global__ void convm_k(const float* __restrict__ X, const float* __restrict__ W,
                        const float* __restrict__ bias, const float* __restrict__ Res,
                        float* __restrict__ Y, int dil) {
  const int d = (NTAPS == 3) ? dil : 0;
  const int width = 128 + 2 * d;
  __shared__ __align__(16) _Float16 Ws16[NTAPS][64][72];
  __shared__ __align__(16) _Float16 Xs16[192][72];
  const int t0 = blockIdx.x * 128, c0 = blockIdx.y * 64;
  const int tid = threadIdx.x;
  const int l = tid & 63, w = tid >> 6;
  const int wm = w & 1, wn = w >> 1;
  const int l31 = l & 31, q = l >> 5;
  f32x16 acc0, acc1;
#pragma unroll
  for (int i = 0; i < 16; i++) { acc0[i] = 0.f; acc1[i] = 0.f; }
  const int xk = tid >> 2;
  const int xu0 = tid & 3;
  for (int kc = 0; kc < 512; kc += 64) {
    __syncthreads();
    {
      const float* xr = X + (size_t)(kc + xk) * TT;
      for (int u = xu0; u < width; u += 4) {
        const int gt = t0 - d + u;
        const float v = (gt >= 0 && gt < TT) ? xr[gt] : 0.f;
        Xs16[u][xk] = (_Float16)v;
      }
    }
    if (NTAPS == 3) {
      // W chunk for channel row c is 192 CONTIGUOUS floats at
      // (c0+c)*1536 + kc*3  (f = i*3+tap). Vector-load + scatter.
      for (int e = tid; e < 64 * 48; e += 256) {
        const int c = e / 48;
        const int f0 = (e - c * 48) * 4;
        const float4 wv = *reinterpret_cast<const float4*>(
            W + (size_t)(c0 + c) * 1536 + (size_t)kc * 3 + f0);
        const float vv[4] = {wv.x, wv.y, wv.z, wv.w};
#pragma unroll
        for (int t = 0; t < 4; t++) {
          const int f = f0 + t;
          Ws16[f % 3][c][f / 3] = (_Float16)vv[t];
        }
      }
    } else {
      for (int e = tid; e < 1024; e += 256) {
        const int c = e >> 4, i0 = (e & 15) << 2;
        const float4 wv = *reinterpret_cast<const float4*>(W + (size_t)(c0 + c) * 512 + kc + i0);
        Ws16[0][c][i0 + 0] = (_Float16)wv.x; Ws16[0][c][i0 + 1] = (_Float16)wv.y;
        Ws16[0][c][i0 + 2] = (_Float16)wv.z; Ws16[0][c][i0 + 3] = (_Float16)wv.w;
      }
    }
    __syncthreads();
#pragma unroll
    for (int tap = 0; tap < NTAPS; tap++) {
#pragma unroll
      for (int ks = 0; ks < 4; ks++) {
        const int k0 = ks * 16 + q * 8;
        const f16x8 a = *reinterpret_cast<const f16x8*>(&Ws16[tap][wm * 32 + l31][k0]);
        const int row0 = wn * 64 + l31 + tap * d;
        const f16x8 b0 = *reinterpret_cast<const f16x8*>(&Xs16[row0][k0]);
        acc0 = __builtin_amdgcn_mfma_f32_32x32x16_f16(a, b0, acc0, 0, 0, 0);
        const f16x8 b1 = *reinterpret_cast<const f16x8*>(&Xs16[row0 + 32][k0]);
        acc1 = __builtin_amdgcn_mfma_f32_32x32x16_f16(a, b1, acc1, 0, 0, 0);
      }
    }
  }
#pragma unroll
  for (int r = 0; r < 16; r++) {
    const int m = wm * 32 + (r & 3) + 8 * (r >> 2) + 4 * q;
    const int c = c0 + m;
    const float bb = bias[c];
    {
      const int t = t0 + wn * 64 + l31;
      float v = acc0[r] + bb;
      if (RES) v += Res[(size_t)c * TT + t];
      if (RELU) v = fmaxf(v, 0.f);
      Y[(size_t)c * TT + t] = v;
    }
    {
      const int t = t0 + wn * 64 + 32 + l31;
      float v = acc1[r] + bb;
      if (RES) v += Res[(size_t)c * TT + t];
      if (RELU) v = fmaxf(v, 0.f);
      Y[(size_t)c * TT + t] = v;
    }
  }
}

// -------------------- tiled transpose (512,T) -> out (T,512) + f32 copy (T,512)
__launch_bounds__(256)
__global__ void temit_k(const float* __restrict__ Xin, float* __restrict__ outp,
                        float* __restrict__ Aout) {
  __shared__ float tile[32][33];
  const int t0 = blockIdx.x * 32, d0 = blockIdx.y * 32;
  const int lx = threadIdx.x & 31, ly = threadIdx.x >> 5;
#pragma unroll
  for (int r = 0; r < 4; r++)
    tile[ly + 8 * r][lx] = Xin[(size_t)(d0 + ly + 8 * r) * TT + t0 + lx];
  __syncthreads();
#pragma unroll
  for (int r = 0; r < 4; r++) {
    const int t = t0 + ly + 8 * r, dd = d0 + lx;
    const float v = tile[lx][ly + 8 * r];
    outp[(size_t)t * 512 + dd] = v;
    Aout[(size_t)t * 512 + dd] = v;
  }
}

// --------------------------- cosine sim, block per row (||v|| computed once)
__launch_bounds__(256)
__global__ void csim_k(const float* __restrict__ V, const float* __restrict__ text,
                       const float* __restrict__ tnorm, float* __restrict__ out) {
  __shared__ float vs[512];
  __shared__ float red[4];
  const int r = blockIdx.x, tid = threadIdx.x;
  const float a = V[(size_t)r * 512 + tid];
  const float b = V[(size_t)r * 512 + 256 + tid];
  vs[tid] = a; vs[tid + 256] = b;
  float ssp = a * a + b * b;
  for (int off = 32; off >= 1; off >>= 1) ssp += __shfl_xor(ssp, off);
  if ((tid & 63) == 0) red[tid >> 6] = ssp;
  __syncthreads();
  const float ss = red[0] + red[1] + red[2] + red[3];
  const int c = tid >> 3, p = tid & 7;
  const float* tr = text + (size_t)c * 512 + p * 64;
  const float* vr = vs + p * 64;
  float d = 0.f;
#pragma unroll
  for (int k = 0; k < 64; k++) d += vr[k] * tr[k];
  for (int off = 4; off >= 1; off >>= 1) d += __shfl_xor(d, off);
  if (p == 0) out[(size_t)r * 32 + c] = d / (sqrtf(ss) * tnorm[c]);
}

// ======================================================================= host
extern "C" void kernel_launch(void* const* d_in, const int* in_sizes, int n_in,
                              void* d_out, int out_size, void* d_ws, size_t ws_size,
                              hipStream_t stream) {
  const float* in_ff   = (const float*)d_in[0];
  const float* in_act  = (const float*)d_in[1];
  const float* in_fpos = (const float*)d_in[2];
  const float* in_apos = (const float*)d_in[3];
  const float* in_text = (const float*)d_in[4];
  const float* Wf2c = (const float*)d_in[5];  const float* bf2c = (const float*)d_in[6];
  const float* Wa2c = (const float*)d_in[7];  const float* ba2c = (const float*)d_in[8];
  const float* Ws2c = (const float*)d_in[9];  const float* bs2c = (const float*)d_in[10];
  const float* Wih_f = (const float*)d_in[11]; const float* Whh_f = (const float*)d_in[12];
  const float* bih_f = (const float*)d_in[13]; const float* bhh_f = (const float*)d_in[14];
  const float* Wih_b = (const float*)d_in[15]; const float* Whh_b = (const float*)d_in[16];
  const float* bih_b = (const float*)d_in[17]; const float* bhh_b = (const float*)d_in[18];
  const float* Wcomb = (const float*)d_in[19]; const float* bcomb = (const float*)d_in[20];
  const float* f2a_Wq = (const float*)d_in[21]; const float* f2a_Wk = (const float*)d_in[22];
  const float* f2a_Wv = (const float*)d_in[23]; const float* f2a_Wo = (const float*)d_in[24];
  const float* f2a_bo = (const float*)d_in[25];
  const float* ag_Wih = (const float*)d_in[26]; const float* ag_Whh = (const float*)d_in[27];
  const float* ag_bih = (const float*)d_in[28]; const float* ag_bhh = (const float*)d_in[29];
  const float* a2f_Wq = (const float*)d_in[30]; const float* a2f_Wk = (const float*)d_in[31];
  const float* a2f_Wv = (const float*)d_in[32]; const float* a2f_Wo = (const float*)d_in[33];
  const float* a2f_bo = (const float*)d_in[34];
  const float* Wsf = (const float*)d_in[35]; const float* bsf = (const float*)d_in[36];
  const float* tcn_inW = (const float*)d_in[37]; const float* tcn_inb = (const float*)d_in[38];
  const float* tcn_dW = (const float*)d_in[39]; const float* tcn_db = (const float*)d_in[40];
  const float* tcn_pW = (const float*)d_in[41]; const float* tcn_pb = (const float*)d_in[42];
  const float* tcn_outW = (const float*)d_in[43]; const float* tcn_outb = (const float*)d_in[44];

  int S = (out_size - (TT * DD + MM * DD + TT * CC + MM * CC)) / CC;
  if (S < 1) S = 1;
  if (S > TT) S = TT;
  const int Spad = (S + 63) & ~63;

  char* ws = (char*)d_ws;
  size_t off = 0;
  auto alloc = [&](size_t b) -> char* { char* p = ws + off; off += (b + 255) & ~(size_t)255; return p; };
  float* Mmat = (float*)alloc((size_t)512 * 32 * 4);
  float* bdot = (float*)alloc(32 * 4);
  const size_t BTD = (size_t)TT * DD * 4;
  float* bufA = (float*)alloc(BTD);
  float* bufB = (float*)alloc(BTD);
  int* pred    = (int*)alloc((size_t)TT * 4);
  int* segid   = (int*)alloc((size_t)TT * 4);
  int* starts  = (int*)alloc((size_t)TT * 4);
  int* centers = (int*)alloc((size_t)TT * 4);
  int* cnts    = (int*)alloc((size_t)TT * 4);
  float* tnorm = (float*)alloc(32 * 4);
  float* segmean = (float*)alloc((size_t)Spad * 512 * 4);
  float* gif  = (float*)alloc((size_t)Spad * 768 * 4);
  float* gib  = (float*)alloc((size_t)Spad * 768 * 4);
  float* hfb  = (float*)alloc((size_t)Spad * 256 * 4);
  float* hbb  = (float*)alloc((size_t)Spad * 256 * 4);
  float* acmb = (float*)alloc((size_t)Spad * 512 * 4);
  float* segc = (float*)alloc((size_t)Spad * 512 * 4);
  float* segpos = (float*)alloc((size_t)Spad * 512 * 4);
  float* kin  = (float*)alloc((size_t)Spad * 512 * 4);
  float* kf2a = (float*)alloc((size_t)Spad * 512 * 4);
  float* vf2a = (float*)alloc((size_t)Spad * 512 * 4);
  float* q2   = (float*)alloc((size_t)Spad * 512 * 4);
  float* att2 = (float*)alloc((size_t)Spad * 512 * 4);
  float* seg2 = (float*)alloc((size_t)Spad * 512 * 4);
  float* vseg = (float*)alloc((size_t)Spad * 512 * 4);
  float* pbuf = (float*)alloc((size_t)64 * Spad * 4);
  float* qin  = (float*)alloc((size_t)64 * 512 * 4);
  float* qf2a = (float*)alloc((size_t)64 * 512 * 4);
  float* att1 = (float*)alloc((size_t)64 * 512 * 4);
  float* af0  = (float*)alloc((size_t)64 * 512 * 4);
  float* aggi = (float*)alloc((size_t)64 * 1536 * 4);
  float* afg  = (float*)alloc((size_t)64 * 512 * 4);
  float* k2in = (float*)alloc((size_t)64 * 512 * 4);
  float* k2   = (float*)alloc((size_t)64 * 512 * 4);
  float* v2   = (float*)alloc((size_t)64 * 512 * 4);
  float* vaf  = (float*)alloc((size_t)64 * 512 * 4);
  (void)ws_size; (void)in_sizes; (void)n_in;

  float* outp = (float*)d_out;
  float* out_ff   = outp;
  float* out_af   = outp + (size_t)TT * DD;
  float* out_fsim = out_af + (size_t)MM * DD;
  float* out_asim = out_fsim + (size_t)TT * CC;
  float* out_ssim = out_asim + (size_t)MM * CC;

  auto GR = [](long n) { return (unsigned)((n + 255) / 256); };
  const unsigned Sg = (unsigned)(Spad / 64);

  tnorm_k<<<1, 256, 0, stream>>>(in_text, tnorm);

  // NaN-prefill mailbox buffers (polled-data protocol)
  nanfill_k<<<128, 256, 0, stream>>>(hfb, (long)Spad * 256);
  nanfill_k<<<128, 256, 0, stream>>>(hbb, (long)Spad * 256);
  nanfill_k<<<32, 256, 0, stream>>>(afg, (long)64 * 512);

  // segmentation: folded projection (ff @ (Wf2c @ t_hat)) -> argmax
  prepM_k<<<64, 256, 0, stream>>>(Wf2c, bf2c, in_text, tnorm, Mmat, bdot);
  fargmax_k<<<TT / 8, 256, 0, stream>>>(in_ff, Mmat, bdot, pred);
  segscan_k<<<1, 256, 0, stream>>>(pred, segid, starts, centers, cnts);
  segmean_k<<<GR((long)S * 512), 256, 0, stream>>>(in_ff, starts, cnts, segmean, S);

  // seg BiGRU (NaN-poll mailbox, remote-only polling)
  gemmm_k<<<dim3(6, Sg), 256, 0, stream>>>(segmean, Wih_f, bih_f, gif, Spad, 768, 512);
  gemmm_k<<<dim3(6, Sg), 256, 0, stream>>>(segmean, Wih_b, bih_b, gib, Spad, 768, 512);
  gru_seg_mb_k<<<8, 192, 0, stream>>>(gif, gib, Whh_f, bhh_f, Whh_b, bhh_b, hfb, hbb, S);
  acomb_k<<<GR((long)S * 512), 256, 0, stream>>>(hfb, hbb, acmb, S * 512);
  gemmm_k<<<dim3(4, Sg), 256, 0, stream>>>(acmb, Wcomb, bcomb, segc, Spad, 512, 512);
  gatherpos_k<<<GR((long)S * 512), 256, 0, stream>>>(in_fpos, centers, segpos, S * 512);

  // f2a attention (actions query segments)
  addff_k<<<GR(64 * 512), 256, 0, stream>>>(in_act, in_apos, qin, 64 * 512);
  addff_k<<<GR((long)S * 512), 256, 0, stream>>>(segc, segpos, kin, S * 512);
  gemmm_k<<<dim3(4, 1), 256, 0, stream>>>(qin, f2a_Wq, nullptr, qf2a, 64, 512, 512);
  gemmm_k<<<dim3(4, Sg), 256, 0, stream>>>(kin, f2a_Wk, nullptr, kf2a, Spad, 512, 512);
  gemmm_k<<<dim3(4, Sg), 256, 0, stream>>>(segc, f2a_Wv, nullptr, vf2a, Spad, 512, 512);
  nlogit_k<<<GR((long)64 * S), 256, 0, stream>>>(qf2a, kf2a, pbuf, 64, S);
  nsoft_k<<<1, 256, 0, stream>>>(pbuf, 64, S);
  nav_k<<<GR(64 * 512), 256, 0, stream>>>(pbuf, vf2a, att1, 64, S);
  gemmm_k<<<dim3(4, 1), 256, 0, stream>>>(att1, f2a_Wo, f2a_bo, af0, 64, 512, 512);

  // action GRU (NaN-poll mailbox, grouped polling)
  gemmm_k<<<dim3(12, 1), 256, 0, stream>>>(af0, ag_Wih, ag_bih, aggi, 64, 1536, 512);
  gru_act_mb_k<<<16, 128, 0, stream>>>(aggi, ag_Whh, ag_bhh, afg, MM);
  copy_k<<<GR(64 * 512), 256, 0, stream>>>(afg, out_af, 64 * 512);

  // a2f attention (segments query actions)
  addff_k<<<GR(64 * 512), 256, 0, stream>>>(afg, in_apos, k2in, 64 * 512);
  gemmm_k<<<dim3(4, Sg), 256, 0, stream>>>(kin, a2f_Wq, nullptr, q2, Spad, 512, 512);
  gemmm_k<<<dim3(4, 1), 256, 0, stream>>>(k2in, a2f_Wk, nullptr, k2, 64, 512, 512);
  gemmm_k<<<dim3(4, 1), 256, 0, stream>>>(afg, a2f_Wv, nullptr, v2, 64, 512, 512);
  nlogit_k<<<GR((long)S * 64), 256, 0, stream>>>(q2, k2, pbuf, S, 64);
  nsoft_k<<<GR(S), 256, 0, stream>>>(pbuf, S, 64);
  nav_k<<<GR((long)S * 512), 256, 0, stream>>>(pbuf, v2, att2, S, 64);
  gemmm_k<<<dim3(4, Sg), 256, 0, stream>>>(att2, a2f_Wo, a2f_bo, seg2, Spad, 512, 512);

  // frame fusion + TCN (MFMA), ping-pong bufA <-> bufB as (D,T)
  ff2m_k<<<dim3(64, 8), 256, 0, stream>>>(seg2, in_ff, segid, Wsf, bsf, bufA, S);
  convm_k<1, 0, 0><<<dim3(64, 8), 256, 0, stream>>>(bufA, tcn_inW, tcn_inb, nullptr, bufB, 1);
  for (int l = 0; l < 6; l++) {
    convm_k<3, 1, 0><<<dim3(64, 8), 256, 0, stream>>>(
        bufB, tcn_dW + (size_t)l * 512 * 512 * 3, tcn_db + (size_t)l * 512, nullptr, bufA, 1 << l);
    convm_k<1, 0, 1><<<dim3(64, 8), 256, 0, stream>>>(
        bufA, tcn_pW + (size_t)l * 512 * 512, tcn_pb + (size_t)l * 512, bufB, bufB, 1);
  }
  convm_k<1, 0, 0><<<dim3(64, 8), 256, 0, stream>>>(bufB, tcn_outW, tcn_outb, nullptr, bufA, 1);
  temit_k<<<dim3(256, 16), 256, 0, stream>>>(bufA, out_ff, bufB);

  // similarity heads
  gemmm_k<<<dim3(4, 128), 256, 0, stream>>>(bufB, Wf2c, bf2c, bufA, TT, 512, 512);
  csim_k<<<TT, 256, 0, stream>>>(bufA, in_text, tnorm, out_fsim);
  gemmm_k<<<dim3(4, 1), 256, 0, stream>>>(afg, Wa2c, ba2c, vaf, 64, 512, 512);
  csim_k<<<64, 256, 0, stream>>>(vaf, in_text, tnorm, out_asim);
  gemmm_k<<<dim3(4, Sg), 256, 0, stream>>>(seg2, Ws2c, bs2c, vseg, Spad, 512, 512);
  csim_k<<<(unsigned)S, 256, 0, stream>>>(vseg, in_text, tnorm, out_ssim);
}

// Round 13
// 3760.720 us; speedup vs baseline: 1.1709x; 1.0055x over previous
//
#include <hip/hip_runtime.h>
#include <cstdint>
#include <cstddef>

__device__ __forceinline__ float sigf(float x) { return 1.f / (1.f + expf(-x)); }

__device__ __forceinline__ unsigned packh(float a, float b) {
  union { unsigned u; _Float16 h[2]; } cv;
  cv.h[0] = (_Float16)a; cv.h[1] = (_Float16)b; return cv.u;
}
__device__ __forceinline__ float2 uph(unsigned u) {
  union { unsigned uu; _Float16 h[2]; } cv; cv.uu = u;
  return make_float2((float)cv.h[0], (float)cv.h[1]);
}

typedef _Float16 f16x8 __attribute__((ext_vector_type(8)));
typedef float f32x16 __attribute__((ext_vector_type(16)));

static constexpr int TT = 8192;
static constexpr int MM = 64;
static constexpr int CC = 32;
static constexpr int DD = 512;
static constexpr unsigned GUARD_MAX = 1u << 30;
static constexpr unsigned HSENT = 0x7FC07FC0u;  // fp16 NaN pair sentinel

// --------------------------------------------------------------- fills
__global__ void nanfill_k(float* __restrict__ p, long n) {
  long i = (long)blockIdx.x * 256 + threadIdx.x;
  long stride = (long)gridDim.x * 256;
  const float qnan = __int_as_float(0x7fc00000);
  for (; i < n; i += stride) p[i] = qnan;
}
__global__ void sfill_k(unsigned* __restrict__ p, long n) {
  long i = (long)blockIdx.x * 256 + threadIdx.x;
  long stride = (long)gridDim.x * 256;
  for (; i < n; i += stride) p[i] = HSENT;
}

// ---------------------------------------------------------------- elementwise
__global__ void copy_k(const float* __restrict__ a, float* __restrict__ o, int n) {
  int i = blockIdx.x * 256 + threadIdx.x;
  if (i < n) o[i] = a[i];
}
__global__ void addff_k(const float* __restrict__ a, const float* __restrict__ b, float* __restrict__ o, int n) {
  int i = blockIdx.x * 256 + threadIdx.x;
  if (i < n) o[i] = a[i] + b[i];
}
// hf/hb are PACKED u32 fp16-pair mailboxes [Spad*128]
__global__ void acomb_k(const unsigned* __restrict__ hf, const unsigned* __restrict__ hb,
                        float* __restrict__ o, int n) {
  int i = blockIdx.x * 256 + threadIdx.x;
  if (i >= n) return;
  int s = i >> 9, j = i & 511;
  const unsigned pk = (j < 256) ? hf[(size_t)s * 128 + (j >> 1)]
                                : hb[(size_t)s * 128 + ((j - 256) >> 1)];
  const float2 two = uph(pk);
  const float v = (j & 1) ? two.y : two.x;
  o[i] = fmaxf(v, 0.f);
}
__global__ void gatherpos_k(const float* __restrict__ fpos, const int* __restrict__ centers,
                            float* __restrict__ segpos, int n) {
  int i = blockIdx.x * 256 + threadIdx.x;
  if (i >= n) return;
  int s = i >> 9, dd = i & 511;
  int ct = centers[s];
  ct = ct < 0 ? 0 : (ct > TT - 1 ? TT - 1 : ct);
  segpos[i] = fpos[(size_t)ct * 512 + dd];
}

// ---------------------------------------------------------------- text norms
__global__ void tnorm_k(const float* __restrict__ text, float* __restrict__ tnorm) {
  int c = blockIdx.x * 256 + threadIdx.x;
  if (c >= 32) return;
  float s = 0.f;
  for (int dd = 0; dd < 512; dd++) { float v = text[(size_t)c * 512 + dd]; s += v * v; }
  tnorm[c] = sqrtf(s);
}

// ---------------- fold argmax projection: M[k][c] = Wf2c[k,:]·(text_c/|t_c|)
__global__ void prepM_k(const float* __restrict__ W, const float* __restrict__ b,
                        const float* __restrict__ text, const float* __restrict__ tnorm,
                        float* __restrict__ M, float* __restrict__ bdot) {
  int idx = blockIdx.x * 256 + threadIdx.x;
  if (idx < 512 * 32) {
    int k = idx >> 5, c = idx & 31;
    const float* wr = W + (size_t)k * 512;
    const float* tr = text + (size_t)c * 512;
    float s = 0.f;
    for (int dd = 0; dd < 512; dd++) s += wr[dd] * tr[dd];
    M[idx] = s / tnorm[c];
  }
  if (idx < 32) {
    const float* tr = text + (size_t)idx * 512;
    float s = 0.f;
    for (int dd = 0; dd < 512; dd++) s += b[dd] * tr[dd];
    bdot[idx] = s / tnorm[idx];
  }
}

// 8 rows/block; lane c of each 32-group owns class c; shfl-argmax (min idx tie)
__launch_bounds__(256)
__global__ void fargmax_k(const float* __restrict__ ff, const float* __restrict__ M,
                          const float* __restrict__ bdot, int* __restrict__ pred) {
  const int r = blockIdx.x * 8 + (threadIdx.x >> 5);
  const int c = threadIdx.x & 31;
  const float* fr = ff + (size_t)r * 512;
  float acc = bdot[c];
  for (int k = 0; k < 512; k++) acc += fr[k] * M[k * 32 + c];
  float best = acc; int bidx = c;
  for (int off = 16; off >= 1; off >>= 1) {
    const float ov = __shfl_xor(best, off);
    const int oi = __shfl_xor(bidx, off);
    if (ov > best || (ov == best && oi < bidx)) { best = ov; bidx = oi; }
  }
  if (c == 0) pred[r] = bidx;
}

// ---------------------------------------------------- naive attention pieces
__global__ void nlogit_k(const float* __restrict__ Q, const float* __restrict__ Kk,
                         float* __restrict__ L, int NY, int NX) {
  int idx = blockIdx.x * 256 + threadIdx.x;
  if (idx >= NY * NX) return;
  int y = idx / NX, x = idx - y * NX;
  const float* qr = Q + (size_t)y * 512;
  const float* kr = Kk + (size_t)x * 512;
  float d = 0.f;
  for (int k = 0; k < 512; k++) d += qr[k] * kr[k];
  L[idx] = d * 0.044194173824159216f;
}
__global__ void nsoft_k(float* __restrict__ L, int NY, int NX) {
  int y = blockIdx.x * 256 + threadIdx.x;
  if (y >= NY) return;
  float* row = L + (size_t)y * NX;
  float m = row[0];
  for (int x = 1; x < NX; x++) m = fmaxf(m, row[x]);
  float s = 0.f;
  for (int x = 0; x < NX; x++) { float p = expf(row[x] - m); row[x] = p; s += p; }
  const float inv = 1.f / s;
  for (int x = 0; x < NX; x++) row[x] *= inv;
}
__global__ void nav_k(const float* __restrict__ P, const float* __restrict__ V,
                      float* __restrict__ O, int NY, int NX) {
  int idx = blockIdx.x * 256 + threadIdx.x;
  if (idx >= NY * 512) return;
  int y = idx >> 9, dd = idx & 511;
  const float* pr = P + (size_t)y * NX;
  float o = 0.f;
  for (int x = 0; x < NX; x++) o += pr[x] * V[(size_t)x * 512 + dd];
  O[idx] = o;
}

// ------------------------------- parallel run-length segmentation (one block)
__global__ void segscan_k(const int* __restrict__ pred, int* __restrict__ segid,
                          int* __restrict__ starts, int* __restrict__ centers,
                          int* __restrict__ cnts) {
  __shared__ int base[256];
  __shared__ int SS;
  const int tid = threadIdx.x;
  int lc = 0;
  unsigned flags = 0;
  int prev = (tid > 0) ? pred[tid * 32 - 1] : 0;
  for (int i = 0; i < 32; i++) {
    const int t = tid * 32 + i;
    const int cur = pred[t];
    const int c = (t > 0) && (cur != prev);
    prev = cur;
    flags |= ((unsigned)c) << i;
    lc += c;
  }
  base[tid] = lc;
  __syncthreads();
  if (tid == 0) {
    int run = 0;
    for (int i = 0; i < 256; i++) { const int v = base[i]; base[i] = run; run += v; }
    SS = run + 1;
  }
  __syncthreads();
  int b = base[tid];
  for (int i = 0; i < 32; i++) {
    const int t = tid * 32 + i;
    if ((flags >> i) & 1u) { b++; starts[b] = t; }
    segid[t] = b;
  }
  if (tid == 0) starts[0] = 0;
  __threadfence_block();
  __syncthreads();
  const int S = SS;
  for (int s = tid; s < TT; s += 256) {
    if (s < S) {
      const int e = (s == S - 1) ? (TT - 1) : (starts[s + 1] - 1);
      centers[s] = (starts[s] + e) >> 1;
      cnts[s] = e - starts[s] + 1;
    } else {
      starts[s] = 0; cnts[s] = 1; centers[s] = 0;
    }
  }
}

// ---------------------------------------------------------- segment mean pool
__global__ void segmean_k(const float* __restrict__ ff, const int* __restrict__ starts,
                          const int* __restrict__ cnts, float* __restrict__ segmean, int S) {
  int idx = blockIdx.x * 256 + threadIdx.x;
  if (idx >= S * 512) return;
  int s = idx >> 9, dd = idx & 511;
  int st = starts[s], n = cnts[s];
  st = st < 0 ? 0 : (st > TT - 1 ? TT - 1 : st);
  n = n < 1 ? 1 : n;
  if (st + n > TT) n = TT - st;
  float a = 0.f;
  for (int t = st; t < st + n; t++) a += ff[(size_t)t * 512 + dd];
  segmean[idx] = a / (float)n;
}

// ------------------- multi-block bidirectional seg GRU (H=256), LDS weights
// r0-verified compute core. r11 NaN-poll protocol; r12 remote-only polling;
// r13: PACKED u32 mailbox (fp16 pairs; sentinel HSENT=NaN:NaN). Writers
// shfl-pack and store 32 u32/partition; own h_old lives in a register;
// readers poll 96 remote u32 straight into hpk -- hcur array, the repack
// pass, and one sync per step are gone. Downstream consumes h at fp16
// precision, identical to the existing gemmm fp16 cast.
__launch_bounds__(192)
__global__ void gru_seg_mb_k(const float* __restrict__ gi_f, const float* __restrict__ gi_b,
                             const float* __restrict__ Whh_f, const float* __restrict__ bhh_f,
                             const float* __restrict__ Whh_b, const float* __restrict__ bhh_b,
                             unsigned* __restrict__ hf, unsigned* __restrict__ hb, int S) {
  const int dir = blockIdx.x >> 2;
  const int part = blockIdx.x & 3;
  const float* gi = dir ? gi_b : gi_f;
  const float* Whh = dir ? Whh_b : Whh_f;
  const float* bhh = dir ? bhh_b : bhh_f;
  unsigned* ho = dir ? hb : hf;
  const int tid = threadIdx.x;
  const int h0 = part * 64;
  const int w0 = h0 >> 1;           // word base of this partition (32 words)
  const int grp = tid >> 6;
  const int jj = tid & 63;
  const int j = grp * 256 + h0 + jj;
  __shared__ __align__(16) unsigned wlds[128 * 192];
  __shared__ __align__(16) unsigned hpk[128];
  __shared__ float rbuf[64], zbuf[64], gnbuf[64];
  for (int e = tid; e < 128 * 192; e += 192) {
    const int q = e / 768, rem = e % 768;
    const int g = rem >> 2, r = rem & 3;
    const int i2 = q * 4 + r;
    const int gg = (g >> 6) * 256 + h0 + (g & 63);
    wlds[e] = packh(Whh[(size_t)(2 * i2) * 768 + gg], Whh[(size_t)(2 * i2 + 1) * 768 + gg]);
  }
  for (int e = tid; e < 128; e += 192) hpk[e] = 0u;
  const float bj = bhh[j];
  float h_reg = 0.f;                // own h (threads 0..63)
  __syncthreads();
  const uint4* hp4 = reinterpret_cast<const uint4*>(hpk);
  const uint4* wp4 = reinterpret_cast<const uint4*>(wlds);
  // prefetch step 0 gi
  int s = dir ? (S - 1) : 0;
  float g_j = gi[(size_t)s * 768 + j];
  float g_n = (tid < 64) ? gi[(size_t)s * 768 + 512 + h0 + tid] : 0.f;
  for (int step = 0; step < S; step++) {
    float a0 = 0.f, a1 = 0.f, a2 = 0.f, a3 = 0.f;
#pragma unroll 8
    for (int q = 0; q < 32; q++) {
      const uint4 h4 = hp4[q];
      const uint4 w4 = wp4[q * 192 + tid];
      const float2 hh0 = uph(h4.x), hh1 = uph(h4.y), hh2 = uph(h4.z), hh3 = uph(h4.w);
      const float2 ww0 = uph(w4.x), ww1 = uph(w4.y), ww2 = uph(w4.z), ww3 = uph(w4.w);
      a0 += hh0.x * ww0.x + hh0.y * ww0.y;
      a1 += hh1.x * ww1.x + hh1.y * ww1.y;
      a2 += hh2.x * ww2.x + hh2.y * ww2.y;
      a3 += hh3.x * ww3.x + hh3.y * ww3.y;
    }
    const float gh = bj + (a0 + a1) + (a2 + a3);
    if (grp == 0)      rbuf[jj] = sigf(g_j + gh);
    else if (grp == 1) zbuf[jj] = sigf(g_j + gh);
    else               gnbuf[jj] = gh;
    __syncthreads();
    if (tid < 64) {
      const float nval = tanhf(g_n + rbuf[tid] * gnbuf[tid]);
      const float hn = (1.f - zbuf[tid]) * nval + zbuf[tid] * h_reg;
      h_reg = hn;
      const float hnb = __shfl_down(hn, 1);
      if ((tid & 1) == 0) {
        const unsigned pk = packh(hn, hnb);
        hpk[w0 + (tid >> 1)] = pk;                          // own words: LDS direct
        __hip_atomic_store(&ho[(size_t)s * 128 + w0 + (tid >> 1)], pk,
                           __ATOMIC_RELAXED, __HIP_MEMORY_SCOPE_AGENT);
      }
    }
    // prefetch next-step gi (overlaps peers' stores landing)
    const int sn = dir ? (s - 1) : (s + 1);
    if (step + 1 < S) {
      g_j = gi[(size_t)sn * 768 + j];
      if (tid < 64) g_n = gi[(size_t)sn * 768 + 512 + h0 + tid];
    }
    __syncthreads();
    // poll 96 REMOTE packed words straight into hpk (threads 0..95)
    if (tid < 96) {
      const int re = (tid < w0) ? tid : tid + 32;
      unsigned v = __hip_atomic_load(&ho[(size_t)s * 128 + re],
                                     __ATOMIC_RELAXED, __HIP_MEMORY_SCOPE_AGENT);
      unsigned guard = 0;
      while (v == HSENT && ++guard < GUARD_MAX) {
        __builtin_amdgcn_s_sleep(1);
        v = __hip_atomic_load(&ho[(size_t)s * 128 + re],
                              __ATOMIC_RELAXED, __HIP_MEMORY_SCOPE_AGENT);
      }
      hpk[re] = v;
    }
    __syncthreads();
    s = sn;
  }
}

// ------------------------- multi-block action GRU (H=512), LDS weights
// r11 NaN-poll protocol (fp32 mailbox: afg is an output, precision kept);
// r13: own h in register, owners write their hpk words directly, poll phase
// packs remote groups straight into hpk -- hcur + repack + one sync removed.
__launch_bounds__(128)
__global__ void gru_act_mb_k(const float* __restrict__ gi, const float* __restrict__ Whh,
                             const float* __restrict__ bhh, float* __restrict__ hout,
                             int steps) {
  const int part = blockIdx.x;
  const int tid = threadIdx.x;
  const int h0 = part * 32;
  const int grp = tid >> 5;
  const int jj = tid & 31;
  const bool act = (tid < 96);
  const int j = act ? (grp * 512 + h0 + jj) : 0;
  __shared__ __align__(16) unsigned wlds[256 * 96];
  __shared__ __align__(16) unsigned hpk[256];
  __shared__ float rbuf[32], zbuf[32], gnbuf[32];
  for (int e = tid; e < 256 * 96; e += 128) {
    const int q = e / 384, rem = e % 384;
    const int g = rem >> 2, r = rem & 3;
    const int i2 = q * 4 + r;
    const int gg = (g >> 5) * 512 + h0 + (g & 31);
    wlds[e] = packh(Whh[(size_t)(2 * i2) * 1536 + gg], Whh[(size_t)(2 * i2 + 1) * 1536 + gg]);
  }
  for (int e = tid; e < 256; e += 128) hpk[e] = 0u;
  const float bj = act ? bhh[j] : 0.f;
  float h_reg = 0.f;                // own h (threads 0..31)
  __syncthreads();
  const uint4* hp4 = reinterpret_cast<const uint4*>(hpk);
  const uint4* wp4 = reinterpret_cast<const uint4*>(wlds);
  float g_j = act ? gi[j] : 0.f;
  float g_n = (tid < 32) ? gi[1024 + h0 + tid] : 0.f;
  const int gown0 = h0 >> 2;            // own float4 groups [gown0, gown0+8)
  for (int step = 0; step < steps; step++) {
    if (act) {
      float a0 = 0.f, a1 = 0.f, a2 = 0.f, a3 = 0.f;
#pragma unroll 8
      for (int q = 0; q < 64; q++) {
        const uint4 h4 = hp4[q];
        const uint4 w4 = wp4[q * 96 + tid];
        const float2 hh0 = uph(h4.x), hh1 = uph(h4.y), hh2 = uph(h4.z), hh3 = uph(h4.w);
        const float2 ww0 = uph(w4.x), ww1 = uph(w4.y), ww2 = uph(w4.z), ww3 = uph(w4.w);
        a0 += hh0.x * ww0.x + hh0.y * ww0.y;
        a1 += hh1.x * ww1.x + hh1.y * ww1.y;
        a2 += hh2.x * ww2.x + hh2.y * ww2.y;
        a3 += hh3.x * ww3.x + hh3.y * ww3.y;
      }
      const float gh = bj + (a0 + a1) + (a2 + a3);
      if (grp == 0)      rbuf[jj] = sigf(g_j + gh);
      else if (grp == 1) zbuf[jj] = sigf(g_j + gh);
      else               gnbuf[jj] = gh;
    }
    __syncthreads();
    if (tid < 32) {
      const float nval = tanhf(g_n + rbuf[tid] * gnbuf[tid]);
      const float hn = (1.f - zbuf[tid]) * nval + zbuf[tid] * h_reg;
      h_reg = hn;
      __hip_atomic_store(&hout[(size_t)step * 512 + h0 + tid], hn,
                         __ATOMIC_RELAXED, __HIP_MEMORY_SCOPE_AGENT);
      const float hnb = __shfl_down(hn, 1);
      if ((tid & 1) == 0) hpk[(h0 + tid) >> 1] = packh(hn, hnb);  // own words
    }
    if (step + 1 < steps) {
      if (act) g_j = gi[(size_t)(step + 1) * 1536 + j];
      if (tid < 32) g_n = gi[(size_t)(step + 1) * 1536 + 1024 + h0 + tid];
    }
    __syncthreads();
    // poll remote groups (4-wide) straight into hpk; own groups done above
    {
      const int g = tid;  // 0..127 covers all 128 groups of 4
      if (g < gown0 || g >= gown0 + 8) {
        const float* gp = hout + (size_t)step * 512 + 4 * g;
        float x0, x1, x2, x3;
        unsigned guard = 0;
        do {
          x0 = __hip_atomic_load(gp + 0, __ATOMIC_RELAXED, __HIP_MEMORY_SCOPE_AGENT);
          x1 = __hip_atomic_load(gp + 1, __ATOMIC_RELAXED, __HIP_MEMORY_SCOPE_AGENT);
          x2 = __hip_atomic_load(gp + 2, __ATOMIC_RELAXED, __HIP_MEMORY_SCOPE_AGENT);
          x3 = __hip_atomic_load(gp + 3, __ATOMIC_RELAXED, __HIP_MEMORY_SCOPE_AGENT);
          if (x0 == x0 && x1 == x1 && x2 == x2 && x3 == x3) break;
          __builtin_amdgcn_s_sleep(1);
        } while (++guard < GUARD_MAX);
        hpk[2 * g + 0] = packh(x0, x1);
        hpk[2 * g + 1] = packh(x2, x3);
      }
    }
    __syncthreads();
  }
}

// ------------------------------------------------ MFMA GEMM (fp16 staged)
// C[M,N] = A[M,K] @ B[K,N] + bias.  Tile M64 x N128, K-chunk 64.
__launch_bounds__(256)
__global__ void gemmm_k(const float* __restrict__ A, const float* __restrict__ B,
                        const float* __restrict__ bias, float* __restrict__ C,
                        int M, int N, int K) {
  __shared__ __align__(16) _Float16 As16[64][72];
  __shared__ __align__(16) _Float16 Bs16[128][72];
  const int n0 = blockIdx.x * 128, m0 = blockIdx.y * 64;
  const int tid = threadIdx.x;
  const int l = tid & 63, w = tid >> 6;
  const int wm = w & 1, wn = w >> 1;
  const int l31 = l & 31, q = l >> 5;
  f32x16 acc0, acc1;
#pragma unroll
  for (int i = 0; i < 16; i++) { acc0[i] = 0.f; acc1[i] = 0.f; }
  const int am = tid >> 2, ak0 = (tid & 3) * 16;
  const int bk = tid >> 2, bn0 = (tid & 3) * 32;
  for (int kc = 0; kc < K; kc += 64) {
    __syncthreads();
#pragma unroll
    for (int kk = 0; kk < 16; kk += 4) {
      const float4 av = *reinterpret_cast<const float4*>(A + (size_t)(m0 + am) * K + kc + ak0 + kk);
      As16[am][ak0 + kk + 0] = (_Float16)av.x; As16[am][ak0 + kk + 1] = (_Float16)av.y;
      As16[am][ak0 + kk + 2] = (_Float16)av.z; As16[am][ak0 + kk + 3] = (_Float16)av.w;
    }
#pragma unroll
    for (int nn = 0; nn < 32; nn += 4) {
      const float4 bv = *reinterpret_cast<const float4*>(B + (size_t)(kc + bk) * N + n0 + bn0 + nn);
      Bs16[bn0 + nn + 0][bk] = (_Float16)bv.x; Bs16[bn0 + nn + 1][bk] = (_Float16)bv.y;
      Bs16[bn0 + nn + 2][bk] = (_Float16)bv.z; Bs16[bn0 + nn + 3][bk] = (_Float16)bv.w;
    }
    __syncthreads();
#pragma unroll
    for (int ks = 0; ks < 4; ks++) {
      const int k0 = ks * 16 + q * 8;
      const f16x8 a = *reinterpret_cast<const f16x8*>(&As16[wm * 32 + l31][k0]);
      const f16x8 b0 = *reinterpret_cast<const f16x8*>(&Bs16[wn * 64 + l31][k0]);
      acc0 = __builtin_amdgcn_mfma_f32_32x32x16_f16(a, b0, acc0, 0, 0, 0);
      const f16x8 b1 = *reinterpret_cast<const f16x8*>(&Bs16[wn * 64 + 32 + l31][k0]);
      acc1 = __builtin_amdgcn_mfma_f32_32x32x16_f16(a, b1, acc1, 0, 0, 0);
    }
  }
#pragma unroll
  for (int r = 0; r < 16; r++) {
    const int m = m0 + wm * 32 + (r & 3) + 8 * (r >> 2) + 4 * q;
    {
      const int n = n0 + wn * 64 + l31;
      float v = acc0[r];
      if (bias) v += bias[n];
      C[(size_t)m * N + n] = v;
    }
    {
      const int n = n0 + wn * 64 + 32 + l31;
      float v = acc1[r];
      if (bias) v += bias[n];
      C[(size_t)m * N + n] = v;
    }
  }
}

// ------------------- MFMA ff2: Y(D,T) = relu([seg2[sid[t]], ff[t]] @ Wsf + b)^T
__launch_bounds__(256)
__global__ void ff2m_k(const float* __restrict__ seg2, const float* __restrict__ ff,
                       const int* __restrict__ segid, const float* __restrict__ Wsf,
                       const float* __restrict__ bsf, float* __restrict__ Y, int S) {
  __shared__ __align__(16) _Float16 As16[64][72];    // [dim][k]
  __shared__ __align__(16) _Float16 Bs16[128][72];   // [frame][k]
  const int t0 = blockIdx.x * 128, nd0 = blockIdx.y * 64;
  const int tid = threadIdx.x;
  const int l = tid & 63, w = tid >> 6;
  const int wm = w & 1, wn = w >> 1;
  const int l31 = l & 31, q = l >> 5;
  f32x16 acc0, acc1;
#pragma unroll
  for (int i = 0; i < 16; i++) { acc0[i] = 0.f; acc1[i] = 0.f; }
  const int ak = tid >> 2, an0 = (tid & 3) * 16;
  const int bt = tid >> 1, bk0 = (tid & 1) * 32;
  const int tglob = t0 + bt;
  int sid = segid[tglob];
  sid = sid < 0 ? 0 : (sid >= S ? S - 1 : sid);
  for (int kc = 0; kc < 1024; kc += 64) {
    __syncthreads();
#pragma unroll
    for (int nn = 0; nn < 16; nn += 4) {
      const float4 wv = *reinterpret_cast<const float4*>(Wsf + (size_t)(kc + ak) * 512 + nd0 + an0 + nn);
      As16[an0 + nn + 0][ak] = (_Float16)wv.x; As16[an0 + nn + 1][ak] = (_Float16)wv.y;
      As16[an0 + nn + 2][ak] = (_Float16)wv.z; As16[an0 + nn + 3][ak] = (_Float16)wv.w;
    }
    {
      const float* src = (kc < 512) ? (seg2 + (size_t)sid * 512 + kc + bk0)
                                    : (ff + (size_t)tglob * 512 + (kc - 512) + bk0);
#pragma unroll
      for (int kk = 0; kk < 32; kk += 4) {
        const float4 xv = *reinterpret_cast<const float4*>(src + kk);
        Bs16[bt][bk0 + kk + 0] = (_Float16)xv.x; Bs16[bt][bk0 + kk + 1] = (_Float16)xv.y;
        Bs16[bt][bk0 + kk + 2] = (_Float16)xv.z; Bs16[bt][bk0 + kk + 3] = (_Float16)xv.w;
      }
    }
    __syncthreads();
#pragma unroll
    for (int ks = 0; ks < 4; ks++) {
      const int k0 = ks * 16 + q * 8;
      const f16x8 a = *reinterpret_cast<const f16x8*>(&As16[wm * 32 + l31][k0]);
      const f16x8 b0 = *reinterpret_cast<const f16x8*>(&Bs16[wn * 64 + l31][k0]);
      acc0 = __builtin_amdgcn_mfma_f32_32x32x16_f16(a, b0, acc0, 0, 0, 0);
      const f16x8 b1 = *reinterpret_cast<const f16x8*>(&Bs16[wn * 64 + 32 + l31][k0]);
      acc1 = __builtin_amdgcn_mfma_f32_32x32x16_f16(a, b1, acc1, 0, 0, 0);
    }
  }
#pragma unroll
  for (int r = 0; r < 16; r++) {
    const int nd = nd0 + wm * 32 + (r & 3) + 8 * (r >> 2) + 4 * q;
    const float bb = bsf[nd];
    {
      const int t = t0 + wn * 64 + l31;
      Y[(size_t)nd * TT + t] = fmaxf(acc0[r] + bb, 0.f);
    }
    {
      const int t = t0 + wn * 64 + 32 + l31;
      Y[(size_t)nd * TT + t] = fmaxf(acc1[r] + bb, 0.f);
    }
  }
}

// --------------------------------------------------- MFMA TCN conv (fp16 in)
template<int NTAPS, int RELU, int RES>
__launch_bounds__(256)
__global__ void convm_k(const float* __restrict__ X, const float* __restrict__ W,
                        const float* __restrict__ bias, const float* __restrict__ Res,
                        float* __restrict__ Y, int dil) {
  const int d = (NTAPS == 3) ? dil : 0;
  const int width = 128 + 2 * d;
  __shared__ __align__(16) _Float16 Ws16[NTAPS][64][72];
  __shared__ __align__(16) _Float16 Xs16[192][72];
  const int t0 = blockIdx.x * 128, c0 = blockIdx.y * 64;
  const int tid = threadIdx.x;
  const int l = tid & 63, w = tid >> 6;
  const int wm = w & 1, wn = w >> 1;
  const int l31 = l & 31, q = l >> 5;
  f32x16 acc0, acc1;
#pragma unroll
  for (int i = 0; i < 16; i++) { acc0[i] = 0.f; acc1[i] = 0.f; }
  const int xk = tid >> 2;
  const int xu0 = tid & 3;
  for (int kc = 0; kc < 512; kc += 64) {
    __syncthreads();
    {
      const float* xr = X + (size_t)(kc + xk) * TT;
      for (int u = xu0; u < width; u += 4) {
        const int gt = t0 - d + u;
        const float v = (gt >= 0 && gt < TT) ? xr[gt] : 0.f;
        Xs16[u][xk] = (_Float16)v;
      }
    }
    if (NTAPS == 3) {
      for (int e = tid; e < 64 * 48; e += 256) {
        const int c = e / 48;
        const int f0 = (e - c * 48) * 4;
        const float4 wv = *reinterpret_cast<const float4*>(
            W + (size_t)(c0 + c) * 1536 + (size_t)kc * 3 + f0);
        const float vv[4] = {wv.x, wv.y, wv.z, wv.w};
#pragma unroll
        for (int t = 0; t < 4; t++) {
          const int f = f0 + t;
          Ws16[f % 3][c][f / 3] = (_Float16)vv[t];
        }
      }
    } else {
      for (int e = tid; e < 1024; e += 256) {
        const int c = e >> 4, i0 = (e & 15) << 2;
        const float4 wv = *reinterpret_cast<const float4*>(W + (size_t)(c0 + c) * 512 + kc + i0);
        Ws16[0][c][i0 + 0] = (_Float16)wv.x; Ws16[0][c][i0 + 1] = (_Float16)wv.y;
        Ws16[0][c][i0 + 2] = (_Float16)wv.z; Ws16[0][c][i0 + 3] = (_Float16)wv.w;
      }
    }
    __syncthreads();
#pragma unroll
    for (int tap = 0; tap < NTAPS; tap++) {
#pragma unroll
      for (int ks = 0; ks < 4; ks++) {
        const int k0 = ks * 16 + q * 8;
        const f16x8 a = *reinterpret_cast<const f16x8*>(&Ws16[tap][wm * 32 + l31][k0]);
        const int row0 = wn * 64 + l31 + tap * d;
        const f16x8 b0 = *reinterpret_cast<const f16x8*>(&Xs16[row0][k0]);
        acc0 = __builtin_amdgcn_mfma_f32_32x32x16_f16(a, b0, acc0, 0, 0, 0);
        const f16x8 b1 = *reinterpret_cast<const f16x8*>(&Xs16[row0 + 32][k0]);
        acc1 = __builtin_amdgcn_mfma_f32_32x32x16_f16(a, b1, acc1, 0, 0, 0);
      }
    }
  }
#pragma unroll
  for (int r = 0; r < 16; r++) {
    const int m = wm * 32 + (r & 3) + 8 * (r >> 2) + 4 * q;
    const int c = c0 + m;
    const float bb = bias[c];
    {
      const int t = t0 + wn * 64 + l31;
      float v = acc0[r] + bb;
      if (RES) v += Res[(size_t)c * TT + t];
      if (RELU) v = fmaxf(v, 0.f);
      Y[(size_t)c * TT + t] = v;
    }
    {
      const int t = t0 + wn * 64 + 32 + l31;
      float v = acc1[r] + bb;
      if (RES) v += Res[(size_t)c * TT + t];
      if (RELU) v = fmaxf(v, 0.f);
      Y[(size_t)c * TT + t] = v;
    }
  }
}

// -------------------- tiled transpose (512,T) -> out (T,512) + f32 copy (T,512)
__launch_bounds__(256)
__global__ void temit_k(const float* __restrict__ Xin, float* __restrict__ outp,
                        float* __restrict__ Aout) {
  __shared__ float tile[32][33];
  const int t0 = blockIdx.x * 32, d0 = blockIdx.y * 32;
  const int lx = threadIdx.x & 31, ly = threadIdx.x >> 5;
#pragma unroll
  for (int r = 0; r < 4; r++)
    tile[ly + 8 * r][lx] = Xin[(size_t)(d0 + ly + 8 * r) * TT + t0 + lx];
  __syncthreads();
#pragma unroll
  for (int r = 0; r < 4; r++) {
    const int t = t0 + ly + 8 * r, dd = d0 + lx;
    const float v = tile[lx][ly + 8 * r];
    outp[(size_t)t * 512 + dd] = v;
    Aout[(size_t)t * 512 + dd] = v;
  }
}

// --------------------------- cosine sim, block per row (||v|| computed once)
__launch_bounds__(256)
__global__ void csim_k(const float* __restrict__ V, const float* __restrict__ text,
                       const float* __restrict__ tnorm, float* __restrict__ out) {
  __shared__ float vs[512];
  __shared__ float red[4];
  const int r = blockIdx.x, tid = threadIdx.x;
  const float a = V[(size_t)r * 512 + tid];
  const float b = V[(size_t)r * 512 + 256 + tid];
  vs[tid] = a; vs[tid + 256] = b;
  float ssp = a * a + b * b;
  for (int off = 32; off >= 1; off >>= 1) ssp += __shfl_xor(ssp, off);
  if ((tid & 63) == 0) red[tid >> 6] = ssp;
  __syncthreads();
  const float ss = red[0] + red[1] + red[2] + red[3];
  const int c = tid >> 3, p = tid & 7;
  const float* tr = text + (size_t)c * 512 + p * 64;
  const float* vr = vs + p * 64;
  float d = 0.f;
#pragma unroll
  for (int k = 0; k < 64; k++) d += vr[k] * tr[k];
  for (int off = 4; off >= 1; off >>= 1) d += __shfl_xor(d, off);
  if (p == 0) out[(size_t)r * 32 + c] = d / (sqrtf(ss) * tnorm[c]);
}

// ======================================================================= host
extern "C" void kernel_launch(void* const* d_in, const int* in_sizes, int n_in,
                              void* d_out, int out_size, void* d_ws, size_t ws_size,
                              hipStream_t stream) {
  const float* in_ff   = (const float*)d_in[0];
  const float* in_act  = (const float*)d_in[1];
  const float* in_fpos = (const float*)d_in[2];
  const float* in_apos = (const float*)d_in[3];
  const float* in_text = (const float*)d_in[4];
  const float* Wf2c = (const float*)d_in[5];  const float* bf2c = (const float*)d_in[6];
  const float* Wa2c = (const float*)d_in[7];  const float* ba2c = (const float*)d_in[8];
  const float* Ws2c = (const float*)d_in[9];  const float* bs2c = (const float*)d_in[10];
  const float* Wih_f = (const float*)d_in[11]; const float* Whh_f = (const float*)d_in[12];
  const float* bih_f = (const float*)d_in[13]; const float* bhh_f = (const float*)d_in[14];
  const float* Wih_b = (const float*)d_in[15]; const float* Whh_b = (const float*)d_in[16];
  const float* bih_b = (const float*)d_in[17]; const float* bhh_b = (const float*)d_in[18];
  const float* Wcomb = (const float*)d_in[19]; const float* bcomb = (const float*)d_in[20];
  const float* f2a_Wq = (const float*)d_in[21]; const float* f2a_Wk = (const float*)d_in[22];
  const float* f2a_Wv = (const float*)d_in[23]; const float* f2a_Wo = (const float*)d_in[24];
  const float* f2a_bo = (const float*)d_in[25];
  const float* ag_Wih = (const float*)d_in[26]; const float* ag_Whh = (const float*)d_in[27];
  const float* ag_bih = (const float*)d_in[28]; const float* ag_bhh = (const float*)d_in[29];
  const float* a2f_Wq = (const float*)d_in[30]; const float* a2f_Wk = (const float*)d_in[31];
  const float* a2f_Wv = (const float*)d_in[32]; const float* a2f_Wo = (const float*)d_in[33];
  const float* a2f_bo = (const float*)d_in[34];
  const float* Wsf = (const float*)d_in[35]; const float* bsf = (const float*)d_in[36];
  const float* tcn_inW = (const float*)d_in[37]; const float* tcn_inb = (const float*)d_in[38];
  const float* tcn_dW = (const float*)d_in[39]; const float* tcn_db = (const float*)d_in[40];
  const float* tcn_pW = (const float*)d_in[41]; const float* tcn_pb = (const float*)d_in[42];
  const float* tcn_outW = (const float*)d_in[43]; const float* tcn_outb = (const float*)d_in[44];

  int S = (out_size - (TT * DD + MM * DD + TT * CC + MM * CC)) / CC;
  if (S < 1) S = 1;
  if (S > TT) S = TT;
  const int Spad = (S + 63) & ~63;

  char* ws = (char*)d_ws;
  size_t off = 0;
  auto alloc = [&](size_t b) -> char* { char* p = ws + off; off += (b + 255) & ~(size_t)255; return p; };
  float* Mmat = (float*)alloc((size_t)512 * 32 * 4);
  float* bdot = (float*)alloc(32 * 4);
  const size_t BTD = (size_t)TT * DD * 4;
  float* bufA = (float*)alloc(BTD);
  float* bufB = (float*)alloc(BTD);
  int* pred    = (int*)alloc((size_t)TT * 4);
  int* segid   = (int*)alloc((size_t)TT * 4);
  int* starts  = (int*)alloc((size_t)TT * 4);
  int* centers = (int*)alloc((size_t)TT * 4);
  int* cnts    = (int*)alloc((size_t)TT * 4);
  float* tnorm = (float*)alloc(32 * 4);
  float* segmean = (float*)alloc((size_t)Spad * 512 * 4);
  float* gif  = (float*)alloc((size_t)Spad * 768 * 4);
  float* gib  = (float*)alloc((size_t)Spad * 768 * 4);
  unsigned* hfb = (unsigned*)alloc((size_t)Spad * 128 * 4);   // packed fp16 pairs
  unsigned* hbb = (unsigned*)alloc((size_t)Spad * 128 * 4);   // packed fp16 pairs
  float* acmb = (float*)alloc((size_t)Spad * 512 * 4);
  float* segc = (float*)alloc((size_t)Spad * 512 * 4);
  float* segpos = (float*)alloc((size_t)Spad * 512 * 4);
  float* kin  = (float*)alloc((size_t)Spad * 512 * 4);
  float* kf2a = (float*)alloc((size_t)Spad * 512 * 4);
  float* vf2a = (float*)alloc((size_t)Spad * 512 * 4);
  float* q2   = (float*)alloc((size_t)Spad * 512 * 4);
  float* att2 = (float*)alloc((size_t)Spad * 512 * 4);
  float* seg2 = (float*)alloc((size_t)Spad * 512 * 4);
  float* vseg = (float*)alloc((size_t)Spad * 512 * 4);
  float* pbuf = (float*)alloc((size_t)64 * Spad * 4);
  float* qin  = (float*)alloc((size_t)64 * 512 * 4);
  float* qf2a = (float*)alloc((size_t)64 * 512 * 4);
  float* att1 = (float*)alloc((size_t)64 * 512 * 4);
  float* af0  = (float*)alloc((size_t)64 * 512 * 4);
  float* aggi = (float*)alloc((size_t)64 * 1536 * 4);
  float* afg  = (float*)alloc((size_t)64 * 512 * 4);
  float* k2in = (float*)alloc((size_t)64 * 512 * 4);
  float* k2   = (float*)alloc((size_t)64 * 512 * 4);
  float* v2   = (float*)alloc((size_t)64 * 512 * 4);
  float* vaf  = (float*)alloc((size_t)64 * 512 * 4);
  (void)ws_size; (void)in_sizes; (void)n_in;

  float* outp = (float*)d_out;
  float* out_ff   = outp;
  float* out_af   = outp + (size_t)TT * DD;
  float* out_fsim = out_af + (size_t)MM * DD;
  float* out_asim = out_fsim + (size_t)TT * CC;
  float* out_ssim = out_asim + (size_t)MM * CC;

  auto GR = [](long n) { return (unsigned)((n + 255) / 256); };
  const unsigned Sg = (unsigned)(Spad / 64);

  tnorm_k<<<1, 256, 0, stream>>>(in_text, tnorm);

  // prefill mailboxes (sentinel-poll protocol)
  sfill_k<<<64, 256, 0, stream>>>(hfb, (long)Spad * 128);
  sfill_k<<<64, 256, 0, stream>>>(hbb, (long)Spad * 128);
  nanfill_k<<<32, 256, 0, stream>>>(afg, (long)64 * 512);

  // segmentation: folded projection (ff @ (Wf2c @ t_hat)) -> argmax
  prepM_k<<<64, 256, 0, stream>>>(Wf2c, bf2c, in_text, tnorm, Mmat, bdot);
  fargmax_k<<<TT / 8, 256, 0, stream>>>(in_ff, Mmat, bdot, pred);
  segscan_k<<<1, 256, 0, stream>>>(pred, segid, starts, centers, cnts);
  segmean_k<<<GR((long)S * 512), 256, 0, stream>>>(in_ff, starts, cnts, segmean, S);

  // seg BiGRU (packed-u32 sentinel-poll mailbox)
  gemmm_k<<<dim3(6, Sg), 256, 0, stream>>>(segmean, Wih_f, bih_f, gif, Spad, 768, 512);
  gemmm_k<<<dim3(6, Sg), 256, 0, stream>>>(segmean, Wih_b, bih_b, gib, Spad, 768, 512);
  gru_seg_mb_k<<<8, 192, 0, stream>>>(gif, gib, Whh_f, bhh_f, Whh_b, bhh_b, hfb, hbb, S);
  acomb_k<<<GR((long)S * 512), 256, 0, stream>>>(hfb, hbb, acmb, S * 512);
  gemmm_k<<<dim3(4, Sg), 256, 0, stream>>>(acmb, Wcomb, bcomb, segc, Spad, 512, 512);
  gatherpos_k<<<GR((long)S * 512), 256, 0, stream>>>(in_fpos, centers, segpos, S * 512);

  // f2a attention (actions query segments)
  addff_k<<<GR(64 * 512), 256, 0, stream>>>(in_act, in_apos, qin, 64 * 512);
  addff_k<<<GR((long)S * 512), 256, 0, stream>>>(segc, segpos, kin, S * 512);
  gemmm_k<<<dim3(4, 1), 256, 0, stream>>>(qin, f2a_Wq, nullptr, qf2a, 64, 512, 512);
  gemmm_k<<<dim3(4, Sg), 256, 0, stream>>>(kin, f2a_Wk, nullptr, kf2a, Spad, 512, 512);
  gemmm_k<<<dim3(4, Sg), 256, 0, stream>>>(segc, f2a_Wv, nullptr, vf2a, Spad, 512, 512);
  nlogit_k<<<GR((long)64 * S), 256, 0, stream>>>(qf2a, kf2a, pbuf, 64, S);
  nsoft_k<<<1, 256, 0, stream>>>(pbuf, 64, S);
  nav_k<<<GR(64 * 512), 256, 0, stream>>>(pbuf, vf2a, att1, 64, S);
  gemmm_k<<<dim3(4, 1), 256, 0, stream>>>(att1, f2a_Wo, f2a_bo, af0, 64, 512, 512);

  // action GRU (NaN-poll mailbox, register h, folded repack)
  gemmm_k<<<dim3(12, 1), 256, 0, stream>>>(af0, ag_Wih, ag_bih, aggi, 64, 1536, 512);
  gru_act_mb_k<<<16, 128, 0, stream>>>(aggi, ag_Whh, ag_bhh, afg, MM);
  copy_k<<<GR(64 * 512), 256, 0, stream>>>(afg, out_af, 64 * 512);

  // a2f attention (segments query actions)
  addff_k<<<GR(64 * 512), 256, 0, stream>>>(afg, in_apos, k2in, 64 * 512);
  gemmm_k<<<dim3(4, Sg), 256, 0, stream>>>(kin, a2f_Wq, nullptr, q2, Spad, 512, 512);
  gemmm_k<<<dim3(4, 1), 256, 0, stream>>>(k2in, a2f_Wk, nullptr, k2, 64, 512, 512);
  gemmm_k<<<dim3(4, 1), 256, 0, stream>>>(afg, a2f_Wv, nullptr, v2, 64, 512, 512);
  nlogit_k<<<GR((long)S * 64), 256, 0, stream>>>(q2, k2, pbuf, S, 64);
  nsoft_k<<<GR(S), 256, 0, stream>>>(pbuf, S, 64);
  nav_k<<<GR((long)S * 512), 256, 0, stream>>>(pbuf, v2, att2, S, 64);
  gemmm_k<<<dim3(4, Sg), 256, 0, stream>>>(att2, a2f_Wo, a2f_bo, seg2, Spad, 512, 512);

  // frame fusion + TCN (MFMA), ping-pong bufA <-> bufB as (D,T)
  ff2m_k<<<dim3(64, 8), 256, 0, stream>>>(seg2, in_ff, segid, Wsf, bsf, bufA, S);
  convm_k<1, 0, 0><<<dim3(64, 8), 256, 0, stream>>>(bufA, tcn_inW, tcn_inb, nullptr, bufB, 1);
  for (int l = 0; l < 6; l++) {
    convm_k<3, 1, 0><<<dim3(64, 8), 256, 0, stream>>>(
        bufB, tcn_dW + (size_t)l * 512 * 512 * 3, tcn_db + (size_t)l * 512, nullptr, bufA, 1 << l);
    convm_k<1, 0, 1><<<dim3(64, 8), 256, 0, stream>>>(
        bufA, tcn_pW + (size_t)l * 512 * 512, tcn_pb + (size_t)l * 512, bufB, bufB, 1);
  }
  convm_k<1, 0, 0><<<dim3(64, 8), 256, 0, stream>>>(bufB, tcn_outW, tcn_outb, nullptr, bufA, 1);
  temit_k<<<dim3(256, 16), 256, 0, stream>>>(bufA, out_ff, bufB);

  // similarity heads
  gemmm_k<<<dim3(4, 128), 256, 0, stream>>>(bufB, Wf2c, bf2c, bufA, TT, 512, 512);
  csim_k<<<TT, 256, 0, stream>>>(bufA, in_text, tnorm, out_fsim);
  gemmm_k<<<dim3(4, 1), 256, 0, stream>>>(afg, Wa2c, ba2c, vaf, 64, 512, 512);
  csim_k<<<64, 256, 0, stream>>>(vaf, in_text, tnorm, out_asim);
  gemmm_k<<<dim3(4, Sg), 256, 0, stream>>>(seg2, Ws2c, bs2c, vseg, Spad, 512, 512);
  csim_k<<<(unsigned)S, 256, 0, stream>>>(vseg, in_text, tnorm, out_ssim);
}

// Round 14
// 3416.970 us; speedup vs baseline: 1.2887x; 1.1006x over previous
//
#include <hip/hip_runtime.h>
#include <cstdint>
#include <cstddef>

__device__ __forceinline__ float sigf(float x) { return 1.f / (1.f + expf(-x)); }

__device__ __forceinline__ unsigned packh(float a, float b) {
  union { unsigned u; _Float16 h[2]; } cv;
  cv.h[0] = (_Float16)a; cv.h[1] = (_Float16)b; return cv.u;
}
__device__ __forceinline__ float2 uph(unsigned u) {
  union { unsigned uu; _Float16 h[2]; } cv; cv.uu = u;
  return make_float2((float)cv.h[0], (float)cv.h[1]);
}

typedef _Float16 f16x8 __attribute__((ext_vector_type(8)));
typedef float f32x16 __attribute__((ext_vector_type(16)));

static constexpr int TT = 8192;
static constexpr int MM = 64;
static constexpr int CC = 32;
static constexpr int DD = 512;
static constexpr unsigned GUARD_MAX = 1u << 30;
static constexpr unsigned HSENT = 0x7FC07FC0u;  // fp16 NaN pair sentinel

// --------------------------------------------------------------- fills
__global__ void nanfill_k(float* __restrict__ p, long n) {
  long i = (long)blockIdx.x * 256 + threadIdx.x;
  long stride = (long)gridDim.x * 256;
  const float qnan = __int_as_float(0x7fc00000);
  for (; i < n; i += stride) p[i] = qnan;
}
__global__ void sfill_k(unsigned* __restrict__ p, long n) {
  long i = (long)blockIdx.x * 256 + threadIdx.x;
  long stride = (long)gridDim.x * 256;
  for (; i < n; i += stride) p[i] = HSENT;
}

// ---------------------------------------------------------------- elementwise
__global__ void copy_k(const float* __restrict__ a, float* __restrict__ o, int n) {
  int i = blockIdx.x * 256 + threadIdx.x;
  if (i < n) o[i] = a[i];
}
// hf/hb are PACKED u32 fp16-pair mailboxes [Spad*128]
__global__ void acomb_k(const unsigned* __restrict__ hf, const unsigned* __restrict__ hb,
                        float* __restrict__ o, int n) {
  int i = blockIdx.x * 256 + threadIdx.x;
  if (i >= n) return;
  int s = i >> 9, j = i & 511;
  const unsigned pk = (j < 256) ? hf[(size_t)s * 128 + (j >> 1)]
                                : hb[(size_t)s * 128 + ((j - 256) >> 1)];
  const float2 two = uph(pk);
  const float v = (j & 1) ? two.y : two.x;
  o[i] = fmaxf(v, 0.f);
}
__global__ void gatherpos_k(const float* __restrict__ fpos, const int* __restrict__ centers,
                            float* __restrict__ segpos, int n) {
  int i = blockIdx.x * 256 + threadIdx.x;
  if (i >= n) return;
  int s = i >> 9, dd = i & 511;
  int ct = centers[s];
  ct = ct < 0 ? 0 : (ct > TT - 1 ? TT - 1 : ct);
  segpos[i] = fpos[(size_t)ct * 512 + dd];
}

// ---------------------------------------------------------------- text norms
__global__ void tnorm_k(const float* __restrict__ text, float* __restrict__ tnorm) {
  int c = blockIdx.x * 256 + threadIdx.x;
  if (c >= 32) return;
  float s = 0.f;
  for (int dd = 0; dd < 512; dd++) { float v = text[(size_t)c * 512 + dd]; s += v * v; }
  tnorm[c] = sqrtf(s);
}

// ---------------- fold argmax projection: M[k][c] = Wf2c[k,:]·(text_c/|t_c|)
__global__ void prepM_k(const float* __restrict__ W, const float* __restrict__ b,
                        const float* __restrict__ text, const float* __restrict__ tnorm,
                        float* __restrict__ M, float* __restrict__ bdot) {
  int idx = blockIdx.x * 256 + threadIdx.x;
  if (idx < 512 * 32) {
    int k = idx >> 5, c = idx & 31;
    const float* wr = W + (size_t)k * 512;
    const float* tr = text + (size_t)c * 512;
    float s = 0.f;
    for (int dd = 0; dd < 512; dd++) s += wr[dd] * tr[dd];
    M[idx] = s / tnorm[c];
  }
  if (idx < 32) {
    const float* tr = text + (size_t)idx * 512;
    float s = 0.f;
    for (int dd = 0; dd < 512; dd++) s += b[dd] * tr[dd];
    bdot[idx] = s / tnorm[idx];
  }
}

// 8 rows/block; lane c of each 32-group owns class c; shfl-argmax (min idx tie)
__launch_bounds__(256)
__global__ void fargmax_k(const float* __restrict__ ff, const float* __restrict__ M,
                          const float* __restrict__ bdot, int* __restrict__ pred) {
  const int r = blockIdx.x * 8 + (threadIdx.x >> 5);
  const int c = threadIdx.x & 31;
  const float* fr = ff + (size_t)r * 512;
  float acc = bdot[c];
  for (int k = 0; k < 512; k++) acc += fr[k] * M[k * 32 + c];
  float best = acc; int bidx = c;
  for (int off = 16; off >= 1; off >>= 1) {
    const float ov = __shfl_xor(best, off);
    const int oi = __shfl_xor(bidx, off);
    if (ov > best || (ov == best && oi < bidx)) { best = ov; bidx = oi; }
  }
  if (c == 0) pred[r] = bidx;
}

// ------------------------------- parallel run-length segmentation (one block)
__global__ void segscan_k(const int* __restrict__ pred, int* __restrict__ segid,
                          int* __restrict__ starts, int* __restrict__ centers,
                          int* __restrict__ cnts) {
  __shared__ int base[256];
  __shared__ int SS;
  const int tid = threadIdx.x;
  int lc = 0;
  unsigned flags = 0;
  int prev = (tid > 0) ? pred[tid * 32 - 1] : 0;
  for (int i = 0; i < 32; i++) {
    const int t = tid * 32 + i;
    const int cur = pred[t];
    const int c = (t > 0) && (cur != prev);
    prev = cur;
    flags |= ((unsigned)c) << i;
    lc += c;
  }
  base[tid] = lc;
  __syncthreads();
  if (tid == 0) {
    int run = 0;
    for (int i = 0; i < 256; i++) { const int v = base[i]; base[i] = run; run += v; }
    SS = run + 1;
  }
  __syncthreads();
  int b = base[tid];
  for (int i = 0; i < 32; i++) {
    const int t = tid * 32 + i;
    if ((flags >> i) & 1u) { b++; starts[b] = t; }
    segid[t] = b;
  }
  if (tid == 0) starts[0] = 0;
  __threadfence_block();
  __syncthreads();
  const int S = SS;
  for (int s = tid; s < TT; s += 256) {
    if (s < S) {
      const int e = (s == S - 1) ? (TT - 1) : (starts[s + 1] - 1);
      centers[s] = (starts[s] + e) >> 1;
      cnts[s] = e - starts[s] + 1;
    } else {
      starts[s] = 0; cnts[s] = 1; centers[s] = 0;
    }
  }
}

// ---------------------------------------------------------- segment mean pool
__global__ void segmean_k(const float* __restrict__ ff, const int* __restrict__ starts,
                          const int* __restrict__ cnts, float* __restrict__ segmean, int S) {
  int idx = blockIdx.x * 256 + threadIdx.x;
  if (idx >= S * 512) return;
  int s = idx >> 9, dd = idx & 511;
  int st = starts[s], n = cnts[s];
  st = st < 0 ? 0 : (st > TT - 1 ? TT - 1 : st);
  n = n < 1 ? 1 : n;
  if (st + n > TT) n = TT - st;
  float a = 0.f;
  for (int t = st; t < st + n; t++) a += ff[(size_t)t * 512 + dd];
  segmean[idx] = a / (float)n;
}

// ------------------- multi-block bidirectional seg GRU (H=256), LDS weights
// r0-verified compute core; r11 NaN-poll; r12 remote-only; r13 packed u32
// mailbox. FROZEN (r13 post-mortem: protocol lever exhausted; residual cost
// is MALL store->visible latency, tier- and traffic-insensitive).
__launch_bounds__(192)
__global__ void gru_seg_mb_k(const float* __restrict__ gi_f, const float* __restrict__ gi_b,
                             const float* __restrict__ Whh_f, const float* __restrict__ bhh_f,
                             const float* __restrict__ Whh_b, const float* __restrict__ bhh_b,
                             unsigned* __restrict__ hf, unsigned* __restrict__ hb, int S) {
  const int dir = blockIdx.x >> 2;
  const int part = blockIdx.x & 3;
  const float* gi = dir ? gi_b : gi_f;
  const float* Whh = dir ? Whh_b : Whh_f;
  const float* bhh = dir ? bhh_b : bhh_f;
  unsigned* ho = dir ? hb : hf;
  const int tid = threadIdx.x;
  const int h0 = part * 64;
  const int w0 = h0 >> 1;           // word base of this partition (32 words)
  const int grp = tid >> 6;
  const int jj = tid & 63;
  const int j = grp * 256 + h0 + jj;
  __shared__ __align__(16) unsigned wlds[128 * 192];
  __shared__ __align__(16) unsigned hpk[128];
  __shared__ float rbuf[64], zbuf[64], gnbuf[64];
  for (int e = tid; e < 128 * 192; e += 192) {
    const int q = e / 768, rem = e % 768;
    const int g = rem >> 2, r = rem & 3;
    const int i2 = q * 4 + r;
    const int gg = (g >> 6) * 256 + h0 + (g & 63);
    wlds[e] = packh(Whh[(size_t)(2 * i2) * 768 + gg], Whh[(size_t)(2 * i2 + 1) * 768 + gg]);
  }
  for (int e = tid; e < 128; e += 192) hpk[e] = 0u;
  const float bj = bhh[j];
  float h_reg = 0.f;                // own h (threads 0..63)
  __syncthreads();
  const uint4* hp4 = reinterpret_cast<const uint4*>(hpk);
  const uint4* wp4 = reinterpret_cast<const uint4*>(wlds);
  // prefetch step 0 gi
  int s = dir ? (S - 1) : 0;
  float g_j = gi[(size_t)s * 768 + j];
  float g_n = (tid < 64) ? gi[(size_t)s * 768 + 512 + h0 + tid] : 0.f;
  for (int step = 0; step < S; step++) {
    float a0 = 0.f, a1 = 0.f, a2 = 0.f, a3 = 0.f;
#pragma unroll 8
    for (int q = 0; q < 32; q++) {
      const uint4 h4 = hp4[q];
      const uint4 w4 = wp4[q * 192 + tid];
      const float2 hh0 = uph(h4.x), hh1 = uph(h4.y), hh2 = uph(h4.z), hh3 = uph(h4.w);
      const float2 ww0 = uph(w4.x), ww1 = uph(w4.y), ww2 = uph(w4.z), ww3 = uph(w4.w);
      a0 += hh0.x * ww0.x + hh0.y * ww0.y;
      a1 += hh1.x * ww1.x + hh1.y * ww1.y;
      a2 += hh2.x * ww2.x + hh2.y * ww2.y;
      a3 += hh3.x * ww3.x + hh3.y * ww3.y;
    }
    const float gh = bj + (a0 + a1) + (a2 + a3);
    if (grp == 0)      rbuf[jj] = sigf(g_j + gh);
    else if (grp == 1) zbuf[jj] = sigf(g_j + gh);
    else               gnbuf[jj] = gh;
    __syncthreads();
    if (tid < 64) {
      const float nval = tanhf(g_n + rbuf[tid] * gnbuf[tid]);
      const float hn = (1.f - zbuf[tid]) * nval + zbuf[tid] * h_reg;
      h_reg = hn;
      const float hnb = __shfl_down(hn, 1);
      if ((tid & 1) == 0) {
        const unsigned pk = packh(hn, hnb);
        hpk[w0 + (tid >> 1)] = pk;                          // own words: LDS direct
        __hip_atomic_store(&ho[(size_t)s * 128 + w0 + (tid >> 1)], pk,
                           __ATOMIC_RELAXED, __HIP_MEMORY_SCOPE_AGENT);
      }
    }
    // prefetch next-step gi (overlaps peers' stores landing)
    const int sn = dir ? (s - 1) : (s + 1);
    if (step + 1 < S) {
      g_j = gi[(size_t)sn * 768 + j];
      if (tid < 64) g_n = gi[(size_t)sn * 768 + 512 + h0 + tid];
    }
    __syncthreads();
    // poll 96 REMOTE packed words straight into hpk (threads 0..95)
    if (tid < 96) {
      const int re = (tid < w0) ? tid : tid + 32;
      unsigned v = __hip_atomic_load(&ho[(size_t)s * 128 + re],
                                     __ATOMIC_RELAXED, __HIP_MEMORY_SCOPE_AGENT);
      unsigned guard = 0;
      while (v == HSENT && ++guard < GUARD_MAX) {
        __builtin_amdgcn_s_sleep(1);
        v = __hip_atomic_load(&ho[(size_t)s * 128 + re],
                              __ATOMIC_RELAXED, __HIP_MEMORY_SCOPE_AGENT);
      }
      hpk[re] = v;
    }
    __syncthreads();
    s = sn;
  }
}

// ------------------------- multi-block action GRU (H=512), LDS weights
// r11 NaN-poll protocol (fp32 mailbox); r13 register h + folded repack.
__launch_bounds__(128)
__global__ void gru_act_mb_k(const float* __restrict__ gi, const float* __restrict__ Whh,
                             const float* __restrict__ bhh, float* __restrict__ hout,
                             int steps) {
  const int part = blockIdx.x;
  const int tid = threadIdx.x;
  const int h0 = part * 32;
  const int grp = tid >> 5;
  const int jj = tid & 31;
  const bool act = (tid < 96);
  const int j = act ? (grp * 512 + h0 + jj) : 0;
  __shared__ __align__(16) unsigned wlds[256 * 96];
  __shared__ __align__(16) unsigned hpk[256];
  __shared__ float rbuf[32], zbuf[32], gnbuf[32];
  for (int e = tid; e < 256 * 96; e += 128) {
    const int q = e / 384, rem = e % 384;
    const int g = rem >> 2, r = rem & 3;
    const int i2 = q * 4 + r;
    const int gg = (g >> 5) * 512 + h0 + (g & 31);
    wlds[e] = packh(Whh[(size_t)(2 * i2) * 1536 + gg], Whh[(size_t)(2 * i2 + 1) * 1536 + gg]);
  }
  for (int e = tid; e < 256; e += 128) hpk[e] = 0u;
  const float bj = act ? bhh[j] : 0.f;
  float h_reg = 0.f;                // own h (threads 0..31)
  __syncthreads();
  const uint4* hp4 = reinterpret_cast<const uint4*>(hpk);
  const uint4* wp4 = reinterpret_cast<const uint4*>(wlds);
  float g_j = act ? gi[j] : 0.f;
  float g_n = (tid < 32) ? gi[1024 + h0 + tid] : 0.f;
  const int gown0 = h0 >> 2;            // own float4 groups [gown0, gown0+8)
  for (int step = 0; step < steps; step++) {
    if (act) {
      float a0 = 0.f, a1 = 0.f, a2 = 0.f, a3 = 0.f;
#pragma unroll 8
      for (int q = 0; q < 64; q++) {
        const uint4 h4 = hp4[q];
        const uint4 w4 = wp4[q * 96 + tid];
        const float2 hh0 = uph(h4.x), hh1 = uph(h4.y), hh2 = uph(h4.z), hh3 = uph(h4.w);
        const float2 ww0 = uph(w4.x), ww1 = uph(w4.y), ww2 = uph(w4.z), ww3 = uph(w4.w);
        a0 += hh0.x * ww0.x + hh0.y * ww0.y;
        a1 += hh1.x * ww1.x + hh1.y * ww1.y;
        a2 += hh2.x * ww2.x + hh2.y * ww2.y;
        a3 += hh3.x * ww3.x + hh3.y * ww3.y;
      }
      const float gh = bj + (a0 + a1) + (a2 + a3);
      if (grp == 0)      rbuf[jj] = sigf(g_j + gh);
      else if (grp == 1) zbuf[jj] = sigf(g_j + gh);
      else               gnbuf[jj] = gh;
    }
    __syncthreads();
    if (tid < 32) {
      const float nval = tanhf(g_n + rbuf[tid] * gnbuf[tid]);
      const float hn = (1.f - zbuf[tid]) * nval + zbuf[tid] * h_reg;
      h_reg = hn;
      __hip_atomic_store(&hout[(size_t)step * 512 + h0 + tid], hn,
                         __ATOMIC_RELAXED, __HIP_MEMORY_SCOPE_AGENT);
      const float hnb = __shfl_down(hn, 1);
      if ((tid & 1) == 0) hpk[(h0 + tid) >> 1] = packh(hn, hnb);  // own words
    }
    if (step + 1 < steps) {
      if (act) g_j = gi[(size_t)(step + 1) * 1536 + j];
      if (tid < 32) g_n = gi[(size_t)(step + 1) * 1536 + 1024 + h0 + tid];
    }
    __syncthreads();
    // poll remote groups (4-wide) straight into hpk; own groups done above
    {
      const int g = tid;  // 0..127 covers all 128 groups of 4
      if (g < gown0 || g >= gown0 + 8) {
        const float* gp = hout + (size_t)step * 512 + 4 * g;
        float x0, x1, x2, x3;
        unsigned guard = 0;
        do {
          x0 = __hip_atomic_load(gp + 0, __ATOMIC_RELAXED, __HIP_MEMORY_SCOPE_AGENT);
          x1 = __hip_atomic_load(gp + 1, __ATOMIC_RELAXED, __HIP_MEMORY_SCOPE_AGENT);
          x2 = __hip_atomic_load(gp + 2, __ATOMIC_RELAXED, __HIP_MEMORY_SCOPE_AGENT);
          x3 = __hip_atomic_load(gp + 3, __ATOMIC_RELAXED, __HIP_MEMORY_SCOPE_AGENT);
          if (x0 == x0 && x1 == x1 && x2 == x2 && x3 == x3) break;
          __builtin_amdgcn_s_sleep(1);
        } while (++guard < GUARD_MAX);
        hpk[2 * g + 0] = packh(x0, x1);
        hpk[2 * g + 1] = packh(x2, x3);
      }
    }
    __syncthreads();
  }
}

// ------------------------------------------------ MFMA GEMM (fp16 staged)
// C[M,N] = (A [+ A2]) @ B + bias.  Tile M64 x N128, K-chunk 64.
// A2 (optional, same shape as A) fused elementwise add during staging.
__launch_bounds__(256)
__global__ void gemmm_k(const float* __restrict__ A, const float* __restrict__ A2,
                        const float* __restrict__ B,
                        const float* __restrict__ bias, float* __restrict__ C,
                        int M, int N, int K) {
  __shared__ __align__(16) _Float16 As16[64][72];
  __shared__ __align__(16) _Float16 Bs16[128][72];
  const int n0 = blockIdx.x * 128, m0 = blockIdx.y * 64;
  const int tid = threadIdx.x;
  const int l = tid & 63, w = tid >> 6;
  const int wm = w & 1, wn = w >> 1;
  const int l31 = l & 31, q = l >> 5;
  f32x16 acc0, acc1;
#pragma unroll
  for (int i = 0; i < 16; i++) { acc0[i] = 0.f; acc1[i] = 0.f; }
  const int am = tid >> 2, ak0 = (tid & 3) * 16;
  const int bk = tid >> 2, bn0 = (tid & 3) * 32;
  for (int kc = 0; kc < K; kc += 64) {
    __syncthreads();
#pragma unroll
    for (int kk = 0; kk < 16; kk += 4) {
      float4 av = *reinterpret_cast<const float4*>(A + (size_t)(m0 + am) * K + kc + ak0 + kk);
      if (A2) {
        const float4 a2 = *reinterpret_cast<const float4*>(A2 + (size_t)(m0 + am) * K + kc + ak0 + kk);
        av.x += a2.x; av.y += a2.y; av.z += a2.z; av.w += a2.w;
      }
      As16[am][ak0 + kk + 0] = (_Float16)av.x; As16[am][ak0 + kk + 1] = (_Float16)av.y;
      As16[am][ak0 + kk + 2] = (_Float16)av.z; As16[am][ak0 + kk + 3] = (_Float16)av.w;
    }
#pragma unroll
    for (int nn = 0; nn < 32; nn += 4) {
      const float4 bv = *reinterpret_cast<const float4*>(B + (size_t)(kc + bk) * N + n0 + bn0 + nn);
      Bs16[bn0 + nn + 0][bk] = (_Float16)bv.x; Bs16[bn0 + nn + 1][bk] = (_Float16)bv.y;
      Bs16[bn0 + nn + 2][bk] = (_Float16)bv.z; Bs16[bn0 + nn + 3][bk] = (_Float16)bv.w;
    }
    __syncthreads();
#pragma unroll
    for (int ks = 0; ks < 4; ks++) {
      const int k0 = ks * 16 + q * 8;
      const f16x8 a = *reinterpret_cast<const f16x8*>(&As16[wm * 32 + l31][k0]);
      const f16x8 b0 = *reinterpret_cast<const f16x8*>(&Bs16[wn * 64 + l31][k0]);
      acc0 = __builtin_amdgcn_mfma_f32_32x32x16_f16(a, b0, acc0, 0, 0, 0);
      const f16x8 b1 = *reinterpret_cast<const f16x8*>(&Bs16[wn * 64 + 32 + l31][k0]);
      acc1 = __builtin_amdgcn_mfma_f32_32x32x16_f16(a, b1, acc1, 0, 0, 0);
    }
  }
#pragma unroll
  for (int r = 0; r < 16; r++) {
    const int m = m0 + wm * 32 + (r & 3) + 8 * (r >> 2) + 4 * q;
    {
      const int n = n0 + wn * 64 + l31;
      float v = acc0[r];
      if (bias) v += bias[n];
      C[(size_t)m * N + n] = v;
    }
    {
      const int n = n0 + wn * 64 + 32 + l31;
      float v = acc1[r];
      if (bias) v += bias[n];
      C[(size_t)m * N + n] = v;
    }
  }
}

// ------------------------ MFMA logits: C[M,N] = scale * A[M,K] @ B[N,K]^T
// Tile 64x64, K mult of 64. B rows stage coalesced (B is row-major [N][K]).
// Stores guarded by m < Mv (rows >= Mv may read garbage A rows; row-separable
// MFMA confines it). Row stride of C is Nld.
__launch_bounds__(256)
__global__ void gemmnt_k(const float* __restrict__ A, const float* __restrict__ B,
                         float* __restrict__ C, int Mv, int Nld, int K, float scale) {
  __shared__ __align__(16) _Float16 As16[64][72];
  __shared__ __align__(16) _Float16 Bs16[64][72];
  const int n0 = blockIdx.x * 64, m0 = blockIdx.y * 64;
  const int tid = threadIdx.x;
  const int l = tid & 63, w = tid >> 6;
  const int wm = w & 1, wn = w >> 1;
  const int l31 = l & 31, q = l >> 5;
  f32x16 acc;
#pragma unroll
  for (int i = 0; i < 16; i++) acc[i] = 0.f;
  const int am = tid >> 2, ak0 = (tid & 3) * 16;
  for (int kc = 0; kc < K; kc += 64) {
    __syncthreads();
#pragma unroll
    for (int kk = 0; kk < 16; kk += 4) {
      const float4 av = *reinterpret_cast<const float4*>(A + (size_t)(m0 + am) * K + kc + ak0 + kk);
      As16[am][ak0 + kk + 0] = (_Float16)av.x; As16[am][ak0 + kk + 1] = (_Float16)av.y;
      As16[am][ak0 + kk + 2] = (_Float16)av.z; As16[am][ak0 + kk + 3] = (_Float16)av.w;
      const float4 bv = *reinterpret_cast<const float4*>(B + (size_t)(n0 + am) * K + kc + ak0 + kk);
      Bs16[am][ak0 + kk + 0] = (_Float16)bv.x; Bs16[am][ak0 + kk + 1] = (_Float16)bv.y;
      Bs16[am][ak0 + kk + 2] = (_Float16)bv.z; Bs16[am][ak0 + kk + 3] = (_Float16)bv.w;
    }
    __syncthreads();
#pragma unroll
    for (int ks = 0; ks < 4; ks++) {
      const int k0 = ks * 16 + q * 8;
      const f16x8 a = *reinterpret_cast<const f16x8*>(&As16[wm * 32 + l31][k0]);
      const f16x8 b = *reinterpret_cast<const f16x8*>(&Bs16[wn * 32 + l31][k0]);
      acc = __builtin_amdgcn_mfma_f32_32x32x16_f16(a, b, acc, 0, 0, 0);
    }
  }
#pragma unroll
  for (int r = 0; r < 16; r++) {
    const int m = m0 + wm * 32 + (r & 3) + 8 * (r >> 2) + 4 * q;
    const int n = n0 + wn * 32 + l31;
    if (m < Mv) C[(size_t)m * Nld + n] = acc[r] * scale;
  }
}

// ------------------ parallel row softmax; zero-fills [NV, NXs) for K-padding
__launch_bounds__(256)
__global__ void psoft_k(float* __restrict__ L, int NXs, int NV) {
  float* row = L + (size_t)blockIdx.x * NXs;
  __shared__ float redm[4], reds[4];
  const int tid = threadIdx.x;
  float m = -3.4e38f;
  for (int x = tid; x < NV; x += 256) m = fmaxf(m, row[x]);
  for (int off = 32; off >= 1; off >>= 1) m = fmaxf(m, __shfl_xor(m, off));
  if ((tid & 63) == 0) redm[tid >> 6] = m;
  __syncthreads();
  m = fmaxf(fmaxf(redm[0], redm[1]), fmaxf(redm[2], redm[3]));
  float s = 0.f;
  for (int x = tid; x < NV; x += 256) {
    const float p = expf(row[x] - m);
    row[x] = p;
    s += p;
  }
  for (int off = 32; off >= 1; off >>= 1) s += __shfl_xor(s, off);
  if ((tid & 63) == 0) reds[tid >> 6] = s;
  __syncthreads();
  s = reds[0] + reds[1] + reds[2] + reds[3];
  const float inv = 1.f / s;
  for (int x = tid; x < NV; x += 256) row[x] *= inv;
  for (int x = NV + tid; x < NXs; x += 256) row[x] = 0.f;
}

// ------------------- MFMA ff2: Y(D,T) = relu([seg2[sid[t]], ff[t]] @ Wsf + b)^T
__launch_bounds__(256)
__global__ void ff2m_k(const float* __restrict__ seg2, const float* __restrict__ ff,
                       const int* __restrict__ segid, const float* __restrict__ Wsf,
                       const float* __restrict__ bsf, float* __restrict__ Y, int S) {
  __shared__ __align__(16) _Float16 As16[64][72];    // [dim][k]
  __shared__ __align__(16) _Float16 Bs16[128][72];   // [frame][k]
  const int t0 = blockIdx.x * 128, nd0 = blockIdx.y * 64;
  const int tid = threadIdx.x;
  const int l = tid & 63, w = tid >> 6;
  const int wm = w & 1, wn = w >> 1;
  const int l31 = l & 31, q = l >> 5;
  f32x16 acc0, acc1;
#pragma unroll
  for (int i = 0; i < 16; i++) { acc0[i] = 0.f; acc1[i] = 0.f; }
  const int ak = tid >> 2, an0 = (tid & 3) * 16;
  const int bt = tid >> 1, bk0 = (tid & 1) * 32;
  const int tglob = t0 + bt;
  int sid = segid[tglob];
  sid = sid < 0 ? 0 : (sid >= S ? S - 1 : sid);
  for (int kc = 0; kc < 1024; kc += 64) {
    __syncthreads();
#pragma unroll
    for (int nn = 0; nn < 16; nn += 4) {
      const float4 wv = *reinterpret_cast<const float4*>(Wsf + (size_t)(kc + ak) * 512 + nd0 + an0 + nn);
      As16[an0 + nn + 0][ak] = (_Float16)wv.x; As16[an0 + nn + 1][ak] = (_Float16)wv.y;
      As16[an0 + nn + 2][ak] = (_Float16)wv.z; As16[an0 + nn + 3][ak] = (_Float16)wv.w;
    }
    {
      const float* src = (kc < 512) ? (seg2 + (size_t)sid * 512 + kc + bk0)
                                    : (ff + (size_t)tglob * 512 + (kc - 512) + bk0);
#pragma unroll
      for (int kk = 0; kk < 32; kk += 4) {
        const float4 xv = *reinterpret_cast<const float4*>(src + kk);
        Bs16[bt][bk0 + kk + 0] = (_Float16)xv.x; Bs16[bt][bk0 + kk + 1] = (_Float16)xv.y;
        Bs16[bt][bk0 + kk + 2] = (_Float16)xv.z; Bs16[bt][bk0 + kk + 3] = (_Float16)xv.w;
      }
    }
    __syncthreads();
#pragma unroll
    for (int ks = 0; ks < 4; ks++) {
      const int k0 = ks * 16 + q * 8;
      const f16x8 a = *reinterpret_cast<const f16x8*>(&As16[wm * 32 + l31][k0]);
      const f16x8 b0 = *reinterpret_cast<const f16x8*>(&Bs16[wn * 64 + l31][k0]);
      acc0 = __builtin_amdgcn_mfma_f32_32x32x16_f16(a, b0, acc0, 0, 0, 0);
      const f16x8 b1 = *reinterpret_cast<const f16x8*>(&Bs16[wn * 64 + 32 + l31][k0]);
      acc1 = __builtin_amdgcn_mfma_f32_32x32x16_f16(a, b1, acc1, 0, 0, 0);
    }
  }
#pragma unroll
  for (int r = 0; r < 16; r++) {
    const int nd = nd0 + wm * 32 + (r & 3) + 8 * (r >> 2) + 4 * q;
    const float bb = bsf[nd];
    {
      const int t = t0 + wn * 64 + l31;
      Y[(size_t)nd * TT + t] = fmaxf(acc0[r] + bb, 0.f);
    }
    {
      const int t = t0 + wn * 64 + 32 + l31;
      Y[(size_t)nd * TT + t] = fmaxf(acc1[r] + bb, 0.f);
    }
  }
}

// --------------------------------------------------- MFMA TCN conv (fp16 in)
template<int NTAPS, int RELU, int RES>
__launch_bounds__(256)
__global__ void convm_k(const float* __restrict__ X, const float* __restrict__ W,
                        const float* __restrict__ bias, const float* __restrict__ Res,
                        float* __restrict__ Y, int dil) {
  const int d = (NTAPS == 3) ? dil : 0;
  const int width = 128 + 2 * d;
  __shared__ __align__(16) _Float16 Ws16[NTAPS][64][72];
  __shared__ __align__(16) _Float16 Xs16[192][72];
  const int t0 = blockIdx.x * 128, c0 = blockIdx.y * 64;
  const int tid = threadIdx.x;
  const int l = tid & 63, w = tid >> 6;
  const int wm = w & 1, wn = w >> 1;
  const int l31 = l & 31, q = l >> 5;
  f32x16 acc0, acc1;
#pragma unroll
  for (int i = 0; i < 16; i++) { acc0[i] = 0.f; acc1[i] = 0.f; }
  const int xk = tid >> 2;
  const int xu0 = tid & 3;
  for (int kc = 0; kc < 512; kc += 64) {
    __syncthreads();
    {
      const float* xr = X + (size_t)(kc + xk) * TT;
      for (int u = xu0; u < width; u += 4) {
        const int gt = t0 - d + u;
        const float v = (gt >= 0 && gt < TT) ? xr[gt] : 0.f;
        Xs16[u][xk] = (_Float16)v;
      }
    }
    if (NTAPS == 3) {
      for (int e = tid; e < 64 * 48; e += 256) {
        const int c = e / 48;
        const int f0 = (e - c * 48) * 4;
        const float4 wv = *reinterpret_cast<const float4*>(
            W + (size_t)(c0 + c) * 1536 + (size_t)kc * 3 + f0);
        const float vv[4] = {wv.x, wv.y, wv.z, wv.w};
#pragma unroll
        for (int t = 0; t < 4; t++) {
          const int f = f0 + t;
          Ws16[f % 3][c][f / 3] = (_Float16)vv[t];
        }
      }
    } else {
      for (int e = tid; e < 1024; e += 256) {
        const int c = e >> 4, i0 = (e & 15) << 2;
        const float4 wv = *reinterpret_cast<const float4*>(W + (size_t)(c0 + c) * 512 + kc + i0);
        Ws16[0][c][i0 + 0] = (_Float16)wv.x; Ws16[0][c][i0 + 1] = (_Float16)wv.y;
        Ws16[0][c][i0 + 2] = (_Float16)wv.z; Ws16[0][c][i0 + 3] = (_Float16)wv.w;
      }
    }
    __syncthreads();
#pragma unroll
    for (int tap = 0; tap < NTAPS; tap++) {
#pragma unroll
      for (int ks = 0; ks < 4; ks++) {
        const int k0 = ks * 16 + q * 8;
        const f16x8 a = *reinterpret_cast<const f16x8*>(&Ws16[tap][wm * 32 + l31][k0]);
        const int row0 = wn * 64 + l31 + tap * d;
        const f16x8 b0 = *reinterpret_cast<const f16x8*>(&Xs16[row0][k0]);
        acc0 = __builtin_amdgcn_mfma_f32_32x32x16_f16(a, b0, acc0, 0, 0, 0);
        const f16x8 b1 = *reinterpret_cast<const f16x8*>(&Xs16[row0 + 32][k0]);
        acc1 = __builtin_amdgcn_mfma_f32_32x32x16_f16(a, b1, acc1, 0, 0, 0);
      }
    }
  }
#pragma unroll
  for (int r = 0; r < 16; r++) {
    const int m = wm * 32 + (r & 3) + 8 * (r >> 2) + 4 * q;
    const int c = c0 + m;
    const float bb = bias[c];
    {
      const int t = t0 + wn * 64 + l31;
      float v = acc0[r] + bb;
      if (RES) v += Res[(size_t)c * TT + t];
      if (RELU) v = fmaxf(v, 0.f);
      Y[(size_t)c * TT + t] = v;
    }
    {
      const int t = t0 + wn * 64 + 32 + l31;
      float v = acc1[r] + bb;
      if (RES) v += Res[(size_t)c * TT + t];
      if (RELU) v = fmaxf(v, 0.f);
      Y[(size_t)c * TT + t] = v;
    }
  }
}

// -------------------- tiled transpose (512,T) -> out (T,512) + f32 copy (T,512)
__launch_bounds__(256)
__global__ void temit_k(const float* __restrict__ Xin, float* __restrict__ outp,
                        float* __restrict__ Aout) {
  __shared__ float tile[32][33];
  const int t0 = blockIdx.x * 32, d0 = blockIdx.y * 32;
  const int lx = threadIdx.x & 31, ly = threadIdx.x >> 5;
#pragma unroll
  for (int r = 0; r < 4; r++)
    tile[ly + 8 * r][lx] = Xin[(size_t)(d0 + ly + 8 * r) * TT + t0 + lx];
  __syncthreads();
#pragma unroll
  for (int r = 0; r < 4; r++) {
    const int t = t0 + ly + 8 * r, dd = d0 + lx;
    const float v = tile[lx][ly + 8 * r];
    outp[(size_t)t * 512 + dd] = v;
    Aout[(size_t)t * 512 + dd] = v;
  }
}

// --------------------------- cosine sim, block per row (||v|| computed once)
__launch_bounds__(256)
__global__ void csim_k(const float* __restrict__ V, const float* __restrict__ text,
                       const float* __restrict__ tnorm, float* __restrict__ out) {
  __shared__ float vs[512];
  __shared__ float red[4];
  const int r = blockIdx.x, tid = threadIdx.x;
  const float a = V[(size_t)r * 512 + tid];
  const float b = V[(size_t)r * 512 + 256 + tid];
  vs[tid] = a; vs[tid + 256] = b;
  float ssp = a * a + b * b;
  for (int off = 32; off >= 1; off >>= 1) ssp += __shfl_xor(ssp, off);
  if ((tid & 63) == 0) red[tid >> 6] = ssp;
  __syncthreads();
  const float ss = red[0] + red[1] + red[2] + red[3];
  const int c = tid >> 3, p = tid & 7;
  const float* tr = text + (size_t)c * 512 + p * 64;
  const float* vr = vs + p * 64;
  float d = 0.f;
#pragma unroll
  for (int k = 0; k < 64; k++) d += vr[k] * tr[k];
  for (int off = 4; off >= 1; off >>= 1) d += __shfl_xor(d, off);
  if (p == 0) out[(size_t)r * 32 + c] = d / (sqrtf(ss) * tnorm[c]);
}

// ======================================================================= host
extern "C" void kernel_launch(void* const* d_in, const int* in_sizes, int n_in,
                              void* d_out, int out_size, void* d_ws, size_t ws_size,
                              hipStream_t stream) {
  const float* in_ff   = (const float*)d_in[0];
  const float* in_act  = (const float*)d_in[1];
  const float* in_fpos = (const float*)d_in[2];
  const float* in_apos = (const float*)d_in[3];
  const float* in_text = (const float*)d_in[4];
  const float* Wf2c = (const float*)d_in[5];  const float* bf2c = (const float*)d_in[6];
  const float* Wa2c = (const float*)d_in[7];  const float* ba2c = (const float*)d_in[8];
  const float* Ws2c = (const float*)d_in[9];  const float* bs2c = (const float*)d_in[10];
  const float* Wih_f = (const float*)d_in[11]; const float* Whh_f = (const float*)d_in[12];
  const float* bih_f = (const float*)d_in[13]; const float* bhh_f = (const float*)d_in[14];
  const float* Wih_b = (const float*)d_in[15]; const float* Whh_b = (const float*)d_in[16];
  const float* bih_b = (const float*)d_in[17]; const float* bhh_b = (const float*)d_in[18];
  const float* Wcomb = (const float*)d_in[19]; const float* bcomb = (const float*)d_in[20];
  const float* f2a_Wq = (const float*)d_in[21]; const float* f2a_Wk = (const float*)d_in[22];
  const float* f2a_Wv = (const float*)d_in[23]; const float* f2a_Wo = (const float*)d_in[24];
  const float* f2a_bo = (const float*)d_in[25];
  const float* ag_Wih = (const float*)d_in[26]; const float* ag_Whh = (const float*)d_in[27];
  const float* ag_bih = (const float*)d_in[28]; const float* ag_bhh = (const float*)d_in[29];
  const float* a2f_Wq = (const float*)d_in[30]; const float* a2f_Wk = (const float*)d_in[31];
  const float* a2f_Wv = (const float*)d_in[32]; const float* a2f_Wo = (const float*)d_in[33];
  const float* a2f_bo = (const float*)d_in[34];
  const float* Wsf = (const float*)d_in[35]; const float* bsf = (const float*)d_in[36];
  const float* tcn_inW = (const float*)d_in[37]; const float* tcn_inb = (const float*)d_in[38];
  const float* tcn_dW = (const float*)d_in[39]; const float* tcn_db = (const float*)d_in[40];
  const float* tcn_pW = (const float*)d_in[41]; const float* tcn_pb = (const float*)d_in[42];
  const float* tcn_outW = (const float*)d_in[43]; const float* tcn_outb = (const float*)d_in[44];

  int S = (out_size - (TT * DD + MM * DD + TT * CC + MM * CC)) / CC;
  if (S < 1) S = 1;
  if (S > TT) S = TT;
  const int Spad = (S + 63) & ~63;

  char* ws = (char*)d_ws;
  size_t off = 0;
  auto alloc = [&](size_t b) -> char* { char* p = ws + off; off += (b + 255) & ~(size_t)255; return p; };
  float* Mmat = (float*)alloc((size_t)512 * 32 * 4);
  float* bdot = (float*)alloc(32 * 4);
  const size_t BTD = (size_t)TT * DD * 4;
  float* bufA = (float*)alloc(BTD);
  float* bufB = (float*)alloc(BTD);
  int* pred    = (int*)alloc((size_t)TT * 4);
  int* segid   = (int*)alloc((size_t)TT * 4);
  int* starts  = (int*)alloc((size_t)TT * 4);
  int* centers = (int*)alloc((size_t)TT * 4);
  int* cnts    = (int*)alloc((size_t)TT * 4);
  float* tnorm = (float*)alloc(32 * 4);
  float* segmean = (float*)alloc((size_t)Spad * 512 * 4);
  float* gif  = (float*)alloc((size_t)Spad * 768 * 4);
  float* gib  = (float*)alloc((size_t)Spad * 768 * 4);
  unsigned* hfb = (unsigned*)alloc((size_t)Spad * 128 * 4);   // packed fp16 pairs
  unsigned* hbb = (unsigned*)alloc((size_t)Spad * 128 * 4);   // packed fp16 pairs
  float* acmb = (float*)alloc((size_t)Spad * 512 * 4);
  float* segc = (float*)alloc((size_t)Spad * 512 * 4);
  float* segpos = (float*)alloc((size_t)Spad * 512 * 4);
  float* kf2a = (float*)alloc((size_t)Spad * 512 * 4);
  float* vf2a = (float*)alloc((size_t)Spad * 512 * 4);
  float* q2   = (float*)alloc((size_t)Spad * 512 * 4);
  float* att2 = (float*)alloc((size_t)Spad * 512 * 4);
  float* seg2 = (float*)alloc((size_t)Spad * 512 * 4);
  float* vseg = (float*)alloc((size_t)Spad * 512 * 4);
  float* pbuf = (float*)alloc((size_t)64 * Spad * 4);
  float* qf2a = (float*)alloc((size_t)64 * 512 * 4);
  float* att1 = (float*)alloc((size_t)64 * 512 * 4);
  float* af0  = (float*)alloc((size_t)64 * 512 * 4);
  float* aggi = (float*)alloc((size_t)64 * 1536 * 4);
  float* afg  = (float*)alloc((size_t)64 * 512 * 4);
  float* k2   = (float*)alloc((size_t)64 * 512 * 4);
  float* v2   = (float*)alloc((size_t)64 * 512 * 4);
  float* vaf  = (float*)alloc((size_t)64 * 512 * 4);
  (void)ws_size; (void)in_sizes; (void)n_in;

  float* outp = (float*)d_out;
  float* out_ff   = outp;
  float* out_af   = outp + (size_t)TT * DD;
  float* out_fsim = out_af + (size_t)MM * DD;
  float* out_asim = out_fsim + (size_t)TT * CC;
  float* out_ssim = out_asim + (size_t)MM * CC;

  auto GR = [](long n) { return (unsigned)((n + 255) / 256); };
  const unsigned Sg = (unsigned)(Spad / 64);
  const float ATTS = 0.044194173824159216f;

  tnorm_k<<<1, 256, 0, stream>>>(in_text, tnorm);

  // prefill mailboxes (sentinel-poll protocol)
  sfill_k<<<64, 256, 0, stream>>>(hfb, (long)Spad * 128);
  sfill_k<<<64, 256, 0, stream>>>(hbb, (long)Spad * 128);
  nanfill_k<<<32, 256, 0, stream>>>(afg, (long)64 * 512);

  // segmentation: folded projection (ff @ (Wf2c @ t_hat)) -> argmax
  prepM_k<<<64, 256, 0, stream>>>(Wf2c, bf2c, in_text, tnorm, Mmat, bdot);
  fargmax_k<<<TT / 8, 256, 0, stream>>>(in_ff, Mmat, bdot, pred);
  segscan_k<<<1, 256, 0, stream>>>(pred, segid, starts, centers, cnts);
  segmean_k<<<GR((long)S * 512), 256, 0, stream>>>(in_ff, starts, cnts, segmean, S);

  // seg BiGRU (packed-u32 sentinel-poll mailbox)
  gemmm_k<<<dim3(6, Sg), 256, 0, stream>>>(segmean, nullptr, Wih_f, bih_f, gif, Spad, 768, 512);
  gemmm_k<<<dim3(6, Sg), 256, 0, stream>>>(segmean, nullptr, Wih_b, bih_b, gib, Spad, 768, 512);
  gru_seg_mb_k<<<8, 192, 0, stream>>>(gif, gib, Whh_f, bhh_f, Whh_b, bhh_b, hfb, hbb, S);
  acomb_k<<<GR((long)S * 512), 256, 0, stream>>>(hfb, hbb, acmb, S * 512);
  gemmm_k<<<dim3(4, Sg), 256, 0, stream>>>(acmb, nullptr, Wcomb, bcomb, segc, Spad, 512, 512);
  gatherpos_k<<<GR((long)S * 512), 256, 0, stream>>>(in_fpos, centers, segpos, S * 512);

  // f2a attention (actions query segments); pos-add fused into projections
  gemmm_k<<<dim3(4, 1), 256, 0, stream>>>(in_act, in_apos, f2a_Wq, nullptr, qf2a, 64, 512, 512);
  gemmm_k<<<dim3(4, Sg), 256, 0, stream>>>(segc, segpos, f2a_Wk, nullptr, kf2a, Spad, 512, 512);
  gemmm_k<<<dim3(4, Sg), 256, 0, stream>>>(segc, nullptr, f2a_Wv, nullptr, vf2a, Spad, 512, 512);
  gemmnt_k<<<dim3(Spad / 64, 1), 256, 0, stream>>>(qf2a, kf2a, pbuf, 64, Spad, 512, ATTS);
  psoft_k<<<64, 256, 0, stream>>>(pbuf, Spad, S);
  gemmm_k<<<dim3(4, 1), 256, 0, stream>>>(pbuf, nullptr, vf2a, nullptr, att1, 64, 512, Spad);
  gemmm_k<<<dim3(4, 1), 256, 0, stream>>>(att1, nullptr, f2a_Wo, f2a_bo, af0, 64, 512, 512);

  // action GRU (NaN-poll mailbox)
  gemmm_k<<<dim3(12, 1), 256, 0, stream>>>(af0, nullptr, ag_Wih, ag_bih, aggi, 64, 1536, 512);
  gru_act_mb_k<<<16, 128, 0, stream>>>(aggi, ag_Whh, ag_bhh, afg, MM);
  copy_k<<<GR(64 * 512), 256, 0, stream>>>(afg, out_af, 64 * 512);

  // a2f attention (segments query actions)
  gemmm_k<<<dim3(4, Sg), 256, 0, stream>>>(segc, segpos, a2f_Wq, nullptr, q2, Spad, 512, 512);
  gemmm_k<<<dim3(4, 1), 256, 0, stream>>>(afg, in_apos, a2f_Wk, nullptr, k2, 64, 512, 512);
  gemmm_k<<<dim3(4, 1), 256, 0, stream>>>(afg, nullptr, a2f_Wv, nullptr, v2, 64, 512, 512);
  gemmnt_k<<<dim3(1, Spad / 64), 256, 0, stream>>>(q2, k2, pbuf, S, 64, 512, ATTS);
  psoft_k<<<(unsigned)S, 256, 0, stream>>>(pbuf, 64, 64);
  gemmm_k<<<dim3(4, Sg), 256, 0, stream>>>(pbuf, nullptr, v2, nullptr, att2, Spad, 512, 64);
  gemmm_k<<<dim3(4, Sg), 256, 0, stream>>>(att2, nullptr, a2f_Wo, a2f_bo, seg2, Spad, 512, 512);

  // frame fusion + TCN (MFMA), ping-pong bufA <-> bufB as (D,T)
  ff2m_k<<<dim3(64, 8), 256, 0, stream>>>(seg2, in_ff, segid, Wsf, bsf, bufA, S);
  convm_k<1, 0, 0><<<dim3(64, 8), 256, 0, stream>>>(bufA, tcn_inW, tcn_inb, nullptr, bufB, 1);
  for (int l = 0; l < 6; l++) {
    convm_k<3, 1, 0><<<dim3(64, 8), 256, 0, stream>>>(
        bufB, tcn_dW + (size_t)l * 512 * 512 * 3, tcn_db + (size_t)l * 512, nullptr, bufA, 1 << l);
    convm_k<1, 0, 1><<<dim3(64, 8), 256, 0, stream>>>(
        bufA, tcn_pW + (size_t)l * 512 * 512, tcn_pb + (size_t)l * 512, bufB, bufB, 1);
  }
  convm_k<1, 0, 0><<<dim3(64, 8), 256, 0, stream>>>(bufB, tcn_outW, tcn_outb, nullptr, bufA, 1);
  temit_k<<<dim3(256, 16), 256, 0, stream>>>(bufA, out_ff, bufB);

  // similarity heads
  gemmm_k<<<dim3(4, 128), 256, 0, stream>>>(bufB, nullptr, Wf2c, bf2c, bufA, TT, 512, 512);
  csim_k<<<TT, 256, 0, stream>>>(bufA, in_text, tnorm, out_fsim);
  gemmm_k<<<dim3(4, 1), 256, 0, stream>>>(afg, nullptr, Wa2c, ba2c, vaf, 64, 512, 512);
  csim_k<<<64, 256, 0, stream>>>(vaf, in_text, tnorm, out_asim);
  gemmm_k<<<dim3(4, Sg), 256, 0, stream>>>(seg2, nullptr, Ws2c, bs2c, vseg, Spad, 512, 512);
  csim_k<<<(unsigned)S, 256, 0, stream>>>(vseg, in_text, tnorm, out_ssim);
}